// Round 5
// baseline (228.317 us; speedup 1.0000x reference)
//
#include <hip/hip_runtime.h>
#include <math.h>

#define Bv   8192
#define EPSv 1e-5f
#define CONFv 0.1f
#define MB (1024*1024)

typedef __attribute__((ext_vector_type(8))) short short8;
typedef __attribute__((ext_vector_type(4))) float f32x4;

__device__ __forceinline__ float wave_sum64(float v){
  #pragma unroll
  for (int o = 32; o; o >>= 1) v += __shfl_xor(v, o, 64);
  return v;
}

__device__ __forceinline__ void split3f(float x, short &h, short &m, short &l){
  unsigned u = __float_as_uint(x);
  h = (short)(u >> 16);
  float r1 = x - __uint_as_float(u & 0xffff0000u);
  unsigned u1 = __float_as_uint(r1);
  m = (short)(u1 >> 16);
  float r2 = r1 - __uint_as_float(u1 & 0xffff0000u);
  l = (short)(__float_as_uint(r2) >> 16);
}

__device__ __forceinline__ f32x4 mfma6(short8 ah, short8 am, short8 al,
                                       short8 bh, short8 bm, short8 bl, f32x4 c){
  c = __builtin_amdgcn_mfma_f32_16x16x32_bf16(al, bh, c, 0, 0, 0);
  c = __builtin_amdgcn_mfma_f32_16x16x32_bf16(ah, bl, c, 0, 0, 0);
  c = __builtin_amdgcn_mfma_f32_16x16x32_bf16(am, bm, c, 0, 0, 0);
  c = __builtin_amdgcn_mfma_f32_16x16x32_bf16(am, bh, c, 0, 0, 0);
  c = __builtin_amdgcn_mfma_f32_16x16x32_bf16(ah, bm, c, 0, 0, 0);
  c = __builtin_amdgcn_mfma_f32_16x16x32_bf16(ah, bh, c, 0, 0, 0);
  return c;
}

__device__ __forceinline__ f32x4 mfma3(short8 ah, short8 al,
                                       short8 bh, short8 bl, f32x4 c){
  c = __builtin_amdgcn_mfma_f32_16x16x32_bf16(al, bh, c, 0, 0, 0);
  c = __builtin_amdgcn_mfma_f32_16x16x32_bf16(ah, bl, c, 0, 0, 0);
  c = __builtin_amdgcn_mfma_f32_16x16x32_bf16(ah, bh, c, 0, 0, 0);
  return c;
}

// ---------------- kernel 1: all weight packing + cnt zero, one dispatch ----
// bid<4096: expert W1 hi/lo; <4224: expert W2 hi/lo; <4352: rp w1 3-plane;
// <4864: rp w2 3-plane; else zero cnt.
__global__ __launch_bounds__(256) void k_pack(const float* __restrict__ pw1,
    const float* __restrict__ pw2, const float* __restrict__ w1,
    const float* __restrict__ w2, unsigned short* __restrict__ p1,
    unsigned short* __restrict__ p2, unsigned short* __restrict__ w1p,
    unsigned short* __restrict__ w2p, int* __restrict__ cnt)
{
  int bid = blockIdx.x;
  if (bid < 4096){
    int t = bid*256 + threadIdx.x;
    int e = t >> 14, rem = t & 16383, kg = rem >> 8, n = rem & 255;
    const float* src = pw1 + ((size_t)e << 17) + (size_t)(kg*8)*256 + n;
    short8 h, l;
    #pragma unroll
    for (int j = 0; j < 8; j++){
      float w = src[(size_t)j*256];
      unsigned u = __float_as_uint(w);
      float r2 = w - __uint_as_float(u & 0xffff0000u);
      h[j] = (short)(u >> 16);
      l[j] = (short)(__float_as_uint(r2) >> 16);
    }
    int idx8 = ((((n >> 4)*16 + (kg >> 2))*64) + (kg & 3)*16 + (n & 15)) << 3;
    unsigned short* ep = p1 + (size_t)e * 262144;
    *(short8*)(ep + idx8)          = h;
    *(short8*)(ep + 131072 + idx8) = l;
  } else if (bid < 4224){
    int t = (bid - 4096)*256 + threadIdx.x;
    int e = t >> 9, rem = t & 511, kg = rem >> 4, n = rem & 15;
    const float* src = pw2 + (size_t)e*4096 + (size_t)(kg*8)*16 + n;
    short8 h, l;
    #pragma unroll
    for (int j = 0; j < 8; j++){
      float w = src[(size_t)j*16];
      unsigned u = __float_as_uint(w);
      float r2 = w - __uint_as_float(u & 0xffff0000u);
      h[j] = (short)(u >> 16);
      l[j] = (short)(__float_as_uint(r2) >> 16);
    }
    int idx8 = (((kg >> 2)*64) + (kg & 3)*16 + n) << 3;
    unsigned short* ep = p2 + (size_t)e * 8192;
    *(short8*)(ep + idx8)        = h;
    *(short8*)(ep + 4096 + idx8) = l;
  } else if (bid < 4352){
    int gid = (bid - 4224)*256 + threadIdx.x;   // total 32768, K=128, N=256
    int k = gid >> 8, n = gid & 255;
    short h, m, l;
    split3f(w1[gid], h, m, l);
    int idx = (((n >> 4)*4 + (k >> 5))*64 + (((k >> 3) & 3)*16 + (n & 15)))*8 + (k & 7);
    w1p[idx]             = (unsigned short)h;
    w1p[32768 + idx]     = (unsigned short)m;
    w1p[2*32768 + idx]   = (unsigned short)l;
  } else if (bid < 4864){
    int gid = (bid - 4352)*256 + threadIdx.x;   // total 131072, K=256, N=512
    int k = gid >> 9, n = gid & 511;
    short h, m, l;
    split3f(w2[gid], h, m, l);
    int idx = (((n >> 4)*8 + (k >> 5))*64 + (((k >> 3) & 3)*16 + (n & 15)))*8 + (k & 7);
    w2p[idx]             = (unsigned short)h;
    w2p[131072 + idx]    = (unsigned short)m;
    w2p[2*131072 + idx]  = (unsigned short)l;
  } else {
    if (threadIdx.x < 64) cnt[threadIdx.x] = 0;
  }
}

// ---------------- kernel 2: fused rp1 -> rp2 -> gate (row-local, 32 rows) --
// Dynamic LDS 64KB: phase A = [xs fp32 32x128 (16KB) | h 3-plane bf16 (48KB)],
// phase B overlay = feats fp32 32x512 (64KB).
__global__ __launch_bounds__(256) void k_fwd(const float* __restrict__ X,
    const unsigned short* __restrict__ w1p, const float* __restrict__ b1,
    const float* __restrict__ g1, const float* __restrict__ be1,
    const unsigned short* __restrict__ w2p, const float* __restrict__ b2,
    const float* __restrict__ g2, const float* __restrict__ be2,
    const float* __restrict__ opw, const float* __restrict__ opb,
    float* __restrict__ feats, float* __restrict__ dout,
    int* __restrict__ cnt, int* __restrict__ list)
{
  extern __shared__ unsigned char smem[];
  float*          xs = (float*)smem;                        // 32x128 swizzled
  unsigned short* hb = (unsigned short*)(smem + 16384);     // 3 planes 32x256
  float*          fsL = (float*)smem;                       // 32x512 overlay
  __shared__ float part[4][32][2];
  __shared__ float partg[4][32][64];                        // gate partials 32KB

  const int tid = threadIdx.x;
  const int r0  = blockIdx.x * 32;
  const int wave = tid >> 6, lane = tid & 63, lquad = lane >> 4, l15 = lane & 15;

  // ---- stage X
  for (int i = tid; i < 32*32; i += 256){
    int r = i >> 5, c4 = i & 31;
    float4 v = ((const float4*)X)[(size_t)(r0+r)*32 + c4];
    int off = r*128 + (((c4 >> 1) ^ (r & 7)) << 3) + ((c4 & 1) << 2);
    *(float4*)(xs + off) = v;
  }
  __syncthreads();

  // ---- GEMM1 (K=128) 6-pass
  {
    f32x4 acc[2][4];
    #pragma unroll
    for (int mt = 0; mt < 2; mt++)
      #pragma unroll
      for (int nt = 0; nt < 4; nt++) acc[mt][nt] = (f32x4){0.f,0.f,0.f,0.f};
    const int pstride = 32768;
    for (int ks4 = 0; ks4 < 4; ks4++){
      short8 ah[2], am[2], al[2];
      #pragma unroll
      for (int mt = 0; mt < 2; mt++){
        int r = mt*16 + l15;
        const float* ap = xs + r*128 + (((ks4*4 + lquad) ^ (r & 7)) << 3);
        float4 a0 = *(const float4*)ap;
        float4 a1 = *(const float4*)(ap + 4);
        float av[8] = {a0.x,a0.y,a0.z,a0.w,a1.x,a1.y,a1.z,a1.w};
        #pragma unroll
        for (int j = 0; j < 8; j++){
          short hh, mm2, ll;
          split3f(av[j], hh, mm2, ll);
          ah[mt][j] = hh; am[mt][j] = mm2; al[mt][j] = ll;
        }
      }
      #pragma unroll
      for (int nt = 0; nt < 4; nt++){
        int ntg = wave*4 + nt;
        const unsigned short* bp = w1p + (size_t)(((ntg*4 + ks4)*64 + lane)*8);
        short8 bh = *(const short8*)bp;
        short8 bm = *(const short8*)(bp + pstride);
        short8 bl = *(const short8*)(bp + 2*pstride);
        #pragma unroll
        for (int mt = 0; mt < 2; mt++)
          acc[mt][nt] = mfma6(ah[mt], am[mt], al[mt], bh, bm, bl, acc[mt][nt]);
      }
    }
    float bcol[4], gcol[4], becol[4];
    #pragma unroll
    for (int nt = 0; nt < 4; nt++){
      int col = (wave*4 + nt)*16 + l15;
      bcol[nt] = b1[col]; gcol[nt] = g1[col]; becol[nt] = be1[col];
    }
    #pragma unroll
    for (int mt = 0; mt < 2; mt++)
      #pragma unroll
      for (int reg = 0; reg < 4; reg++){
        float s = 0.f, q = 0.f;
        #pragma unroll
        for (int nt = 0; nt < 4; nt++){
          float z = acc[mt][nt][reg] + bcol[nt];
          s += z; q += z*z;
        }
        #pragma unroll
        for (int o = 1; o < 16; o <<= 1){ s += __shfl_xor(s, o, 64); q += __shfl_xor(q, o, 64); }
        int row = mt*16 + lquad*4 + reg;
        if (l15 == 0){ part[wave][row][0] = s; part[wave][row][1] = q; }
      }
    __syncthreads();
    #pragma unroll
    for (int mt = 0; mt < 2; mt++)
      #pragma unroll
      for (int reg = 0; reg < 4; reg++){
        int row = mt*16 + lquad*4 + reg;
        float s = part[0][row][0] + part[1][row][0] + part[2][row][0] + part[3][row][0];
        float q = part[0][row][1] + part[1][row][1] + part[2][row][1] + part[3][row][1];
        float mean = s * (1.0f/256.0f);
        float var  = q * (1.0f/256.0f) - mean*mean;
        float inv  = 1.0f / sqrtf(var + EPSv);
        #pragma unroll
        for (int nt = 0; nt < 4; nt++){
          int col = (wave*4 + nt)*16 + l15;
          float z = acc[mt][nt][reg] + bcol[nt];
          float y = fmaxf((z - mean)*inv*gcol[nt] + becol[nt], 0.f);
          short hh, mm2, ll;
          split3f(y, hh, mm2, ll);
          int gg = col >> 3, c7 = col & 7;
          int adr = row*256 + ((gg ^ (row & 7)) << 3) + c7;
          hb[adr]            = (unsigned short)hh;
          hb[8192 + adr]     = (unsigned short)mm2;
          hb[16384 + adr]    = (unsigned short)ll;
        }
      }
  }
  __syncthreads();

  // ---- GEMM2 (K=256, N=512) 6-pass
  f32x4 acc2[2][8];
  #pragma unroll
  for (int mt = 0; mt < 2; mt++)
    #pragma unroll
    for (int nt = 0; nt < 8; nt++) acc2[mt][nt] = (f32x4){0.f,0.f,0.f,0.f};
  {
    const int pstride = 131072;
    for (int ks4 = 0; ks4 < 8; ks4++){
      short8 ah[2], am[2], al[2];
      #pragma unroll
      for (int mt = 0; mt < 2; mt++){
        int r = mt*16 + l15;
        int goff = r*256 + (((ks4*4 + lquad) ^ (r & 7)) << 3);
        ah[mt] = *(const short8*)(hb + goff);
        am[mt] = *(const short8*)(hb + 8192 + goff);
        al[mt] = *(const short8*)(hb + 16384 + goff);
      }
      #pragma unroll
      for (int nt = 0; nt < 8; nt++){
        int ntg = wave*8 + nt;
        const unsigned short* bp = w2p + (size_t)(((ntg*8 + ks4)*64 + lane)*8);
        short8 bh = *(const short8*)bp;
        short8 bm = *(const short8*)(bp + pstride);
        short8 bl = *(const short8*)(bp + 2*pstride);
        #pragma unroll
        for (int mt = 0; mt < 2; mt++)
          acc2[mt][nt] = mfma6(ah[mt], am[mt], al[mt], bh, bm, bl, acc2[mt][nt]);
      }
    }
  }
  __syncthreads();   // all h-plane reads done; fsL overlay becomes safe

  {
    float bcol[8], gcol[8], becol[8];
    #pragma unroll
    for (int nt = 0; nt < 8; nt++){
      int col = (wave*8 + nt)*16 + l15;
      bcol[nt] = b2[col]; gcol[nt] = g2[col]; becol[nt] = be2[col];
    }
    #pragma unroll
    for (int mt = 0; mt < 2; mt++)
      #pragma unroll
      for (int reg = 0; reg < 4; reg++){
        float s = 0.f, q = 0.f;
        #pragma unroll
        for (int nt = 0; nt < 8; nt++){
          float z = acc2[mt][nt][reg] + bcol[nt];
          s += z; q += z*z;
        }
        #pragma unroll
        for (int o = 1; o < 16; o <<= 1){ s += __shfl_xor(s, o, 64); q += __shfl_xor(q, o, 64); }
        int row = mt*16 + lquad*4 + reg;
        if (l15 == 0){ part[wave][row][0] = s; part[wave][row][1] = q; }
      }
    __syncthreads();
    #pragma unroll
    for (int mt = 0; mt < 2; mt++)
      #pragma unroll
      for (int reg = 0; reg < 4; reg++){
        int row = mt*16 + lquad*4 + reg;
        float s = part[0][row][0] + part[1][row][0] + part[2][row][0] + part[3][row][0];
        float q = part[0][row][1] + part[1][row][1] + part[2][row][1] + part[3][row][1];
        float mean = s * (1.0f/512.0f);
        float var  = q * (1.0f/512.0f) - mean*mean;
        float inv  = 1.0f / sqrtf(var + EPSv);
        #pragma unroll
        for (int nt = 0; nt < 8; nt++){
          int col = (wave*8 + nt)*16 + l15;
          float z = acc2[mt][nt][reg] + bcol[nt];
          float y = fmaxf((z - mean)*inv*gcol[nt] + becol[nt], 0.f);
          fsL[row*512 + col] = y;
          feats[(size_t)(r0 + row)*512 + col] = y;
        }
      }
  }
  __syncthreads();

  // ---- gate: seg partials (exact old order), then softmax + top3
  {
    const int col = lane, seg = wave, kbase = seg*128;
    float accg[32];
    #pragma unroll
    for (int r = 0; r < 32; r++) accg[r] = 0.f;
    for (int k = kbase; k < kbase + 128; k++){
      float w = opw[k*64 + col];
      #pragma unroll
      for (int r = 0; r < 32; r++) accg[r] += fsL[r*512 + k] * w;
    }
    #pragma unroll
    for (int r = 0; r < 32; r++) partg[seg][r][col] = accg[r];
  }
  __syncthreads();
  {
    float bop = opb[lane];
    for (int rr = 0; rr < 8; rr++){
      int r = wave*8 + rr, row = r0 + r;
      float l = partg[0][r][lane] + partg[1][r][lane] + partg[2][r][lane]
              + partg[3][r][lane] + bop;
      float mx = l;
      #pragma unroll
      for (int o = 32; o; o >>= 1) mx = fmaxf(mx, __shfl_xor(mx, o, 64));
      float p = expf(l - mx);
      float s = wave_sum64(p);
      p /= s;
      float pv = p;
      for (int j = 0; j < 3; j++){
        float v = pv; int idx = lane;
        #pragma unroll
        for (int o = 32; o; o >>= 1){
          float ov = __shfl_xor(v, o, 64);
          int   oi = __shfl_xor(idx, o, 64);
          if (ov > v || (ov == v && oi < idx)){ v = ov; idx = oi; }
        }
        if (lane == 0){
          dout[(size_t)row*3 + j]                = v;
          dout[(size_t)Bv*3 + (size_t)row*3 + j] = (float)idx;
        }
        if (v >= CONFv){
          if (lane == 0){
            int pos = atomicAdd(&cnt[idx], 1);
            list[idx*Bv + pos] = (row << 2) | j;
          }
        } else {
          if (lane < 16) dout[(size_t)Bv*6 + (size_t)row*48 + j*16 + lane] = 0.f;
        }
        if (lane == idx) pv = -1.0f;
      }
    }
  }
}

// ---------------- kernel 3: expert MLP, packed-B MFMA ---------------------
__global__ __launch_bounds__(256) void k_expert(const float* __restrict__ F,
    const unsigned short* __restrict__ p1, const float* __restrict__ b1,
    const float* __restrict__ g,  const float* __restrict__ beta,
    const unsigned short* __restrict__ p2, const float* __restrict__ b2,
    const int* __restrict__ cnt,  const int* __restrict__ list,
    float* __restrict__ dout)
{
  extern __shared__ unsigned char smem[];
  unsigned short* xh = (unsigned short*)smem;
  unsigned short* xl = xh + 32*512;
  float*          zs = (float*)smem;
  unsigned short* zp = (unsigned short*)smem;
  __shared__ int sdesc[3];

  const int tid = threadIdx.x;
  const int wave = tid >> 6, lane = tid & 63;
  const int lquad = lane >> 4, l15 = lane & 15;

  if (wave == 0){
    int c  = cnt[lane];
    int tl = (c + 31) >> 5;
    int incl = tl;
    #pragma unroll
    for (int o = 1; o < 64; o <<= 1){
      int v = __shfl_up(incl, o, 64);
      if (lane >= o) incl += v;
    }
    int total = __shfl(incl, 63, 64);
    int G   = (total + 7) >> 3;
    int grp = blockIdx.x & 7, rr = blockIdx.x >> 3;
    int lgc = grp*G + rr;
    int ok  = (G > 0) && (rr < G) && (lgc < total);
    unsigned long long bm = __ballot(ok && (incl > lgc));
    if (lane == 0){
      if (!ok || bm == 0ull){ sdesc[0] = -1; }
      else {
        int e = __ffsll((long long)bm) - 1;
        sdesc[0] = e; sdesc[1] = lgc; sdesc[2] = 0;
      }
    }
    if (bm != 0ull && ok){
      int e = __ffsll((long long)bm) - 1;
      int excl = __shfl(incl - tl, e, 64);
      int ne   = __shfl(c, e, 64);
      if (lane == 0){ sdesc[1] = lgc - excl; sdesc[2] = ne; }
    }
  }
  __syncthreads();
  const int e = sdesc[0];
  if (e < 0) return;
  const int t = sdesc[1];
  const int n = sdesc[2];
  const int base = t * 32;
  const int m = min(32, n - base);
  const int* lrow = list + e*Bv + base;

  for (int i = tid; i < 32*128; i += 256){
    int r = i >> 7, c4 = i & 127;
    int ev = lrow[(r < m) ? r : 0];
    int row = ev >> 2;
    float4 v = ((const float4*)(F + (size_t)row*512))[c4];
    unsigned u0 = __float_as_uint(v.x), u1 = __float_as_uint(v.y);
    unsigned u2 = __float_as_uint(v.z), u3 = __float_as_uint(v.w);
    float l0f = v.x - __uint_as_float(u0 & 0xffff0000u);
    float l1f = v.y - __uint_as_float(u1 & 0xffff0000u);
    float l2f = v.z - __uint_as_float(u2 & 0xffff0000u);
    float l3f = v.w - __uint_as_float(u3 & 0xffff0000u);
    unsigned hpack0 = (u0 >> 16) | (u1 & 0xffff0000u);
    unsigned hpack1 = (u2 >> 16) | (u3 & 0xffff0000u);
    unsigned lpack0 = (__float_as_uint(l0f) >> 16) | (__float_as_uint(l1f) & 0xffff0000u);
    unsigned lpack1 = (__float_as_uint(l2f) >> 16) | (__float_as_uint(l3f) & 0xffff0000u);
    int gidx = c4 >> 1, half = c4 & 1;
    int off = r*512 + ((gidx ^ (r & 7)) << 3) + half*4;
    ((unsigned*)(xh + off))[0] = hpack0;
    ((unsigned*)(xh + off))[1] = hpack1;
    ((unsigned*)(xl + off))[0] = lpack0;
    ((unsigned*)(xl + off))[1] = lpack1;
  }
  __syncthreads();

  const unsigned short* p1e = p1 + (size_t)e * 262144;
  const int colbase = wave * 64;
  f32x4 acc[2][4];
  #pragma unroll
  for (int mt = 0; mt < 2; mt++)
    #pragma unroll
    for (int nt = 0; nt < 4; nt++) acc[mt][nt] = (f32x4){0.f,0.f,0.f,0.f};

  for (int kt = 0; kt < 16; kt++){
    short8 ah[2], al[2];
    int gk = kt*4 + lquad;
    #pragma unroll
    for (int mt = 0; mt < 2; mt++){
      int r = mt*16 + l15;
      int off = r*512 + ((gk ^ (r & 7)) << 3);
      ah[mt] = *(const short8*)(xh + off);
      al[mt] = *(const short8*)(xl + off);
    }
    #pragma unroll
    for (int nt = 0; nt < 4; nt++){
      int ntg = wave*4 + nt;
      const unsigned short* bp = p1e + (((ntg*16 + kt)*64 + lane) << 3);
      short8 bh = *(const short8*)bp;
      short8 bl = *(const short8*)(bp + 131072);
      #pragma unroll
      for (int mt = 0; mt < 2; mt++)
        acc[mt][nt] = mfma3(ah[mt], al[mt], bh, bl, acc[mt][nt]);
    }
  }
  __syncthreads();

  #pragma unroll
  for (int nt = 0; nt < 4; nt++){
    int col = colbase + nt*16 + l15;
    float bb = b1[e*256 + col];
    #pragma unroll
    for (int mt = 0; mt < 2; mt++)
      #pragma unroll
      for (int rg = 0; rg < 4; rg++){
        int rl = mt*16 + lquad*4 + rg;
        zs[rl*264 + col] = acc[mt][nt][rg] + bb;
      }
  }
  __syncthreads();

  {
    float gv[4], bv[4];
    #pragma unroll
    for (int j = 0; j < 4; j++){
      gv[j] = g[e*256 + lane + 64*j];
      bv[j] = beta[e*256 + lane + 64*j];
    }
    for (int rr2 = 0; rr2 < 8; rr2++){
      int r = wave*8 + rr2;
      float x[4];
      float s = 0.f;
      #pragma unroll
      for (int j = 0; j < 4; j++){ x[j] = zs[r*264 + lane + 64*j]; s += x[j]; }
      s = wave_sum64(s);
      float mm = s * (1.0f/256.0f);
      float v = 0.f;
      #pragma unroll
      for (int j = 0; j < 4; j++){ float d = x[j] - mm; v += d*d; }
      v = wave_sum64(v) * (1.0f/256.0f);
      float inv = 1.0f / sqrtf(v + EPSv);
      #pragma unroll
      for (int j = 0; j < 4; j++){
        int c = lane + 64*j;
        float y = fmaxf((x[j] - mm)*inv*gv[j] + bv[j], 0.f);
        unsigned u = __float_as_uint(y);
        float res = y - __uint_as_float(u & 0xffff0000u);
        zp[r*528 + c]       = (unsigned short)(u >> 16);
        zp[r*528 + 264 + c] = (unsigned short)(__float_as_uint(res) >> 16);
      }
    }
  }
  __syncthreads();

  if (wave < 2){
    const unsigned short* p2e = p2 + (size_t)e * 8192;
    f32x4 acc2 = (f32x4){0.f,0.f,0.f,0.f};
    for (int kt2 = 0; kt2 < 8; kt2++){
      const unsigned short* zb = zp + (wave*16 + l15)*528 + kt2*32 + lquad*8;
      short8 ahh = *(const short8*)zb;
      short8 all2 = *(const short8*)(zb + 264);
      const unsigned short* bp = p2e + ((kt2*64 + lane) << 3);
      short8 bh = *(const short8*)bp;
      short8 bl = *(const short8*)(bp + 4096);
      acc2 = mfma3(ahh, all2, bh, bl, acc2);
    }
    float b2v = b2[e*16 + l15];
    #pragma unroll
    for (int reg = 0; reg < 4; reg++){
      int rl = wave*16 + lquad*4 + reg;
      if (rl < m){
        int ev = lrow[rl];
        int row = ev >> 2, j = ev & 3;
        dout[(size_t)Bv*6 + (size_t)row*48 + j*16 + l15] = acc2[reg] + b2v;
      }
    }
  }
}

extern "C" void kernel_launch(void* const* d_in, const int* in_sizes, int n_in,
                              void* d_out, int out_size, void* d_ws, size_t ws_size,
                              hipStream_t stream)
{
  const float* X   = (const float*)d_in[0];
  const float* w1  = (const float*)d_in[1];
  const float* b1  = (const float*)d_in[2];
  const float* g1  = (const float*)d_in[3];
  const float* be1 = (const float*)d_in[4];
  const float* w2  = (const float*)d_in[5];
  const float* b2  = (const float*)d_in[6];
  const float* g2  = (const float*)d_in[7];
  const float* be2 = (const float*)d_in[8];
  const float* opw = (const float*)d_in[9];
  const float* opb = (const float*)d_in[10];
  const float* pw1 = (const float*)d_in[11];
  const float* pb1 = (const float*)d_in[12];
  const float* pg  = (const float*)d_in[13];
  const float* pbe = (const float*)d_in[14];
  const float* pw2 = (const float*)d_in[15];
  const float* pb2 = (const float*)d_in[16];
  float* out = (float*)d_out;
  char*  ws  = (char*)d_ws;

  // Workspace: p1E @0 (32MB), p2E @32MB (1MB), w1p_rp @33MB (196KB),
  // w2p_rp @34MB (786KB), feat @35MB (16MB), list @51MB (2MB), cnt @53MB.
  unsigned short* p1E    = (unsigned short*)ws;
  unsigned short* p2E    = (unsigned short*)(ws + (size_t)32*MB);
  unsigned short* w1p_rp = (unsigned short*)(ws + (size_t)33*MB);
  unsigned short* w2p_rp = (unsigned short*)(ws + (size_t)34*MB);
  float*          feat   = (float*)(ws + (size_t)35*MB);
  int*            list   = (int*)(ws + (size_t)51*MB);
  int*            cnt    = (int*)(ws + (size_t)53*MB);

  k_pack  <<<4865, 256, 0, stream>>>(pw1, pw2, w1, w2, p1E, p2E,
                                     w1p_rp, w2p_rp, cnt);
  k_fwd   <<<256,  256, 65536, stream>>>(X, w1p_rp, b1, g1, be1,
                                         w2p_rp, b2, g2, be2, opw, opb,
                                         feat, out, cnt, list);
  k_expert<<<832,  256, 65536, stream>>>(feat, p1E, pb1, pg, pbe, p2E, pb2,
                                         cnt, list, out);
}

// Round 6
// 215.258 us; speedup vs baseline: 1.0607x; 1.0607x over previous
//
#include <hip/hip_runtime.h>
#include <math.h>

#define Bv   8192
#define EPSv 1e-5f
#define CONFv 0.1f
#define MB (1024*1024)

typedef __attribute__((ext_vector_type(8))) short short8;
typedef __attribute__((ext_vector_type(4))) float f32x4;

__device__ __forceinline__ float wave_sum64(float v){
  #pragma unroll
  for (int o = 32; o; o >>= 1) v += __shfl_xor(v, o, 64);
  return v;
}

__device__ __forceinline__ void split3f(float x, short &h, short &m, short &l){
  unsigned u = __float_as_uint(x);
  h = (short)(u >> 16);
  float r1 = x - __uint_as_float(u & 0xffff0000u);
  unsigned u1 = __float_as_uint(r1);
  m = (short)(u1 >> 16);
  float r2 = r1 - __uint_as_float(u1 & 0xffff0000u);
  l = (short)(__float_as_uint(r2) >> 16);
}

__device__ __forceinline__ f32x4 mfma6(short8 ah, short8 am, short8 al,
                                       short8 bh, short8 bm, short8 bl, f32x4 c){
  c = __builtin_amdgcn_mfma_f32_16x16x32_bf16(al, bh, c, 0, 0, 0);
  c = __builtin_amdgcn_mfma_f32_16x16x32_bf16(ah, bl, c, 0, 0, 0);
  c = __builtin_amdgcn_mfma_f32_16x16x32_bf16(am, bm, c, 0, 0, 0);
  c = __builtin_amdgcn_mfma_f32_16x16x32_bf16(am, bh, c, 0, 0, 0);
  c = __builtin_amdgcn_mfma_f32_16x16x32_bf16(ah, bm, c, 0, 0, 0);
  c = __builtin_amdgcn_mfma_f32_16x16x32_bf16(ah, bh, c, 0, 0, 0);
  return c;
}

__device__ __forceinline__ f32x4 mfma3(short8 ah, short8 al,
                                       short8 bh, short8 bl, f32x4 c){
  c = __builtin_amdgcn_mfma_f32_16x16x32_bf16(al, bh, c, 0, 0, 0);
  c = __builtin_amdgcn_mfma_f32_16x16x32_bf16(ah, bl, c, 0, 0, 0);
  c = __builtin_amdgcn_mfma_f32_16x16x32_bf16(ah, bh, c, 0, 0, 0);
  return c;
}

// ---------------- kernel 1: all weight packing + cnt zero, one dispatch ----
__global__ __launch_bounds__(256) void k_pack(const float* __restrict__ pw1,
    const float* __restrict__ pw2, const float* __restrict__ w1,
    const float* __restrict__ w2, unsigned short* __restrict__ p1,
    unsigned short* __restrict__ p2, unsigned short* __restrict__ w1p,
    unsigned short* __restrict__ w2p, int* __restrict__ cnt)
{
  int bid = blockIdx.x;
  if (bid < 4096){
    int t = bid*256 + threadIdx.x;
    int e = t >> 14, rem = t & 16383, kg = rem >> 8, n = rem & 255;
    const float* src = pw1 + ((size_t)e << 17) + (size_t)(kg*8)*256 + n;
    short8 h, l;
    #pragma unroll
    for (int j = 0; j < 8; j++){
      float w = src[(size_t)j*256];
      unsigned u = __float_as_uint(w);
      float r2 = w - __uint_as_float(u & 0xffff0000u);
      h[j] = (short)(u >> 16);
      l[j] = (short)(__float_as_uint(r2) >> 16);
    }
    int idx8 = ((((n >> 4)*16 + (kg >> 2))*64) + (kg & 3)*16 + (n & 15)) << 3;
    unsigned short* ep = p1 + (size_t)e * 262144;
    *(short8*)(ep + idx8)          = h;
    *(short8*)(ep + 131072 + idx8) = l;
  } else if (bid < 4224){
    int t = (bid - 4096)*256 + threadIdx.x;
    int e = t >> 9, rem = t & 511, kg = rem >> 4, n = rem & 15;
    const float* src = pw2 + (size_t)e*4096 + (size_t)(kg*8)*16 + n;
    short8 h, l;
    #pragma unroll
    for (int j = 0; j < 8; j++){
      float w = src[(size_t)j*16];
      unsigned u = __float_as_uint(w);
      float r2 = w - __uint_as_float(u & 0xffff0000u);
      h[j] = (short)(u >> 16);
      l[j] = (short)(__float_as_uint(r2) >> 16);
    }
    int idx8 = (((kg >> 2)*64) + (kg & 3)*16 + n) << 3;
    unsigned short* ep = p2 + (size_t)e * 8192;
    *(short8*)(ep + idx8)        = h;
    *(short8*)(ep + 4096 + idx8) = l;
  } else if (bid < 4352){
    int gid = (bid - 4224)*256 + threadIdx.x;   // total 32768, K=128, N=256
    int k = gid >> 8, n = gid & 255;
    short h, m, l;
    split3f(w1[gid], h, m, l);
    int idx = (((n >> 4)*4 + (k >> 5))*64 + (((k >> 3) & 3)*16 + (n & 15)))*8 + (k & 7);
    w1p[idx]             = (unsigned short)h;
    w1p[32768 + idx]     = (unsigned short)m;
    w1p[2*32768 + idx]   = (unsigned short)l;
  } else if (bid < 4864){
    int gid = (bid - 4352)*256 + threadIdx.x;   // total 131072, K=256, N=512
    int k = gid >> 9, n = gid & 511;
    short h, m, l;
    split3f(w2[gid], h, m, l);
    int idx = (((n >> 4)*8 + (k >> 5))*64 + (((k >> 3) & 3)*16 + (n & 15)))*8 + (k & 7);
    w2p[idx]             = (unsigned short)h;
    w2p[131072 + idx]    = (unsigned short)m;
    w2p[2*131072 + idx]  = (unsigned short)l;
  } else {
    if (threadIdx.x < 64) cnt[threadIdx.x] = 0;
  }
}

// ---------------- kernel 2: fused rp1 -> rp2 -> gate, 16-row tiles --------
// grid 512, 256 threads. Dynamic LDS 32 KB: [xs fp32 16x128 (8K) | hb 3-plane
// bf16 16x256 (24K)]; fsL fp32 16x512 (32K) overlays after GEMM2.
// Static: partg 16 KB + part 0.5 KB -> ~49 KB total, 2 blocks/CU.
__global__ __launch_bounds__(256) void k_fused(const float* __restrict__ X,
    const unsigned short* __restrict__ w1p, const float* __restrict__ b1,
    const float* __restrict__ g1, const float* __restrict__ be1,
    const unsigned short* __restrict__ w2p, const float* __restrict__ b2,
    const float* __restrict__ g2, const float* __restrict__ be2,
    const float* __restrict__ opw, const float* __restrict__ opb,
    float* __restrict__ feats, float* __restrict__ dout,
    int* __restrict__ cnt, int* __restrict__ list)
{
  extern __shared__ unsigned char smem[];
  float*          xs  = (float*)smem;                       // 16x128 swizzled
  unsigned short* hb  = (unsigned short*)(smem + 8192);     // 3 planes 16x256
  float*          fsL = (float*)smem;                       // 16x512 overlay
  __shared__ float part[4][16][2];
  __shared__ float partg[4][16][64];

  const int tid = threadIdx.x;
  const int r0  = blockIdx.x * 16;
  const int wave = tid >> 6, lane = tid & 63, lquad = lane >> 4, l15 = lane & 15;

  // ---- stage X (16 rows x 128 cols)
  for (int i = tid; i < 16*32; i += 256){
    int r = i >> 5, c4 = i & 31;
    float4 v = ((const float4*)X)[(size_t)(r0+r)*32 + c4];
    int off = r*128 + (((c4 >> 1) ^ (r & 7)) << 3) + ((c4 & 1) << 2);
    *(float4*)(xs + off) = v;
  }
  __syncthreads();

  // ---- GEMM1 (M=16, N=256, K=128) 6-pass; wave owns 64 cols (4 ntiles)
  {
    f32x4 acc[4];
    #pragma unroll
    for (int nt = 0; nt < 4; nt++) acc[nt] = (f32x4){0.f,0.f,0.f,0.f};
    const int pstride = 32768;
    for (int ks4 = 0; ks4 < 4; ks4++){
      short8 ah, am, al;
      {
        int r = l15;
        const float* ap = xs + r*128 + (((ks4*4 + lquad) ^ (r & 7)) << 3);
        float4 a0 = *(const float4*)ap;
        float4 a1 = *(const float4*)(ap + 4);
        float av[8] = {a0.x,a0.y,a0.z,a0.w,a1.x,a1.y,a1.z,a1.w};
        #pragma unroll
        for (int j = 0; j < 8; j++){
          short hh, mm2, ll;
          split3f(av[j], hh, mm2, ll);
          ah[j] = hh; am[j] = mm2; al[j] = ll;
        }
      }
      #pragma unroll
      for (int nt = 0; nt < 4; nt++){
        int ntg = wave*4 + nt;
        const unsigned short* bp = w1p + (size_t)(((ntg*4 + ks4)*64 + lane)*8);
        short8 bh = *(const short8*)bp;
        short8 bm = *(const short8*)(bp + pstride);
        short8 bl = *(const short8*)(bp + 2*pstride);
        acc[nt] = mfma6(ah, am, al, bh, bm, bl, acc[nt]);
      }
    }
    float bcol[4], gcol[4], becol[4];
    #pragma unroll
    for (int nt = 0; nt < 4; nt++){
      int col = (wave*4 + nt)*16 + l15;
      bcol[nt] = b1[col]; gcol[nt] = g1[col]; becol[nt] = be1[col];
    }
    #pragma unroll
    for (int reg = 0; reg < 4; reg++){
      float s = 0.f, q = 0.f;
      #pragma unroll
      for (int nt = 0; nt < 4; nt++){
        float z = acc[nt][reg] + bcol[nt];
        s += z; q += z*z;
      }
      #pragma unroll
      for (int o = 1; o < 16; o <<= 1){ s += __shfl_xor(s, o, 64); q += __shfl_xor(q, o, 64); }
      int row = lquad*4 + reg;
      if (l15 == 0){ part[wave][row][0] = s; part[wave][row][1] = q; }
    }
    __syncthreads();
    #pragma unroll
    for (int reg = 0; reg < 4; reg++){
      int row = lquad*4 + reg;
      float s = part[0][row][0] + part[1][row][0] + part[2][row][0] + part[3][row][0];
      float q = part[0][row][1] + part[1][row][1] + part[2][row][1] + part[3][row][1];
      float mean = s * (1.0f/256.0f);
      float var  = q * (1.0f/256.0f) - mean*mean;
      float inv  = 1.0f / sqrtf(var + EPSv);
      #pragma unroll
      for (int nt = 0; nt < 4; nt++){
        int col = (wave*4 + nt)*16 + l15;
        float z = acc[nt][reg] + bcol[nt];
        float y = fmaxf((z - mean)*inv*gcol[nt] + becol[nt], 0.f);
        short hh, mm2, ll;
        split3f(y, hh, mm2, ll);
        int gg = col >> 3, c7 = col & 7;
        int adr = row*256 + ((gg ^ (row & 7)) << 3) + c7;
        hb[adr]         = (unsigned short)hh;
        hb[4096 + adr]  = (unsigned short)mm2;
        hb[8192 + adr]  = (unsigned short)ll;
      }
    }
  }
  __syncthreads();

  // ---- GEMM2 (M=16, N=512, K=256) 6-pass; wave owns 128 cols (8 ntiles)
  f32x4 acc2[8];
  #pragma unroll
  for (int nt = 0; nt < 8; nt++) acc2[nt] = (f32x4){0.f,0.f,0.f,0.f};
  {
    const int pstride = 131072;
    for (int ks4 = 0; ks4 < 8; ks4++){
      short8 ah, am, al;
      {
        int r = l15;
        int goff = r*256 + (((ks4*4 + lquad) ^ (r & 7)) << 3);
        ah = *(const short8*)(hb + goff);
        am = *(const short8*)(hb + 4096 + goff);
        al = *(const short8*)(hb + 8192 + goff);
      }
      #pragma unroll
      for (int nt = 0; nt < 8; nt++){
        int ntg = wave*8 + nt;
        const unsigned short* bp = w2p + (size_t)(((ntg*8 + ks4)*64 + lane)*8);
        short8 bh = *(const short8*)bp;
        short8 bm = *(const short8*)(bp + pstride);
        short8 bl = *(const short8*)(bp + 2*pstride);
        acc2[nt] = mfma6(ah, am, al, bh, bm, bl, acc2[nt]);
      }
    }
  }

  // ---- LN2 + ReLU -> feats (global) + fsL (LDS overlay)
  {
    float bcol[8], gcol[8], becol[8];
    #pragma unroll
    for (int nt = 0; nt < 8; nt++){
      int col = (wave*8 + nt)*16 + l15;
      bcol[nt] = b2[col]; gcol[nt] = g2[col]; becol[nt] = be2[col];
    }
    #pragma unroll
    for (int reg = 0; reg < 4; reg++){
      float s = 0.f, q = 0.f;
      #pragma unroll
      for (int nt = 0; nt < 8; nt++){
        float z = acc2[nt][reg] + bcol[nt];
        s += z; q += z*z;
      }
      #pragma unroll
      for (int o = 1; o < 16; o <<= 1){ s += __shfl_xor(s, o, 64); q += __shfl_xor(q, o, 64); }
      int row = lquad*4 + reg;
      if (l15 == 0){ part[wave][row][0] = s; part[wave][row][1] = q; }
    }
    __syncthreads();   // also: all hb reads done -> fsL overlay safe
    #pragma unroll
    for (int reg = 0; reg < 4; reg++){
      int row = lquad*4 + reg;
      float s = part[0][row][0] + part[1][row][0] + part[2][row][0] + part[3][row][0];
      float q = part[0][row][1] + part[1][row][1] + part[2][row][1] + part[3][row][1];
      float mean = s * (1.0f/512.0f);
      float var  = q * (1.0f/512.0f) - mean*mean;
      float inv  = 1.0f / sqrtf(var + EPSv);
      #pragma unroll
      for (int nt = 0; nt < 8; nt++){
        int col = (wave*8 + nt)*16 + l15;
        float z = acc2[nt][reg] + bcol[nt];
        float y = fmaxf((z - mean)*inv*gcol[nt] + becol[nt], 0.f);
        fsL[row*512 + col] = y;
        feats[(size_t)(r0 + row)*512 + col] = y;
      }
    }
  }
  __syncthreads();

  // ---- gate: seg partials (exact R4 operand order), softmax + top3
  {
    const int col = lane, seg = wave, kbase = seg*128;
    float accg[16];
    #pragma unroll
    for (int r = 0; r < 16; r++) accg[r] = 0.f;
    for (int k = kbase; k < kbase + 128; k++){
      float w = opw[k*64 + col];
      #pragma unroll
      for (int r = 0; r < 16; r++) accg[r] += fsL[r*512 + k] * w;
    }
    #pragma unroll
    for (int r = 0; r < 16; r++) partg[seg][r][col] = accg[r];
  }
  __syncthreads();
  {
    float bop = opb[lane];
    for (int rr = 0; rr < 4; rr++){
      int r = wave*4 + rr, row = r0 + r;
      float l = partg[0][r][lane] + partg[1][r][lane] + partg[2][r][lane]
              + partg[3][r][lane] + bop;
      float mx = l;
      #pragma unroll
      for (int o = 32; o; o >>= 1) mx = fmaxf(mx, __shfl_xor(mx, o, 64));
      float p = expf(l - mx);
      float s = wave_sum64(p);
      p /= s;
      float pv = p;
      for (int j = 0; j < 3; j++){
        float v = pv; int idx = lane;
        #pragma unroll
        for (int o = 32; o; o >>= 1){
          float ov = __shfl_xor(v, o, 64);
          int   oi = __shfl_xor(idx, o, 64);
          if (ov > v || (ov == v && oi < idx)){ v = ov; idx = oi; }
        }
        if (lane == 0){
          dout[(size_t)row*3 + j]                = v;
          dout[(size_t)Bv*3 + (size_t)row*3 + j] = (float)idx;
        }
        if (v >= CONFv){
          if (lane == 0){
            int pos = atomicAdd(&cnt[idx], 1);
            list[idx*Bv + pos] = (row << 2) | j;
          }
        } else {
          if (lane < 16) dout[(size_t)Bv*6 + (size_t)row*48 + j*16 + lane] = 0.f;
        }
        if (lane == idx) pv = -1.0f;
      }
    }
  }
}

// ---------------- kernel 3: expert MLP, packed-B MFMA ---------------------
__global__ __launch_bounds__(256) void k_expert(const float* __restrict__ F,
    const unsigned short* __restrict__ p1, const float* __restrict__ b1,
    const float* __restrict__ g,  const float* __restrict__ beta,
    const unsigned short* __restrict__ p2, const float* __restrict__ b2,
    const int* __restrict__ cnt,  const int* __restrict__ list,
    float* __restrict__ dout)
{
  extern __shared__ unsigned char smem[];
  unsigned short* xh = (unsigned short*)smem;
  unsigned short* xl = xh + 32*512;
  float*          zs = (float*)smem;
  unsigned short* zp = (unsigned short*)smem;
  __shared__ int sdesc[3];

  const int tid = threadIdx.x;
  const int wave = tid >> 6, lane = tid & 63;
  const int lquad = lane >> 4, l15 = lane & 15;

  if (wave == 0){
    int c  = cnt[lane];
    int tl = (c + 31) >> 5;
    int incl = tl;
    #pragma unroll
    for (int o = 1; o < 64; o <<= 1){
      int v = __shfl_up(incl, o, 64);
      if (lane >= o) incl += v;
    }
    int total = __shfl(incl, 63, 64);
    int G   = (total + 7) >> 3;
    int grp = blockIdx.x & 7, rr = blockIdx.x >> 3;
    int lgc = grp*G + rr;
    int ok  = (G > 0) && (rr < G) && (lgc < total);
    unsigned long long bm = __ballot(ok && (incl > lgc));
    if (lane == 0){
      if (!ok || bm == 0ull){ sdesc[0] = -1; }
      else {
        int e = __ffsll((long long)bm) - 1;
        sdesc[0] = e; sdesc[1] = lgc; sdesc[2] = 0;
      }
    }
    if (bm != 0ull && ok){
      int e = __ffsll((long long)bm) - 1;
      int excl = __shfl(incl - tl, e, 64);
      int ne   = __shfl(c, e, 64);
      if (lane == 0){ sdesc[1] = lgc - excl; sdesc[2] = ne; }
    }
  }
  __syncthreads();
  const int e = sdesc[0];
  if (e < 0) return;
  const int t = sdesc[1];
  const int n = sdesc[2];
  const int base = t * 32;
  const int m = min(32, n - base);
  const int* lrow = list + e*Bv + base;

  for (int i = tid; i < 32*128; i += 256){
    int r = i >> 7, c4 = i & 127;
    int ev = lrow[(r < m) ? r : 0];
    int row = ev >> 2;
    float4 v = ((const float4*)(F + (size_t)row*512))[c4];
    unsigned u0 = __float_as_uint(v.x), u1 = __float_as_uint(v.y);
    unsigned u2 = __float_as_uint(v.z), u3 = __float_as_uint(v.w);
    float l0f = v.x - __uint_as_float(u0 & 0xffff0000u);
    float l1f = v.y - __uint_as_float(u1 & 0xffff0000u);
    float l2f = v.z - __uint_as_float(u2 & 0xffff0000u);
    float l3f = v.w - __uint_as_float(u3 & 0xffff0000u);
    unsigned hpack0 = (u0 >> 16) | (u1 & 0xffff0000u);
    unsigned hpack1 = (u2 >> 16) | (u3 & 0xffff0000u);
    unsigned lpack0 = (__float_as_uint(l0f) >> 16) | (__float_as_uint(l1f) & 0xffff0000u);
    unsigned lpack1 = (__float_as_uint(l2f) >> 16) | (__float_as_uint(l3f) & 0xffff0000u);
    int gidx = c4 >> 1, half = c4 & 1;
    int off = r*512 + ((gidx ^ (r & 7)) << 3) + half*4;
    ((unsigned*)(xh + off))[0] = hpack0;
    ((unsigned*)(xh + off))[1] = hpack1;
    ((unsigned*)(xl + off))[0] = lpack0;
    ((unsigned*)(xl + off))[1] = lpack1;
  }
  __syncthreads();

  const unsigned short* p1e = p1 + (size_t)e * 262144;
  const int colbase = wave * 64;
  f32x4 acc[2][4];
  #pragma unroll
  for (int mt = 0; mt < 2; mt++)
    #pragma unroll
    for (int nt = 0; nt < 4; nt++) acc[mt][nt] = (f32x4){0.f,0.f,0.f,0.f};

  for (int kt = 0; kt < 16; kt++){
    short8 ah[2], al[2];
    int gk = kt*4 + lquad;
    #pragma unroll
    for (int mt = 0; mt < 2; mt++){
      int r = mt*16 + l15;
      int off = r*512 + ((gk ^ (r & 7)) << 3);
      ah[mt] = *(const short8*)(xh + off);
      al[mt] = *(const short8*)(xl + off);
    }
    #pragma unroll
    for (int nt = 0; nt < 4; nt++){
      int ntg = wave*4 + nt;
      const unsigned short* bp = p1e + (((ntg*16 + kt)*64 + lane) << 3);
      short8 bh = *(const short8*)bp;
      short8 bl = *(const short8*)(bp + 131072);
      #pragma unroll
      for (int mt = 0; mt < 2; mt++)
        acc[mt][nt] = mfma3(ah[mt], al[mt], bh, bl, acc[mt][nt]);
    }
  }
  __syncthreads();

  #pragma unroll
  for (int nt = 0; nt < 4; nt++){
    int col = colbase + nt*16 + l15;
    float bb = b1[e*256 + col];
    #pragma unroll
    for (int mt = 0; mt < 2; mt++)
      #pragma unroll
      for (int rg = 0; rg < 4; rg++){
        int rl = mt*16 + lquad*4 + rg;
        zs[rl*264 + col] = acc[mt][nt][rg] + bb;
      }
  }
  __syncthreads();

  {
    float gv[4], bv[4];
    #pragma unroll
    for (int j = 0; j < 4; j++){
      gv[j] = g[e*256 + lane + 64*j];
      bv[j] = beta[e*256 + lane + 64*j];
    }
    for (int rr2 = 0; rr2 < 8; rr2++){
      int r = wave*8 + rr2;
      float x[4];
      float s = 0.f;
      #pragma unroll
      for (int j = 0; j < 4; j++){ x[j] = zs[r*264 + lane + 64*j]; s += x[j]; }
      s = wave_sum64(s);
      float mm = s * (1.0f/256.0f);
      float v = 0.f;
      #pragma unroll
      for (int j = 0; j < 4; j++){ float d = x[j] - mm; v += d*d; }
      v = wave_sum64(v) * (1.0f/256.0f);
      float inv = 1.0f / sqrtf(v + EPSv);
      #pragma unroll
      for (int j = 0; j < 4; j++){
        int c = lane + 64*j;
        float y = fmaxf((x[j] - mm)*inv*gv[j] + bv[j], 0.f);
        unsigned u = __float_as_uint(y);
        float res = y - __uint_as_float(u & 0xffff0000u);
        zp[r*528 + c]       = (unsigned short)(u >> 16);
        zp[r*528 + 264 + c] = (unsigned short)(__float_as_uint(res) >> 16);
      }
    }
  }
  __syncthreads();

  if (wave < 2){
    const unsigned short* p2e = p2 + (size_t)e * 8192;
    f32x4 acc2 = (f32x4){0.f,0.f,0.f,0.f};
    for (int kt2 = 0; kt2 < 8; kt2++){
      const unsigned short* zb = zp + (wave*16 + l15)*528 + kt2*32 + lquad*8;
      short8 ahh = *(const short8*)zb;
      short8 all2 = *(const short8*)(zb + 264);
      const unsigned short* bp = p2e + ((kt2*64 + lane) << 3);
      short8 bh = *(const short8*)bp;
      short8 bl = *(const short8*)(bp + 4096);
      acc2 = mfma3(ahh, all2, bh, bl, acc2);
    }
    float b2v = b2[e*16 + l15];
    #pragma unroll
    for (int reg = 0; reg < 4; reg++){
      int rl = wave*16 + lquad*4 + reg;
      if (rl < m){
        int ev = lrow[rl];
        int row = ev >> 2, j = ev & 3;
        dout[(size_t)Bv*6 + (size_t)row*48 + j*16 + l15] = acc2[reg] + b2v;
      }
    }
  }
}

extern "C" void kernel_launch(void* const* d_in, const int* in_sizes, int n_in,
                              void* d_out, int out_size, void* d_ws, size_t ws_size,
                              hipStream_t stream)
{
  const float* X   = (const float*)d_in[0];
  const float* w1  = (const float*)d_in[1];
  const float* b1  = (const float*)d_in[2];
  const float* g1  = (const float*)d_in[3];
  const float* be1 = (const float*)d_in[4];
  const float* w2  = (const float*)d_in[5];
  const float* b2  = (const float*)d_in[6];
  const float* g2  = (const float*)d_in[7];
  const float* be2 = (const float*)d_in[8];
  const float* opw = (const float*)d_in[9];
  const float* opb = (const float*)d_in[10];
  const float* pw1 = (const float*)d_in[11];
  const float* pb1 = (const float*)d_in[12];
  const float* pg  = (const float*)d_in[13];
  const float* pbe = (const float*)d_in[14];
  const float* pw2 = (const float*)d_in[15];
  const float* pb2 = (const float*)d_in[16];
  float* out = (float*)d_out;
  char*  ws  = (char*)d_ws;

  // Workspace: p1E @0 (32MB), p2E @32MB (1MB), w1p_rp @33MB (196KB),
  // w2p_rp @34MB (786KB), feat @35MB (16MB), list @51MB (2MB), cnt @53MB.
  unsigned short* p1E    = (unsigned short*)ws;
  unsigned short* p2E    = (unsigned short*)(ws + (size_t)32*MB);
  unsigned short* w1p_rp = (unsigned short*)(ws + (size_t)33*MB);
  unsigned short* w2p_rp = (unsigned short*)(ws + (size_t)34*MB);
  float*          feat   = (float*)(ws + (size_t)35*MB);
  int*            list   = (int*)(ws + (size_t)51*MB);
  int*            cnt    = (int*)(ws + (size_t)53*MB);

  k_pack  <<<4865, 256, 0, stream>>>(pw1, pw2, w1, w2, p1E, p2E,
                                     w1p_rp, w2p_rp, cnt);
  k_fused <<<512,  256, 32768, stream>>>(X, w1p_rp, b1, g1, be1,
                                         w2p_rp, b2, g2, be2, opw, opb,
                                         feat, out, cnt, list);
  k_expert<<<832,  256, 65536, stream>>>(feat, p1E, pb1, pg, pbe, p2E, pb2,
                                         cnt, list, out);
}

// Round 7
// 201.187 us; speedup vs baseline: 1.1348x; 1.0699x over previous
//
#include <hip/hip_runtime.h>
#include <math.h>

#define Bv   8192
#define EPSv 1e-5f
#define CONFv 0.1f
#define MB (1024*1024)

typedef __attribute__((ext_vector_type(8))) short short8;
typedef __attribute__((ext_vector_type(4))) float f32x4;

__device__ __forceinline__ float wave_sum64(float v){
  #pragma unroll
  for (int o = 32; o; o >>= 1) v += __shfl_xor(v, o, 64);
  return v;
}

__device__ __forceinline__ void split3f(float x, short &h, short &m, short &l){
  unsigned u = __float_as_uint(x);
  h = (short)(u >> 16);
  float r1 = x - __uint_as_float(u & 0xffff0000u);
  unsigned u1 = __float_as_uint(r1);
  m = (short)(u1 >> 16);
  float r2 = r1 - __uint_as_float(u1 & 0xffff0000u);
  l = (short)(__float_as_uint(r2) >> 16);
}

__device__ __forceinline__ f32x4 mfma6(short8 ah, short8 am, short8 al,
                                       short8 bh, short8 bm, short8 bl, f32x4 c){
  c = __builtin_amdgcn_mfma_f32_16x16x32_bf16(al, bh, c, 0, 0, 0);
  c = __builtin_amdgcn_mfma_f32_16x16x32_bf16(ah, bl, c, 0, 0, 0);
  c = __builtin_amdgcn_mfma_f32_16x16x32_bf16(am, bm, c, 0, 0, 0);
  c = __builtin_amdgcn_mfma_f32_16x16x32_bf16(am, bh, c, 0, 0, 0);
  c = __builtin_amdgcn_mfma_f32_16x16x32_bf16(ah, bm, c, 0, 0, 0);
  c = __builtin_amdgcn_mfma_f32_16x16x32_bf16(ah, bh, c, 0, 0, 0);
  return c;
}

__device__ __forceinline__ f32x4 mfma3(short8 ah, short8 al,
                                       short8 bh, short8 bl, f32x4 c){
  c = __builtin_amdgcn_mfma_f32_16x16x32_bf16(al, bh, c, 0, 0, 0);
  c = __builtin_amdgcn_mfma_f32_16x16x32_bf16(ah, bl, c, 0, 0, 0);
  c = __builtin_amdgcn_mfma_f32_16x16x32_bf16(ah, bh, c, 0, 0, 0);
  return c;
}

// ---------------- kernel 1: all weight packing + cnt zero, one dispatch ----
__global__ __launch_bounds__(256) void k_pack(const float* __restrict__ pw1,
    const float* __restrict__ pw2, const float* __restrict__ w1,
    const float* __restrict__ w2, const float* __restrict__ opw,
    unsigned short* __restrict__ p1, unsigned short* __restrict__ p2,
    unsigned short* __restrict__ w1p, unsigned short* __restrict__ w2p,
    unsigned short* __restrict__ opwp, int* __restrict__ cnt)
{
  int bid = blockIdx.x;
  if (bid < 4096){
    int t = bid*256 + threadIdx.x;
    int e = t >> 14, rem = t & 16383, kg = rem >> 8, n = rem & 255;
    const float* src = pw1 + ((size_t)e << 17) + (size_t)(kg*8)*256 + n;
    short8 h, l;
    #pragma unroll
    for (int j = 0; j < 8; j++){
      float w = src[(size_t)j*256];
      unsigned u = __float_as_uint(w);
      float r2 = w - __uint_as_float(u & 0xffff0000u);
      h[j] = (short)(u >> 16);
      l[j] = (short)(__float_as_uint(r2) >> 16);
    }
    int idx8 = ((((n >> 4)*16 + (kg >> 2))*64) + (kg & 3)*16 + (n & 15)) << 3;
    unsigned short* ep = p1 + (size_t)e * 262144;
    *(short8*)(ep + idx8)          = h;
    *(short8*)(ep + 131072 + idx8) = l;
  } else if (bid < 4224){
    int t = (bid - 4096)*256 + threadIdx.x;
    int e = t >> 9, rem = t & 511, kg = rem >> 4, n = rem & 15;
    const float* src = pw2 + (size_t)e*4096 + (size_t)(kg*8)*16 + n;
    short8 h, l;
    #pragma unroll
    for (int j = 0; j < 8; j++){
      float w = src[(size_t)j*16];
      unsigned u = __float_as_uint(w);
      float r2 = w - __uint_as_float(u & 0xffff0000u);
      h[j] = (short)(u >> 16);
      l[j] = (short)(__float_as_uint(r2) >> 16);
    }
    int idx8 = (((kg >> 2)*64) + (kg & 3)*16 + n) << 3;
    unsigned short* ep = p2 + (size_t)e * 8192;
    *(short8*)(ep + idx8)        = h;
    *(short8*)(ep + 4096 + idx8) = l;
  } else if (bid < 4352){
    int gid = (bid - 4224)*256 + threadIdx.x;   // 32768, K=128, N=256
    int k = gid >> 8, n = gid & 255;
    short h, m, l;
    split3f(w1[gid], h, m, l);
    int idx = (((n >> 4)*4 + (k >> 5))*64 + (((k >> 3) & 3)*16 + (n & 15)))*8 + (k & 7);
    w1p[idx]             = (unsigned short)h;
    w1p[32768 + idx]     = (unsigned short)m;
    w1p[2*32768 + idx]   = (unsigned short)l;
  } else if (bid < 4864){
    int gid = (bid - 4352)*256 + threadIdx.x;   // 131072, K=256, N=512
    int k = gid >> 9, n = gid & 511;
    short h, m, l;
    split3f(w2[gid], h, m, l);
    int idx = (((n >> 4)*8 + (k >> 5))*64 + (((k >> 3) & 3)*16 + (n & 15)))*8 + (k & 7);
    w2p[idx]             = (unsigned short)h;
    w2p[131072 + idx]    = (unsigned short)m;
    w2p[2*131072 + idx]  = (unsigned short)l;
  } else if (bid < 4992){
    int gid = (bid - 4864)*256 + threadIdx.x;   // 32768, K=512, N=64
    int k = gid >> 6, n = gid & 63;
    short h, m, l;
    split3f(opw[gid], h, m, l);
    int idx = (((n >> 4)*16 + (k >> 5))*64 + (((k >> 3) & 3)*16 + (n & 15)))*8 + (k & 7);
    opwp[idx]            = (unsigned short)h;
    opwp[32768 + idx]    = (unsigned short)m;
    opwp[2*32768 + idx]  = (unsigned short)l;
  } else {
    if (threadIdx.x < 64) cnt[threadIdx.x] = 0;
  }
}

// ---------------- kernel 2: fused rp1 -> rp2 -> gate(MFMA), 16-row tiles --
// Dynamic LDS 48KB: phase A [xs fp32 16x128 (8K) | hb 3-plane 16x256 (24K)];
// phase B overlay: ga 3-plane bf16 16x512 (48K). Static: part + lg ~4.6KB.
__global__ __launch_bounds__(256) void k_fused(const float* __restrict__ X,
    const unsigned short* __restrict__ w1p, const float* __restrict__ b1,
    const float* __restrict__ g1, const float* __restrict__ be1,
    const unsigned short* __restrict__ w2p, const float* __restrict__ b2,
    const float* __restrict__ g2, const float* __restrict__ be2,
    const unsigned short* __restrict__ opwp, const float* __restrict__ opb,
    unsigned short* __restrict__ fh, unsigned short* __restrict__ fl,
    float* __restrict__ dout, int* __restrict__ cnt, int* __restrict__ list)
{
  extern __shared__ unsigned char smem[];
  float*          xs = (float*)smem;                       // 16x128 swizzled
  unsigned short* hb = (unsigned short*)(smem + 8192);     // 3 planes 16x256
  unsigned short* ga = (unsigned short*)smem;              // 3 planes 16x512 overlay
  __shared__ float part[4][16][2];
  __shared__ float lg[16][64];

  const int tid = threadIdx.x;
  const int r0  = blockIdx.x * 16;
  const int wave = tid >> 6, lane = tid & 63, lquad = lane >> 4, l15 = lane & 15;

  // ---- stage X (16 rows x 128 cols)
  for (int i = tid; i < 16*32; i += 256){
    int r = i >> 5, c4 = i & 31;
    float4 v = ((const float4*)X)[(size_t)(r0+r)*32 + c4];
    int off = r*128 + (((c4 >> 1) ^ (r & 7)) << 3) + ((c4 & 1) << 2);
    *(float4*)(xs + off) = v;
  }
  __syncthreads();

  // ---- GEMM1 (M=16, N=256, K=128) 6-pass
  {
    f32x4 acc[4];
    #pragma unroll
    for (int nt = 0; nt < 4; nt++) acc[nt] = (f32x4){0.f,0.f,0.f,0.f};
    const int pstride = 32768;
    for (int ks4 = 0; ks4 < 4; ks4++){
      short8 ah, am, al;
      {
        int r = l15;
        const float* ap = xs + r*128 + (((ks4*4 + lquad) ^ (r & 7)) << 3);
        float4 a0 = *(const float4*)ap;
        float4 a1 = *(const float4*)(ap + 4);
        float av[8] = {a0.x,a0.y,a0.z,a0.w,a1.x,a1.y,a1.z,a1.w};
        #pragma unroll
        for (int j = 0; j < 8; j++){
          short hh, mm2, ll;
          split3f(av[j], hh, mm2, ll);
          ah[j] = hh; am[j] = mm2; al[j] = ll;
        }
      }
      #pragma unroll
      for (int nt = 0; nt < 4; nt++){
        int ntg = wave*4 + nt;
        const unsigned short* bp = w1p + (size_t)(((ntg*4 + ks4)*64 + lane)*8);
        short8 bh = *(const short8*)bp;
        short8 bm = *(const short8*)(bp + pstride);
        short8 bl = *(const short8*)(bp + 2*pstride);
        acc[nt] = mfma6(ah, am, al, bh, bm, bl, acc[nt]);
      }
    }
    float bcol[4], gcol[4], becol[4];
    #pragma unroll
    for (int nt = 0; nt < 4; nt++){
      int col = (wave*4 + nt)*16 + l15;
      bcol[nt] = b1[col]; gcol[nt] = g1[col]; becol[nt] = be1[col];
    }
    #pragma unroll
    for (int reg = 0; reg < 4; reg++){
      float s = 0.f, q = 0.f;
      #pragma unroll
      for (int nt = 0; nt < 4; nt++){
        float z = acc[nt][reg] + bcol[nt];
        s += z; q += z*z;
      }
      #pragma unroll
      for (int o = 1; o < 16; o <<= 1){ s += __shfl_xor(s, o, 64); q += __shfl_xor(q, o, 64); }
      int row = lquad*4 + reg;
      if (l15 == 0){ part[wave][row][0] = s; part[wave][row][1] = q; }
    }
    __syncthreads();
    #pragma unroll
    for (int reg = 0; reg < 4; reg++){
      int row = lquad*4 + reg;
      float s = part[0][row][0] + part[1][row][0] + part[2][row][0] + part[3][row][0];
      float q = part[0][row][1] + part[1][row][1] + part[2][row][1] + part[3][row][1];
      float mean = s * (1.0f/256.0f);
      float var  = q * (1.0f/256.0f) - mean*mean;
      float inv  = 1.0f / sqrtf(var + EPSv);
      #pragma unroll
      for (int nt = 0; nt < 4; nt++){
        int col = (wave*4 + nt)*16 + l15;
        float z = acc[nt][reg] + bcol[nt];
        float y = fmaxf((z - mean)*inv*gcol[nt] + becol[nt], 0.f);
        short hh, mm2, ll;
        split3f(y, hh, mm2, ll);
        int gg = col >> 3, c7 = col & 7;
        int adr = row*256 + ((gg ^ (row & 7)) << 3) + c7;
        hb[adr]         = (unsigned short)hh;
        hb[4096 + adr]  = (unsigned short)mm2;
        hb[8192 + adr]  = (unsigned short)ll;
      }
    }
  }
  __syncthreads();

  // ---- GEMM2 (M=16, N=512, K=256) 6-pass
  f32x4 acc2[8];
  #pragma unroll
  for (int nt = 0; nt < 8; nt++) acc2[nt] = (f32x4){0.f,0.f,0.f,0.f};
  {
    const int pstride = 131072;
    for (int ks4 = 0; ks4 < 8; ks4++){
      short8 ah, am, al;
      {
        int r = l15;
        int goff = r*256 + (((ks4*4 + lquad) ^ (r & 7)) << 3);
        ah = *(const short8*)(hb + goff);
        am = *(const short8*)(hb + 4096 + goff);
        al = *(const short8*)(hb + 8192 + goff);
      }
      #pragma unroll
      for (int nt = 0; nt < 8; nt++){
        int ntg = wave*8 + nt;
        const unsigned short* bp = w2p + (size_t)(((ntg*8 + ks4)*64 + lane)*8);
        short8 bh = *(const short8*)bp;
        short8 bm = *(const short8*)(bp + pstride);
        short8 bl = *(const short8*)(bp + 2*pstride);
        acc2[nt] = mfma6(ah, am, al, bh, bm, bl, acc2[nt]);
      }
    }
  }

  // ---- LN2 partials
  float bcol[8], gcol[8], becol[8];
  #pragma unroll
  for (int nt = 0; nt < 8; nt++){
    int col = (wave*8 + nt)*16 + l15;
    bcol[nt] = b2[col]; gcol[nt] = g2[col]; becol[nt] = be2[col];
  }
  #pragma unroll
  for (int reg = 0; reg < 4; reg++){
    float s = 0.f, q = 0.f;
    #pragma unroll
    for (int nt = 0; nt < 8; nt++){
      float z = acc2[nt][reg] + bcol[nt];
      s += z; q += z*z;
    }
    #pragma unroll
    for (int o = 1; o < 16; o <<= 1){ s += __shfl_xor(s, o, 64); q += __shfl_xor(q, o, 64); }
    int row = lquad*4 + reg;
    if (l15 == 0){ part[wave][row][0] = s; part[wave][row][1] = q; }
  }
  __syncthreads();   // all hb reads done -> ga overlay safe after this

  // ---- LN2 finalize -> ga 3-plane bf16 (swizzled A layout)
  #pragma unroll
  for (int reg = 0; reg < 4; reg++){
    int row = lquad*4 + reg;
    float s = part[0][row][0] + part[1][row][0] + part[2][row][0] + part[3][row][0];
    float q = part[0][row][1] + part[1][row][1] + part[2][row][1] + part[3][row][1];
    float mean = s * (1.0f/512.0f);
    float var  = q * (1.0f/512.0f) - mean*mean;
    float inv  = 1.0f / sqrtf(var + EPSv);
    #pragma unroll
    for (int nt = 0; nt < 8; nt++){
      int col = (wave*8 + nt)*16 + l15;
      float z = acc2[nt][reg] + bcol[nt];
      float y = fmaxf((z - mean)*inv*gcol[nt] + becol[nt], 0.f);
      short hh, mm2, ll;
      split3f(y, hh, mm2, ll);
      int gg = col >> 3, c7 = col & 7;
      int adr = row*512 + ((gg ^ (row & 7)) << 3) + c7;
      ga[adr]          = (unsigned short)hh;
      ga[8192 + adr]   = (unsigned short)mm2;
      ga[16384 + adr]  = (unsigned short)ll;
    }
  }
  __syncthreads();

  // ---- gate GEMM (M=16, N=64, K=512) 6-pass; wave owns 16 experts
  {
    f32x4 accg = (f32x4){0.f,0.f,0.f,0.f};
    for (int kt = 0; kt < 16; kt++){
      int r = l15;
      int off = r*512 + (((kt*4 + lquad) ^ (r & 7)) << 3);
      short8 ah = *(const short8*)(ga + off);
      short8 am = *(const short8*)(ga + 8192 + off);
      short8 al = *(const short8*)(ga + 16384 + off);
      const unsigned short* bp = opwp + (((wave*16 + kt)*64 + lane) << 3);
      short8 bh = *(const short8*)bp;
      short8 bm = *(const short8*)(bp + 32768);
      short8 bl = *(const short8*)(bp + 65536);
      accg = mfma6(ah, am, al, bh, bm, bl, accg);
    }
    float opbv = opb[wave*16 + l15];
    #pragma unroll
    for (int reg = 0; reg < 4; reg++)
      lg[lquad*4 + reg][wave*16 + l15] = accg[reg] + opbv;
  }

  // ---- export feats hi/lo planes to global (b128, de-swizzled)
  for (int i = tid; i < 2048; i += 256){
    int p = i >> 10, rem = i & 1023, r = rem >> 6, gg = rem & 63;
    short8 v = *(const short8*)(ga + p*8192 + r*512 + ((gg ^ (r & 7)) << 3));
    unsigned short* dst = (p ? fl : fh) + (size_t)(r0 + r)*512 + gg*8;
    *(short8*)dst = v;
  }
  __syncthreads();

  // ---- softmax + top3 (same shuffle scheme as before)
  {
    for (int rr = 0; rr < 4; rr++){
      int r = wave*4 + rr, row = r0 + r;
      float l = lg[r][lane];
      float mx = l;
      #pragma unroll
      for (int o = 32; o; o >>= 1) mx = fmaxf(mx, __shfl_xor(mx, o, 64));
      float p = expf(l - mx);
      float s = wave_sum64(p);
      p /= s;
      float pv = p;
      for (int j = 0; j < 3; j++){
        float v = pv; int idx = lane;
        #pragma unroll
        for (int o = 32; o; o >>= 1){
          float ov = __shfl_xor(v, o, 64);
          int   oi = __shfl_xor(idx, o, 64);
          if (ov > v || (ov == v && oi < idx)){ v = ov; idx = oi; }
        }
        if (lane == 0){
          dout[(size_t)row*3 + j]                = v;
          dout[(size_t)Bv*3 + (size_t)row*3 + j] = (float)idx;
        }
        if (v >= CONFv){
          if (lane == 0){
            int pos = atomicAdd(&cnt[idx], 1);
            list[idx*Bv + pos] = (row << 2) | j;
          }
        } else {
          if (lane < 16) dout[(size_t)Bv*6 + (size_t)row*48 + j*16 + lane] = 0.f;
        }
        if (lane == idx) pv = -1.0f;
      }
    }
  }
}

// ---------------- kernel 3: expert MLP, packed-B MFMA, pre-split feats ----
__global__ __launch_bounds__(256) void k_expert(const unsigned short* __restrict__ fh,
    const unsigned short* __restrict__ fl,
    const unsigned short* __restrict__ p1, const float* __restrict__ b1,
    const float* __restrict__ g,  const float* __restrict__ beta,
    const unsigned short* __restrict__ p2, const float* __restrict__ b2,
    const int* __restrict__ cnt,  const int* __restrict__ list,
    float* __restrict__ dout)
{
  extern __shared__ unsigned char smem[];
  unsigned short* xh = (unsigned short*)smem;
  unsigned short* xl = xh + 32*512;
  float*          zs = (float*)smem;
  unsigned short* zp = (unsigned short*)smem;
  __shared__ int sdesc[3];

  const int tid = threadIdx.x;
  const int wave = tid >> 6, lane = tid & 63;
  const int lquad = lane >> 4, l15 = lane & 15;

  if (wave == 0){
    int c  = cnt[lane];
    int tl = (c + 31) >> 5;
    int incl = tl;
    #pragma unroll
    for (int o = 1; o < 64; o <<= 1){
      int v = __shfl_up(incl, o, 64);
      if (lane >= o) incl += v;
    }
    int total = __shfl(incl, 63, 64);
    int G   = (total + 7) >> 3;
    int grp = blockIdx.x & 7, rr = blockIdx.x >> 3;
    int lgc = grp*G + rr;
    int ok  = (G > 0) && (rr < G) && (lgc < total);
    unsigned long long bm = __ballot(ok && (incl > lgc));
    if (lane == 0){
      if (!ok || bm == 0ull){ sdesc[0] = -1; }
      else {
        int e = __ffsll((long long)bm) - 1;
        sdesc[0] = e; sdesc[1] = lgc; sdesc[2] = 0;
      }
    }
    if (bm != 0ull && ok){
      int e = __ffsll((long long)bm) - 1;
      int excl = __shfl(incl - tl, e, 64);
      int ne   = __shfl(c, e, 64);
      if (lane == 0){ sdesc[1] = lgc - excl; sdesc[2] = ne; }
    }
  }
  __syncthreads();
  const int e = sdesc[0];
  if (e < 0) return;
  const int t = sdesc[1];
  const int n = sdesc[2];
  const int base = t * 32;
  const int m = min(32, n - base);
  const int* lrow = list + e*Bv + base;

  // ---- stage feats hi/lo planes -> swizzled LDS (pure copy)
  for (int i = tid; i < 4096; i += 256){
    int p = i >> 11, rem = i & 2047, r = rem >> 6, gg = rem & 63;
    int ev = lrow[(r < m) ? r : 0];
    int row = ev >> 2;
    const unsigned short* src = (p ? fl : fh) + (size_t)row*512 + gg*8;
    short8 v = *(const short8*)src;
    unsigned short* dst = (p ? xl : xh) + r*512 + ((gg ^ (r & 7)) << 3);
    *(short8*)dst = v;
  }
  __syncthreads();

  const unsigned short* p1e = p1 + (size_t)e * 262144;
  const int colbase = wave * 64;
  f32x4 acc[2][4];
  #pragma unroll
  for (int mt = 0; mt < 2; mt++)
    #pragma unroll
    for (int nt = 0; nt < 4; nt++) acc[mt][nt] = (f32x4){0.f,0.f,0.f,0.f};

  for (int kt = 0; kt < 16; kt++){
    short8 ah[2], al[2];
    int gk = kt*4 + lquad;
    #pragma unroll
    for (int mt = 0; mt < 2; mt++){
      int r = mt*16 + l15;
      int off = r*512 + ((gk ^ (r & 7)) << 3);
      ah[mt] = *(const short8*)(xh + off);
      al[mt] = *(const short8*)(xl + off);
    }
    #pragma unroll
    for (int nt = 0; nt < 4; nt++){
      int ntg = wave*4 + nt;
      const unsigned short* bp = p1e + (((ntg*16 + kt)*64 + lane) << 3);
      short8 bh = *(const short8*)bp;
      short8 bl = *(const short8*)(bp + 131072);
      #pragma unroll
      for (int mt = 0; mt < 2; mt++)
        acc[mt][nt] = mfma3(ah[mt], al[mt], bh, bl, acc[mt][nt]);
    }
  }
  __syncthreads();

  #pragma unroll
  for (int nt = 0; nt < 4; nt++){
    int col = colbase + nt*16 + l15;
    float bb = b1[e*256 + col];
    #pragma unroll
    for (int mt = 0; mt < 2; mt++)
      #pragma unroll
      for (int rg = 0; rg < 4; rg++){
        int rl = mt*16 + lquad*4 + rg;
        zs[rl*264 + col] = acc[mt][nt][rg] + bb;
      }
  }
  __syncthreads();

  {
    float gv[4], bv[4];
    #pragma unroll
    for (int j = 0; j < 4; j++){
      gv[j] = g[e*256 + lane + 64*j];
      bv[j] = beta[e*256 + lane + 64*j];
    }
    for (int rr2 = 0; rr2 < 8; rr2++){
      int r = wave*8 + rr2;
      float x[4];
      float s = 0.f;
      #pragma unroll
      for (int j = 0; j < 4; j++){ x[j] = zs[r*264 + lane + 64*j]; s += x[j]; }
      s = wave_sum64(s);
      float mm = s * (1.0f/256.0f);
      float v = 0.f;
      #pragma unroll
      for (int j = 0; j < 4; j++){ float d = x[j] - mm; v += d*d; }
      v = wave_sum64(v) * (1.0f/256.0f);
      float inv = 1.0f / sqrtf(v + EPSv);
      #pragma unroll
      for (int j = 0; j < 4; j++){
        int c = lane + 64*j;
        float y = fmaxf((x[j] - mm)*inv*gv[j] + bv[j], 0.f);
        unsigned u = __float_as_uint(y);
        float res = y - __uint_as_float(u & 0xffff0000u);
        zp[r*528 + c]       = (unsigned short)(u >> 16);
        zp[r*528 + 264 + c] = (unsigned short)(__float_as_uint(res) >> 16);
      }
    }
  }
  __syncthreads();

  if (wave < 2){
    const unsigned short* p2e = p2 + (size_t)e * 8192;
    f32x4 acc2 = (f32x4){0.f,0.f,0.f,0.f};
    for (int kt2 = 0; kt2 < 8; kt2++){
      const unsigned short* zb = zp + (wave*16 + l15)*528 + kt2*32 + lquad*8;
      short8 ahh = *(const short8*)zb;
      short8 all2 = *(const short8*)(zb + 264);
      const unsigned short* bp = p2e + ((kt2*64 + lane) << 3);
      short8 bh = *(const short8*)bp;
      short8 bl = *(const short8*)(bp + 4096);
      acc2 = mfma3(ahh, all2, bh, bl, acc2);
    }
    float b2v = b2[e*16 + l15];
    #pragma unroll
    for (int reg = 0; reg < 4; reg++){
      int rl = wave*16 + lquad*4 + reg;
      if (rl < m){
        int ev = lrow[rl];
        int row = ev >> 2, j = ev & 3;
        dout[(size_t)Bv*6 + (size_t)row*48 + j*16 + l15] = acc2[reg] + b2v;
      }
    }
  }
}

extern "C" void kernel_launch(void* const* d_in, const int* in_sizes, int n_in,
                              void* d_out, int out_size, void* d_ws, size_t ws_size,
                              hipStream_t stream)
{
  const float* X   = (const float*)d_in[0];
  const float* w1  = (const float*)d_in[1];
  const float* b1  = (const float*)d_in[2];
  const float* g1  = (const float*)d_in[3];
  const float* be1 = (const float*)d_in[4];
  const float* w2  = (const float*)d_in[5];
  const float* b2  = (const float*)d_in[6];
  const float* g2  = (const float*)d_in[7];
  const float* be2 = (const float*)d_in[8];
  const float* opw = (const float*)d_in[9];
  const float* opb = (const float*)d_in[10];
  const float* pw1 = (const float*)d_in[11];
  const float* pb1 = (const float*)d_in[12];
  const float* pg  = (const float*)d_in[13];
  const float* pbe = (const float*)d_in[14];
  const float* pw2 = (const float*)d_in[15];
  const float* pb2 = (const float*)d_in[16];
  float* out = (float*)d_out;
  char*  ws  = (char*)d_ws;

  // Workspace: p1E @0 (32MB), p2E @32MB (1MB), w1p_rp @33MB, w2p_rp @34MB,
  // opwp @35MB, fh @36MB (8MB), fl @44MB (8MB), list @52MB (2MB), cnt @54MB.
  unsigned short* p1E    = (unsigned short*)ws;
  unsigned short* p2E    = (unsigned short*)(ws + (size_t)32*MB);
  unsigned short* w1p_rp = (unsigned short*)(ws + (size_t)33*MB);
  unsigned short* w2p_rp = (unsigned short*)(ws + (size_t)34*MB);
  unsigned short* opwp   = (unsigned short*)(ws + (size_t)35*MB);
  unsigned short* fh     = (unsigned short*)(ws + (size_t)36*MB);
  unsigned short* fl     = (unsigned short*)(ws + (size_t)44*MB);
  int*            list   = (int*)(ws + (size_t)52*MB);
  int*            cnt    = (int*)(ws + (size_t)54*MB);

  k_pack  <<<4993, 256, 0, stream>>>(pw1, pw2, w1, w2, opw, p1E, p2E,
                                     w1p_rp, w2p_rp, opwp, cnt);
  k_fused <<<512,  256, 49152, stream>>>(X, w1p_rp, b1, g1, be1,
                                         w2p_rp, b2, g2, be2, opwp, opb,
                                         fh, fl, out, cnt, list);
  k_expert<<<832,  256, 65536, stream>>>(fh, fl, p1E, pb1, pg, pbe, p2E, pb2,
                                         cnt, list, out);
}

// Round 8
// 183.076 us; speedup vs baseline: 1.2471x; 1.0989x over previous
//
#include <hip/hip_runtime.h>
#include <math.h>

#define Bv   8192
#define EPSv 1e-5f
#define CONFv 0.1f
#define MB (1024*1024)

typedef __attribute__((ext_vector_type(8))) short short8;
typedef __attribute__((ext_vector_type(4))) float f32x4;

__device__ __forceinline__ float wave_sum64(float v){
  #pragma unroll
  for (int o = 32; o; o >>= 1) v += __shfl_xor(v, o, 64);
  return v;
}

__device__ __forceinline__ void split3f(float x, short &h, short &m, short &l){
  unsigned u = __float_as_uint(x);
  h = (short)(u >> 16);
  float r1 = x - __uint_as_float(u & 0xffff0000u);
  unsigned u1 = __float_as_uint(r1);
  m = (short)(u1 >> 16);
  float r2 = r1 - __uint_as_float(u1 & 0xffff0000u);
  l = (short)(__float_as_uint(r2) >> 16);
}

__device__ __forceinline__ f32x4 mfma6(short8 ah, short8 am, short8 al,
                                       short8 bh, short8 bm, short8 bl, f32x4 c){
  c = __builtin_amdgcn_mfma_f32_16x16x32_bf16(al, bh, c, 0, 0, 0);
  c = __builtin_amdgcn_mfma_f32_16x16x32_bf16(ah, bl, c, 0, 0, 0);
  c = __builtin_amdgcn_mfma_f32_16x16x32_bf16(am, bm, c, 0, 0, 0);
  c = __builtin_amdgcn_mfma_f32_16x16x32_bf16(am, bh, c, 0, 0, 0);
  c = __builtin_amdgcn_mfma_f32_16x16x32_bf16(ah, bm, c, 0, 0, 0);
  c = __builtin_amdgcn_mfma_f32_16x16x32_bf16(ah, bh, c, 0, 0, 0);
  return c;
}

// 5-pass: A 2-plane (h,m) x B 3-plane; drops am*bl (2^-40) and al*bh (2^-24).
__device__ __forceinline__ f32x4 mfma5(short8 ah, short8 am,
                                       short8 bh, short8 bm, short8 bl, f32x4 c){
  c = __builtin_amdgcn_mfma_f32_16x16x32_bf16(am, bm, c, 0, 0, 0);
  c = __builtin_amdgcn_mfma_f32_16x16x32_bf16(ah, bl, c, 0, 0, 0);
  c = __builtin_amdgcn_mfma_f32_16x16x32_bf16(am, bh, c, 0, 0, 0);
  c = __builtin_amdgcn_mfma_f32_16x16x32_bf16(ah, bm, c, 0, 0, 0);
  c = __builtin_amdgcn_mfma_f32_16x16x32_bf16(ah, bh, c, 0, 0, 0);
  return c;
}

__device__ __forceinline__ f32x4 mfma3(short8 ah, short8 al,
                                       short8 bh, short8 bl, f32x4 c){
  c = __builtin_amdgcn_mfma_f32_16x16x32_bf16(al, bh, c, 0, 0, 0);
  c = __builtin_amdgcn_mfma_f32_16x16x32_bf16(ah, bl, c, 0, 0, 0);
  c = __builtin_amdgcn_mfma_f32_16x16x32_bf16(ah, bh, c, 0, 0, 0);
  return c;
}

// ---------------- kernel 1: all weight packing + cnt zero, one dispatch ----
__global__ __launch_bounds__(256) void k_pack(const float* __restrict__ pw1,
    const float* __restrict__ pw2, const float* __restrict__ w1,
    const float* __restrict__ w2, const float* __restrict__ opw,
    unsigned short* __restrict__ p1, unsigned short* __restrict__ p2,
    unsigned short* __restrict__ w1p, unsigned short* __restrict__ w2p,
    unsigned short* __restrict__ opwp, int* __restrict__ cnt)
{
  int bid = blockIdx.x;
  if (bid < 4096){
    int t = bid*256 + threadIdx.x;
    int e = t >> 14, rem = t & 16383, kg = rem >> 8, n = rem & 255;
    const float* src = pw1 + ((size_t)e << 17) + (size_t)(kg*8)*256 + n;
    short8 h, l;
    #pragma unroll
    for (int j = 0; j < 8; j++){
      float w = src[(size_t)j*256];
      unsigned u = __float_as_uint(w);
      float r2 = w - __uint_as_float(u & 0xffff0000u);
      h[j] = (short)(u >> 16);
      l[j] = (short)(__float_as_uint(r2) >> 16);
    }
    int idx8 = ((((n >> 4)*16 + (kg >> 2))*64) + (kg & 3)*16 + (n & 15)) << 3;
    unsigned short* ep = p1 + (size_t)e * 262144;
    *(short8*)(ep + idx8)          = h;
    *(short8*)(ep + 131072 + idx8) = l;
  } else if (bid < 4224){
    int t = (bid - 4096)*256 + threadIdx.x;
    int e = t >> 9, rem = t & 511, kg = rem >> 4, n = rem & 15;
    const float* src = pw2 + (size_t)e*4096 + (size_t)(kg*8)*16 + n;
    short8 h, l;
    #pragma unroll
    for (int j = 0; j < 8; j++){
      float w = src[(size_t)j*16];
      unsigned u = __float_as_uint(w);
      float r2 = w - __uint_as_float(u & 0xffff0000u);
      h[j] = (short)(u >> 16);
      l[j] = (short)(__float_as_uint(r2) >> 16);
    }
    int idx8 = (((kg >> 2)*64) + (kg & 3)*16 + n) << 3;
    unsigned short* ep = p2 + (size_t)e * 8192;
    *(short8*)(ep + idx8)        = h;
    *(short8*)(ep + 4096 + idx8) = l;
  } else if (bid < 4352){
    int gid = (bid - 4224)*256 + threadIdx.x;   // 32768, K=128, N=256
    int k = gid >> 8, n = gid & 255;
    short h, m, l;
    split3f(w1[gid], h, m, l);
    int idx = (((n >> 4)*4 + (k >> 5))*64 + (((k >> 3) & 3)*16 + (n & 15)))*8 + (k & 7);
    w1p[idx]             = (unsigned short)h;
    w1p[32768 + idx]     = (unsigned short)m;
    w1p[2*32768 + idx]   = (unsigned short)l;
  } else if (bid < 4864){
    int gid = (bid - 4352)*256 + threadIdx.x;   // 131072, K=256, N=512
    int k = gid >> 9, n = gid & 511;
    short h, m, l;
    split3f(w2[gid], h, m, l);
    int idx = (((n >> 4)*8 + (k >> 5))*64 + (((k >> 3) & 3)*16 + (n & 15)))*8 + (k & 7);
    w2p[idx]             = (unsigned short)h;
    w2p[131072 + idx]    = (unsigned short)m;
    w2p[2*131072 + idx]  = (unsigned short)l;
  } else if (bid < 4992){
    int gid = (bid - 4864)*256 + threadIdx.x;   // 32768, K=512, N=64
    int k = gid >> 6, n = gid & 63;
    short h, m, l;
    split3f(opw[gid], h, m, l);
    int idx = (((n >> 4)*16 + (k >> 5))*64 + (((k >> 3) & 3)*16 + (n & 15)))*8 + (k & 7);
    opwp[idx]            = (unsigned short)h;
    opwp[32768 + idx]    = (unsigned short)m;
    opwp[2*32768 + idx]  = (unsigned short)l;
  } else {
    if (threadIdx.x < 64) cnt[threadIdx.x] = 0;
  }
}

// ---------------- kernel 2: fused rp1->rp2->gate, M=32, 512 threads -------
// Dynamic LDS 64KB: phase A [xs fp32 32x128 (16K) | hb 3-plane 32x256 (48K)];
// phase B overlay: ga 2-plane bf16 32x512 (64K). Static: part 2K + lg 8K.
__global__ __launch_bounds__(512) void k_fused(const float* __restrict__ X,
    const unsigned short* __restrict__ w1p, const float* __restrict__ b1,
    const float* __restrict__ g1, const float* __restrict__ be1,
    const unsigned short* __restrict__ w2p, const float* __restrict__ b2,
    const float* __restrict__ g2, const float* __restrict__ be2,
    const unsigned short* __restrict__ opwp, const float* __restrict__ opb,
    unsigned short* __restrict__ fh, unsigned short* __restrict__ fl,
    float* __restrict__ dout, int* __restrict__ cnt, int* __restrict__ list)
{
  extern __shared__ unsigned char smem[];
  float*          xs = (float*)smem;                       // 32x128 swizzled
  unsigned short* hb = (unsigned short*)(smem + 16384);    // 3 planes 32x256
  unsigned short* ga = (unsigned short*)smem;              // 2 planes 32x512 overlay
  __shared__ float part[8][32][2];
  __shared__ float lg[32][64];

  const int tid = threadIdx.x;
  const int r0  = blockIdx.x * 32;
  const int wave = tid >> 6, lane = tid & 63, lquad = lane >> 4, l15 = lane & 15;

  // ---- stage X (32 rows x 128 cols)
  for (int i = tid; i < 32*32; i += 512){
    int r = i >> 5, c4 = i & 31;
    float4 v = ((const float4*)X)[(size_t)(r0+r)*32 + c4];
    int off = r*128 + (((c4 >> 1) ^ (r & 7)) << 3) + ((c4 & 1) << 2);
    *(float4*)(xs + off) = v;
  }
  __syncthreads();

  // ---- GEMM1 (M=32, N=256, K=128) 6-pass; wave owns 32 cols (2 ntiles)
  {
    f32x4 acc[2][2];
    #pragma unroll
    for (int mt = 0; mt < 2; mt++)
      #pragma unroll
      for (int nt = 0; nt < 2; nt++) acc[mt][nt] = (f32x4){0.f,0.f,0.f,0.f};
    const int pstride = 32768;
    for (int ks4 = 0; ks4 < 4; ks4++){
      short8 ah[2], am[2], al[2];
      #pragma unroll
      for (int mt = 0; mt < 2; mt++){
        int r = mt*16 + l15;
        const float* ap = xs + r*128 + (((ks4*4 + lquad) ^ (r & 7)) << 3);
        float4 a0 = *(const float4*)ap;
        float4 a1 = *(const float4*)(ap + 4);
        float av[8] = {a0.x,a0.y,a0.z,a0.w,a1.x,a1.y,a1.z,a1.w};
        #pragma unroll
        for (int j = 0; j < 8; j++){
          short hh, mm2, ll;
          split3f(av[j], hh, mm2, ll);
          ah[mt][j] = hh; am[mt][j] = mm2; al[mt][j] = ll;
        }
      }
      #pragma unroll
      for (int nt = 0; nt < 2; nt++){
        int ntg = wave*2 + nt;
        const unsigned short* bp = w1p + (size_t)(((ntg*4 + ks4)*64 + lane)*8);
        short8 bh = *(const short8*)bp;
        short8 bm = *(const short8*)(bp + pstride);
        short8 bl = *(const short8*)(bp + 2*pstride);
        #pragma unroll
        for (int mt = 0; mt < 2; mt++)
          acc[mt][nt] = mfma6(ah[mt], am[mt], al[mt], bh, bm, bl, acc[mt][nt]);
      }
    }
    float bcol[2], gcol[2], becol[2];
    #pragma unroll
    for (int nt = 0; nt < 2; nt++){
      int col = (wave*2 + nt)*16 + l15;
      bcol[nt] = b1[col]; gcol[nt] = g1[col]; becol[nt] = be1[col];
    }
    #pragma unroll
    for (int mt = 0; mt < 2; mt++)
      #pragma unroll
      for (int reg = 0; reg < 4; reg++){
        float s = 0.f, q = 0.f;
        #pragma unroll
        for (int nt = 0; nt < 2; nt++){
          float z = acc[mt][nt][reg] + bcol[nt];
          s += z; q += z*z;
        }
        #pragma unroll
        for (int o = 1; o < 16; o <<= 1){ s += __shfl_xor(s, o, 64); q += __shfl_xor(q, o, 64); }
        int row = mt*16 + lquad*4 + reg;
        if (l15 == 0){ part[wave][row][0] = s; part[wave][row][1] = q; }
      }
    __syncthreads();
    #pragma unroll
    for (int mt = 0; mt < 2; mt++)
      #pragma unroll
      for (int reg = 0; reg < 4; reg++){
        int row = mt*16 + lquad*4 + reg;
        float s = 0.f, q = 0.f;
        #pragma unroll
        for (int w8 = 0; w8 < 8; w8++){ s += part[w8][row][0]; q += part[w8][row][1]; }
        float mean = s * (1.0f/256.0f);
        float var  = q * (1.0f/256.0f) - mean*mean;
        float inv  = 1.0f / sqrtf(var + EPSv);
        #pragma unroll
        for (int nt = 0; nt < 2; nt++){
          int col = (wave*2 + nt)*16 + l15;
          float z = acc[mt][nt][reg] + bcol[nt];
          float y = fmaxf((z - mean)*inv*gcol[nt] + becol[nt], 0.f);
          short hh, mm2, ll;
          split3f(y, hh, mm2, ll);
          int gg = col >> 3, c7 = col & 7;
          int adr = row*256 + ((gg ^ (row & 7)) << 3) + c7;
          hb[adr]         = (unsigned short)hh;
          hb[8192 + adr]  = (unsigned short)mm2;
          hb[16384 + adr] = (unsigned short)ll;
        }
      }
  }
  __syncthreads();

  // ---- GEMM2 (M=32, N=512, K=256) 6-pass; wave owns 64 cols (4 ntiles)
  f32x4 acc2[2][4];
  #pragma unroll
  for (int mt = 0; mt < 2; mt++)
    #pragma unroll
    for (int nt = 0; nt < 4; nt++) acc2[mt][nt] = (f32x4){0.f,0.f,0.f,0.f};
  {
    const int pstride = 131072;
    for (int ks4 = 0; ks4 < 8; ks4++){
      short8 ah[2], am[2], al[2];
      #pragma unroll
      for (int mt = 0; mt < 2; mt++){
        int r = mt*16 + l15;
        int goff = r*256 + (((ks4*4 + lquad) ^ (r & 7)) << 3);
        ah[mt] = *(const short8*)(hb + goff);
        am[mt] = *(const short8*)(hb + 8192 + goff);
        al[mt] = *(const short8*)(hb + 16384 + goff);
      }
      #pragma unroll
      for (int nt = 0; nt < 4; nt++){
        int ntg = wave*4 + nt;
        const unsigned short* bp = w2p + (size_t)(((ntg*8 + ks4)*64 + lane)*8);
        short8 bh = *(const short8*)bp;
        short8 bm = *(const short8*)(bp + pstride);
        short8 bl = *(const short8*)(bp + 2*pstride);
        #pragma unroll
        for (int mt = 0; mt < 2; mt++)
          acc2[mt][nt] = mfma6(ah[mt], am[mt], al[mt], bh, bm, bl, acc2[mt][nt]);
      }
    }
  }

  // ---- LN2 partials
  float bcol[4], gcol[4], becol[4];
  #pragma unroll
  for (int nt = 0; nt < 4; nt++){
    int col = (wave*4 + nt)*16 + l15;
    bcol[nt] = b2[col]; gcol[nt] = g2[col]; becol[nt] = be2[col];
  }
  #pragma unroll
  for (int mt = 0; mt < 2; mt++)
    #pragma unroll
    for (int reg = 0; reg < 4; reg++){
      float s = 0.f, q = 0.f;
      #pragma unroll
      for (int nt = 0; nt < 4; nt++){
        float z = acc2[mt][nt][reg] + bcol[nt];
        s += z; q += z*z;
      }
      #pragma unroll
      for (int o = 1; o < 16; o <<= 1){ s += __shfl_xor(s, o, 64); q += __shfl_xor(q, o, 64); }
      int row = mt*16 + lquad*4 + reg;
      if (l15 == 0){ part[wave][row][0] = s; part[wave][row][1] = q; }
    }
  __syncthreads();   // all hb reads done -> ga overlay safe after this

  // ---- LN2 finalize -> ga 2-plane bf16 (swizzled A layout)
  #pragma unroll
  for (int mt = 0; mt < 2; mt++)
    #pragma unroll
    for (int reg = 0; reg < 4; reg++){
      int row = mt*16 + lquad*4 + reg;
      float s = 0.f, q = 0.f;
      #pragma unroll
      for (int w8 = 0; w8 < 8; w8++){ s += part[w8][row][0]; q += part[w8][row][1]; }
      float mean = s * (1.0f/512.0f);
      float var  = q * (1.0f/512.0f) - mean*mean;
      float inv  = 1.0f / sqrtf(var + EPSv);
      #pragma unroll
      for (int nt = 0; nt < 4; nt++){
        int col = (wave*4 + nt)*16 + l15;
        float z = acc2[mt][nt][reg] + bcol[nt];
        float y = fmaxf((z - mean)*inv*gcol[nt] + becol[nt], 0.f);
        short hh, mm2, ll;
        split3f(y, hh, mm2, ll);
        int gg = col >> 3, c7 = col & 7;
        int adr = row*512 + ((gg ^ (row & 7)) << 3) + c7;
        ga[adr]          = (unsigned short)hh;
        ga[16384 + adr]  = (unsigned short)mm2;
      }
    }
  __syncthreads();

  // ---- waves 0-3: gate GEMM (M=32, N=64, K=512) 5-pass, 16 experts each
  //      waves 4-7: export feats hi/lo planes to global concurrently
  if (wave < 4){
    f32x4 accg[2];
    accg[0] = (f32x4){0.f,0.f,0.f,0.f};
    accg[1] = (f32x4){0.f,0.f,0.f,0.f};
    for (int kt = 0; kt < 16; kt++){
      const unsigned short* bp = opwp + (((wave*16 + kt)*64 + lane) << 3);
      short8 bh = *(const short8*)bp;
      short8 bm = *(const short8*)(bp + 32768);
      short8 bl = *(const short8*)(bp + 65536);
      #pragma unroll
      for (int mt = 0; mt < 2; mt++){
        int r = mt*16 + l15;
        int off = r*512 + (((kt*4 + lquad) ^ (r & 7)) << 3);
        short8 ah = *(const short8*)(ga + off);
        short8 am = *(const short8*)(ga + 16384 + off);
        accg[mt] = mfma5(ah, am, bh, bm, bl, accg[mt]);
      }
    }
    float opbv = opb[wave*16 + l15];
    #pragma unroll
    for (int mt = 0; mt < 2; mt++)
      #pragma unroll
      for (int reg = 0; reg < 4; reg++)
        lg[mt*16 + lquad*4 + reg][wave*16 + l15] = accg[mt][reg] + opbv;
  } else {
    int t4 = (wave - 4)*64 + lane;   // 256 threads
    for (int i = t4; i < 4096; i += 256){
      int p = i >> 11, rem = i & 2047, r = rem >> 6, gg = rem & 63;
      short8 v = *(const short8*)(ga + p*16384 + r*512 + ((gg ^ (r & 7)) << 3));
      unsigned short* dst = (p ? fl : fh) + (size_t)(r0 + r)*512 + gg*8;
      *(short8*)dst = v;
    }
  }
  __syncthreads();

  // ---- softmax + top3 (each wave: 4 rows)
  {
    for (int rr = 0; rr < 4; rr++){
      int r = wave*4 + rr, row = r0 + r;
      float l = lg[r][lane];
      float mx = l;
      #pragma unroll
      for (int o = 32; o; o >>= 1) mx = fmaxf(mx, __shfl_xor(mx, o, 64));
      float p = expf(l - mx);
      float s = wave_sum64(p);
      p /= s;
      float pv = p;
      for (int j = 0; j < 3; j++){
        float v = pv; int idx = lane;
        #pragma unroll
        for (int o = 32; o; o >>= 1){
          float ov = __shfl_xor(v, o, 64);
          int   oi = __shfl_xor(idx, o, 64);
          if (ov > v || (ov == v && oi < idx)){ v = ov; idx = oi; }
        }
        if (lane == 0){
          dout[(size_t)row*3 + j]                = v;
          dout[(size_t)Bv*3 + (size_t)row*3 + j] = (float)idx;
        }
        if (v >= CONFv){
          if (lane == 0){
            int pos = atomicAdd(&cnt[idx], 1);
            list[idx*Bv + pos] = (row << 2) | j;
          }
        } else {
          if (lane < 16) dout[(size_t)Bv*6 + (size_t)row*48 + j*16 + lane] = 0.f;
        }
        if (lane == idx) pv = -1.0f;
      }
    }
  }
}

// ---------------- kernel 3: expert MLP, packed-B MFMA, pre-split feats ----
__global__ __launch_bounds__(256) void k_expert(const unsigned short* __restrict__ fh,
    const unsigned short* __restrict__ fl,
    const unsigned short* __restrict__ p1, const float* __restrict__ b1,
    const float* __restrict__ g,  const float* __restrict__ beta,
    const unsigned short* __restrict__ p2, const float* __restrict__ b2,
    const int* __restrict__ cnt,  const int* __restrict__ list,
    float* __restrict__ dout)
{
  extern __shared__ unsigned char smem[];
  unsigned short* xh = (unsigned short*)smem;
  unsigned short* xl = xh + 32*512;
  float*          zs = (float*)smem;
  unsigned short* zp = (unsigned short*)smem;
  __shared__ int sdesc[3];

  const int tid = threadIdx.x;
  const int wave = tid >> 6, lane = tid & 63;
  const int lquad = lane >> 4, l15 = lane & 15;

  if (wave == 0){
    int c  = cnt[lane];
    int tl = (c + 31) >> 5;
    int incl = tl;
    #pragma unroll
    for (int o = 1; o < 64; o <<= 1){
      int v = __shfl_up(incl, o, 64);
      if (lane >= o) incl += v;
    }
    int total = __shfl(incl, 63, 64);
    int G   = (total + 7) >> 3;
    int grp = blockIdx.x & 7, rr = blockIdx.x >> 3;
    int lgc = grp*G + rr;
    int ok  = (G > 0) && (rr < G) && (lgc < total);
    unsigned long long bm = __ballot(ok && (incl > lgc));
    if (lane == 0){
      if (!ok || bm == 0ull){ sdesc[0] = -1; }
      else {
        int e = __ffsll((long long)bm) - 1;
        sdesc[0] = e; sdesc[1] = lgc; sdesc[2] = 0;
      }
    }
    if (bm != 0ull && ok){
      int e = __ffsll((long long)bm) - 1;
      int excl = __shfl(incl - tl, e, 64);
      int ne   = __shfl(c, e, 64);
      if (lane == 0){ sdesc[1] = lgc - excl; sdesc[2] = ne; }
    }
  }
  __syncthreads();
  const int e = sdesc[0];
  if (e < 0) return;
  const int t = sdesc[1];
  const int n = sdesc[2];
  const int base = t * 32;
  const int m = min(32, n - base);
  const int* lrow = list + e*Bv + base;

  // ---- stage feats hi/lo planes -> swizzled LDS (pure copy)
  for (int i = tid; i < 4096; i += 256){
    int p = i >> 11, rem = i & 2047, r = rem >> 6, gg = rem & 63;
    int ev = lrow[(r < m) ? r : 0];
    int row = ev >> 2;
    const unsigned short* src = (p ? fl : fh) + (size_t)row*512 + gg*8;
    short8 v = *(const short8*)src;
    unsigned short* dst = (p ? xl : xh) + r*512 + ((gg ^ (r & 7)) << 3);
    *(short8*)dst = v;
  }
  __syncthreads();

  const unsigned short* p1e = p1 + (size_t)e * 262144;
  const int colbase = wave * 64;
  f32x4 acc[2][4];
  #pragma unroll
  for (int mt = 0; mt < 2; mt++)
    #pragma unroll
    for (int nt = 0; nt < 4; nt++) acc[mt][nt] = (f32x4){0.f,0.f,0.f,0.f};

  for (int kt = 0; kt < 16; kt++){
    short8 ah[2], al[2];
    int gk = kt*4 + lquad;
    #pragma unroll
    for (int mt = 0; mt < 2; mt++){
      int r = mt*16 + l15;
      int off = r*512 + ((gk ^ (r & 7)) << 3);
      ah[mt] = *(const short8*)(xh + off);
      al[mt] = *(const short8*)(xl + off);
    }
    #pragma unroll
    for (int nt = 0; nt < 4; nt++){
      int ntg = wave*4 + nt;
      const unsigned short* bp = p1e + (((ntg*16 + kt)*64 + lane) << 3);
      short8 bh = *(const short8*)bp;
      short8 bl = *(const short8*)(bp + 131072);
      #pragma unroll
      for (int mt = 0; mt < 2; mt++)
        acc[mt][nt] = mfma3(ah[mt], al[mt], bh, bl, acc[mt][nt]);
    }
  }
  __syncthreads();

  #pragma unroll
  for (int nt = 0; nt < 4; nt++){
    int col = colbase + nt*16 + l15;
    float bb = b1[e*256 + col];
    #pragma unroll
    for (int mt = 0; mt < 2; mt++)
      #pragma unroll
      for (int rg = 0; rg < 4; rg++){
        int rl = mt*16 + lquad*4 + rg;
        zs[rl*264 + col] = acc[mt][nt][rg] + bb;
      }
  }
  __syncthreads();

  {
    float gv[4], bv[4];
    #pragma unroll
    for (int j = 0; j < 4; j++){
      gv[j] = g[e*256 + lane + 64*j];
      bv[j] = beta[e*256 + lane + 64*j];
    }
    for (int rr2 = 0; rr2 < 8; rr2++){
      int r = wave*8 + rr2;
      float x[4];
      float s = 0.f;
      #pragma unroll
      for (int j = 0; j < 4; j++){ x[j] = zs[r*264 + lane + 64*j]; s += x[j]; }
      s = wave_sum64(s);
      float mm = s * (1.0f/256.0f);
      float v = 0.f;
      #pragma unroll
      for (int j = 0; j < 4; j++){ float d = x[j] - mm; v += d*d; }
      v = wave_sum64(v) * (1.0f/256.0f);
      float inv = 1.0f / sqrtf(v + EPSv);
      #pragma unroll
      for (int j = 0; j < 4; j++){
        int c = lane + 64*j;
        float y = fmaxf((x[j] - mm)*inv*gv[j] + bv[j], 0.f);
        unsigned u = __float_as_uint(y);
        float res = y - __uint_as_float(u & 0xffff0000u);
        zp[r*528 + c]       = (unsigned short)(u >> 16);
        zp[r*528 + 264 + c] = (unsigned short)(__float_as_uint(res) >> 16);
      }
    }
  }
  __syncthreads();

  if (wave < 2){
    const unsigned short* p2e = p2 + (size_t)e * 8192;
    f32x4 acc2 = (f32x4){0.f,0.f,0.f,0.f};
    for (int kt2 = 0; kt2 < 8; kt2++){
      const unsigned short* zb = zp + (wave*16 + l15)*528 + kt2*32 + lquad*8;
      short8 ahh = *(const short8*)zb;
      short8 all2 = *(const short8*)(zb + 264);
      const unsigned short* bp = p2e + ((kt2*64 + lane) << 3);
      short8 bh = *(const short8*)bp;
      short8 bl = *(const short8*)(bp + 4096);
      acc2 = mfma3(ahh, all2, bh, bl, acc2);
    }
    float b2v = b2[e*16 + l15];
    #pragma unroll
    for (int reg = 0; reg < 4; reg++){
      int rl = wave*16 + lquad*4 + reg;
      if (rl < m){
        int ev = lrow[rl];
        int row = ev >> 2, j = ev & 3;
        dout[(size_t)Bv*6 + (size_t)row*48 + j*16 + l15] = acc2[reg] + b2v;
      }
    }
  }
}

extern "C" void kernel_launch(void* const* d_in, const int* in_sizes, int n_in,
                              void* d_out, int out_size, void* d_ws, size_t ws_size,
                              hipStream_t stream)
{
  const float* X   = (const float*)d_in[0];
  const float* w1  = (const float*)d_in[1];
  const float* b1  = (const float*)d_in[2];
  const float* g1  = (const float*)d_in[3];
  const float* be1 = (const float*)d_in[4];
  const float* w2  = (const float*)d_in[5];
  const float* b2  = (const float*)d_in[6];
  const float* g2  = (const float*)d_in[7];
  const float* be2 = (const float*)d_in[8];
  const float* opw = (const float*)d_in[9];
  const float* opb = (const float*)d_in[10];
  const float* pw1 = (const float*)d_in[11];
  const float* pb1 = (const float*)d_in[12];
  const float* pg  = (const float*)d_in[13];
  const float* pbe = (const float*)d_in[14];
  const float* pw2 = (const float*)d_in[15];
  const float* pb2 = (const float*)d_in[16];
  float* out = (float*)d_out;
  char*  ws  = (char*)d_ws;

  // Workspace: p1E @0 (32MB), p2E @32MB (1MB), w1p_rp @33MB, w2p_rp @34MB,
  // opwp @35MB, fh @36MB (8MB), fl @44MB (8MB), list @52MB (2MB), cnt @54MB.
  unsigned short* p1E    = (unsigned short*)ws;
  unsigned short* p2E    = (unsigned short*)(ws + (size_t)32*MB);
  unsigned short* w1p_rp = (unsigned short*)(ws + (size_t)33*MB);
  unsigned short* w2p_rp = (unsigned short*)(ws + (size_t)34*MB);
  unsigned short* opwp   = (unsigned short*)(ws + (size_t)35*MB);
  unsigned short* fh     = (unsigned short*)(ws + (size_t)36*MB);
  unsigned short* fl     = (unsigned short*)(ws + (size_t)44*MB);
  int*            list   = (int*)(ws + (size_t)52*MB);
  int*            cnt    = (int*)(ws + (size_t)54*MB);

  k_pack  <<<4993, 256, 0, stream>>>(pw1, pw2, w1, w2, opw, p1E, p2E,
                                     w1p_rp, w2p_rp, opwp, cnt);
  k_fused <<<256,  512, 65536, stream>>>(X, w1p_rp, b1, g1, be1,
                                         w2p_rp, b2, g2, be2, opwp, opb,
                                         fh, fl, out, cnt, list);
  k_expert<<<832,  256, 65536, stream>>>(fh, fl, p1E, pb1, pg, pbe, p2E, pb2,
                                         cnt, list, out);
}

// Round 9
// 179.921 us; speedup vs baseline: 1.2690x; 1.0175x over previous
//
#include <hip/hip_runtime.h>
#include <math.h>

#define Bv   8192
#define EPSv 1e-5f
#define CONFv 0.1f
#define MB (1024*1024)

typedef __attribute__((ext_vector_type(8))) short short8;
typedef __attribute__((ext_vector_type(4))) float f32x4;

__device__ __forceinline__ float wave_sum64(float v){
  #pragma unroll
  for (int o = 32; o; o >>= 1) v += __shfl_xor(v, o, 64);
  return v;
}

__device__ __forceinline__ void split3f(float x, short &h, short &m, short &l){
  unsigned u = __float_as_uint(x);
  h = (short)(u >> 16);
  float r1 = x - __uint_as_float(u & 0xffff0000u);
  unsigned u1 = __float_as_uint(r1);
  m = (short)(u1 >> 16);
  float r2 = r1 - __uint_as_float(u1 & 0xffff0000u);
  l = (short)(__float_as_uint(r2) >> 16);
}

__device__ __forceinline__ void split2f(float x, short &h, short &m){
  unsigned u = __float_as_uint(x);
  h = (short)(u >> 16);
  float r1 = x - __uint_as_float(u & 0xffff0000u);
  m = (short)(__float_as_uint(r1) >> 16);
}

// 5-pass: A 2-plane (h,m) x B 3-plane. Drops al*bh-class terms (~2^-24 rel),
// same error order as the old 6-pass (which dropped ml+lm ~2*2^-24).
__device__ __forceinline__ f32x4 mfma5(short8 ah, short8 am,
                                       short8 bh, short8 bm, short8 bl, f32x4 c){
  c = __builtin_amdgcn_mfma_f32_16x16x32_bf16(am, bm, c, 0, 0, 0);
  c = __builtin_amdgcn_mfma_f32_16x16x32_bf16(ah, bl, c, 0, 0, 0);
  c = __builtin_amdgcn_mfma_f32_16x16x32_bf16(am, bh, c, 0, 0, 0);
  c = __builtin_amdgcn_mfma_f32_16x16x32_bf16(ah, bm, c, 0, 0, 0);
  c = __builtin_amdgcn_mfma_f32_16x16x32_bf16(ah, bh, c, 0, 0, 0);
  return c;
}

__device__ __forceinline__ f32x4 mfma3(short8 ah, short8 al,
                                       short8 bh, short8 bl, f32x4 c){
  c = __builtin_amdgcn_mfma_f32_16x16x32_bf16(al, bh, c, 0, 0, 0);
  c = __builtin_amdgcn_mfma_f32_16x16x32_bf16(ah, bl, c, 0, 0, 0);
  c = __builtin_amdgcn_mfma_f32_16x16x32_bf16(ah, bh, c, 0, 0, 0);
  return c;
}

// ---------------- kernel 1: all weight packing + cnt zero, one dispatch ----
__global__ __launch_bounds__(256) void k_pack(const float* __restrict__ pw1,
    const float* __restrict__ pw2, const float* __restrict__ w1,
    const float* __restrict__ w2, const float* __restrict__ opw,
    unsigned short* __restrict__ p1, unsigned short* __restrict__ p2,
    unsigned short* __restrict__ w1p, unsigned short* __restrict__ w2p,
    unsigned short* __restrict__ opwp, int* __restrict__ cnt)
{
  int bid = blockIdx.x;
  if (bid < 4096){
    int t = bid*256 + threadIdx.x;
    int e = t >> 14, rem = t & 16383, kg = rem >> 8, n = rem & 255;
    const float* src = pw1 + ((size_t)e << 17) + (size_t)(kg*8)*256 + n;
    short8 h, l;
    #pragma unroll
    for (int j = 0; j < 8; j++){
      float w = src[(size_t)j*256];
      unsigned u = __float_as_uint(w);
      float r2 = w - __uint_as_float(u & 0xffff0000u);
      h[j] = (short)(u >> 16);
      l[j] = (short)(__float_as_uint(r2) >> 16);
    }
    int idx8 = ((((n >> 4)*16 + (kg >> 2))*64) + (kg & 3)*16 + (n & 15)) << 3;
    unsigned short* ep = p1 + (size_t)e * 262144;
    *(short8*)(ep + idx8)          = h;
    *(short8*)(ep + 131072 + idx8) = l;
  } else if (bid < 4224){
    int t = (bid - 4096)*256 + threadIdx.x;
    int e = t >> 9, rem = t & 511, kg = rem >> 4, n = rem & 15;
    const float* src = pw2 + (size_t)e*4096 + (size_t)(kg*8)*16 + n;
    short8 h, l;
    #pragma unroll
    for (int j = 0; j < 8; j++){
      float w = src[(size_t)j*16];
      unsigned u = __float_as_uint(w);
      float r2 = w - __uint_as_float(u & 0xffff0000u);
      h[j] = (short)(u >> 16);
      l[j] = (short)(__float_as_uint(r2) >> 16);
    }
    int idx8 = (((kg >> 2)*64) + (kg & 3)*16 + n) << 3;
    unsigned short* ep = p2 + (size_t)e * 8192;
    *(short8*)(ep + idx8)        = h;
    *(short8*)(ep + 4096 + idx8) = l;
  } else if (bid < 4352){
    int gid = (bid - 4224)*256 + threadIdx.x;   // 32768, K=128, N=256
    int k = gid >> 8, n = gid & 255;
    short h, m, l;
    split3f(w1[gid], h, m, l);
    int idx = (((n >> 4)*4 + (k >> 5))*64 + (((k >> 3) & 3)*16 + (n & 15)))*8 + (k & 7);
    w1p[idx]             = (unsigned short)h;
    w1p[32768 + idx]     = (unsigned short)m;
    w1p[2*32768 + idx]   = (unsigned short)l;
  } else if (bid < 4864){
    int gid = (bid - 4352)*256 + threadIdx.x;   // 131072, K=256, N=512
    int k = gid >> 9, n = gid & 511;
    short h, m, l;
    split3f(w2[gid], h, m, l);
    int idx = (((n >> 4)*8 + (k >> 5))*64 + (((k >> 3) & 3)*16 + (n & 15)))*8 + (k & 7);
    w2p[idx]             = (unsigned short)h;
    w2p[131072 + idx]    = (unsigned short)m;
    w2p[2*131072 + idx]  = (unsigned short)l;
  } else if (bid < 4992){
    int gid = (bid - 4864)*256 + threadIdx.x;   // 32768, K=512, N=64
    int k = gid >> 6, n = gid & 63;
    short h, m, l;
    split3f(opw[gid], h, m, l);
    int idx = (((n >> 4)*16 + (k >> 5))*64 + (((k >> 3) & 3)*16 + (n & 15)))*8 + (k & 7);
    opwp[idx]            = (unsigned short)h;
    opwp[32768 + idx]    = (unsigned short)m;
    opwp[2*32768 + idx]  = (unsigned short)l;
  } else {
    if (threadIdx.x < 64) cnt[threadIdx.x] = 0;
  }
}

// ---------------- kernel 2: fused rp1->rp2->gate, M=32, 1024 threads ------
// 16 waves/block, grid 256, 1 block/CU -> 4 waves/SIMD.
// Dynamic LDS 64KB (shorts): xh[0,4K) xm[4K,8K) hbh[8K,16K) hbm[16K,24K);
// overlay after LN2: gah[0,16K) gam[16K,32K).
// A pre-split at staging (2 planes); all GEMMs 5-pass.
__global__ __launch_bounds__(1024) void k_fused(const float* __restrict__ X,
    const unsigned short* __restrict__ w1p, const float* __restrict__ b1,
    const float* __restrict__ g1, const float* __restrict__ be1,
    const unsigned short* __restrict__ w2p, const float* __restrict__ b2,
    const float* __restrict__ g2, const float* __restrict__ be2,
    const unsigned short* __restrict__ opwp, const float* __restrict__ opb,
    unsigned short* __restrict__ fh, unsigned short* __restrict__ fl,
    float* __restrict__ dout, int* __restrict__ cnt, int* __restrict__ list)
{
  extern __shared__ unsigned char smem[];
  unsigned short* xh  = (unsigned short*)smem;          // [32][128]
  unsigned short* xm  = xh + 4096;
  unsigned short* hbh = xh + 8192;                      // [32][256]
  unsigned short* hbm = xh + 16384;
  unsigned short* gah = xh;                             // [32][512] overlay
  unsigned short* gam = xh + 16384;
  __shared__ float part[16][32][2];
  __shared__ float lg[32][64];

  const int tid = threadIdx.x;
  const int r0  = blockIdx.x * 32;
  const int wave = tid >> 6, lane = tid & 63, lquad = lane >> 4, l15 = lane & 15;

  // ---- stage X pre-split (1024 threads, 1 float4 each)
  {
    int r = tid >> 5, c4 = tid & 31;
    float4 v = ((const float4*)X)[(size_t)(r0+r)*32 + c4];
    unsigned u0 = __float_as_uint(v.x), u1 = __float_as_uint(v.y);
    unsigned u2 = __float_as_uint(v.z), u3 = __float_as_uint(v.w);
    float m0 = v.x - __uint_as_float(u0 & 0xffff0000u);
    float m1 = v.y - __uint_as_float(u1 & 0xffff0000u);
    float m2 = v.z - __uint_as_float(u2 & 0xffff0000u);
    float m3 = v.w - __uint_as_float(u3 & 0xffff0000u);
    unsigned hp0 = (u0 >> 16) | (u1 & 0xffff0000u);
    unsigned hp1 = (u2 >> 16) | (u3 & 0xffff0000u);
    unsigned mp0 = (__float_as_uint(m0) >> 16) | (__float_as_uint(m1) & 0xffff0000u);
    unsigned mp1 = (__float_as_uint(m2) >> 16) | (__float_as_uint(m3) & 0xffff0000u);
    int gk = c4 >> 1, half = c4 & 1;
    int off = r*128 + ((gk ^ (r & 7)) << 3) + half*4;
    ((unsigned*)(xh + off))[0] = hp0;
    ((unsigned*)(xh + off))[1] = hp1;
    ((unsigned*)(xm + off))[0] = mp0;
    ((unsigned*)(xm + off))[1] = mp1;
  }
  __syncthreads();

  // ---- GEMM1 (M=32, N=256, K=128) 5-pass; wave owns 1 ntile (16 cols)
  float bcol1, gcol1, becol1;
  {
    int col = wave*16 + l15;
    bcol1 = b1[col]; gcol1 = g1[col]; becol1 = be1[col];
  }
  {
    f32x4 acc[2];
    acc[0] = (f32x4){0.f,0.f,0.f,0.f};
    acc[1] = (f32x4){0.f,0.f,0.f,0.f};
    const int pstride = 32768;
    for (int ks4 = 0; ks4 < 4; ks4++){
      const unsigned short* bp = w1p + (((wave*4 + ks4)*64 + lane) << 3);
      short8 bh = *(const short8*)bp;
      short8 bm = *(const short8*)(bp + pstride);
      short8 bl = *(const short8*)(bp + 2*pstride);
      #pragma unroll
      for (int mt = 0; mt < 2; mt++){
        int r = mt*16 + l15;
        int off = r*128 + (((ks4*4 + lquad) ^ (r & 7)) << 3);
        short8 ah = *(const short8*)(xh + off);
        short8 am = *(const short8*)(xm + off);
        acc[mt] = mfma5(ah, am, bh, bm, bl, acc[mt]);
      }
    }
    #pragma unroll
    for (int mt = 0; mt < 2; mt++)
      #pragma unroll
      for (int reg = 0; reg < 4; reg++){
        float z = acc[mt][reg] + bcol1;
        float s = z, q = z*z;
        #pragma unroll
        for (int o = 1; o < 16; o <<= 1){ s += __shfl_xor(s, o, 64); q += __shfl_xor(q, o, 64); }
        int row = mt*16 + lquad*4 + reg;
        if (l15 == 0){ part[wave][row][0] = s; part[wave][row][1] = q; }
      }
    __syncthreads();
    #pragma unroll
    for (int mt = 0; mt < 2; mt++)
      #pragma unroll
      for (int reg = 0; reg < 4; reg++){
        int row = mt*16 + lquad*4 + reg;
        float s = 0.f, q = 0.f;
        #pragma unroll
        for (int w16 = 0; w16 < 16; w16++){ s += part[w16][row][0]; q += part[w16][row][1]; }
        float mean = s * (1.0f/256.0f);
        float var  = q * (1.0f/256.0f) - mean*mean;
        float inv  = 1.0f / sqrtf(var + EPSv);
        int col = wave*16 + l15;
        float z = acc[mt][reg] + bcol1;
        float y = fmaxf((z - mean)*inv*gcol1 + becol1, 0.f);
        short hh, mm2;
        split2f(y, hh, mm2);
        int gg = col >> 3, c7 = col & 7;
        int adr = row*256 + ((gg ^ (row & 7)) << 3) + c7;
        hbh[adr] = (unsigned short)hh;
        hbm[adr] = (unsigned short)mm2;
      }
  }
  __syncthreads();

  // ---- GEMM2 (M=32, N=512, K=256) 5-pass; wave owns 2 ntiles (32 cols)
  f32x4 acc2[2][2];
  #pragma unroll
  for (int mt = 0; mt < 2; mt++)
    #pragma unroll
    for (int nt = 0; nt < 2; nt++) acc2[mt][nt] = (f32x4){0.f,0.f,0.f,0.f};
  {
    const int pstride = 131072;
    for (int ks4 = 0; ks4 < 8; ks4++){
      short8 ah[2], am[2];
      #pragma unroll
      for (int mt = 0; mt < 2; mt++){
        int r = mt*16 + l15;
        int off = r*256 + (((ks4*4 + lquad) ^ (r & 7)) << 3);
        ah[mt] = *(const short8*)(hbh + off);
        am[mt] = *(const short8*)(hbm + off);
      }
      #pragma unroll
      for (int nt = 0; nt < 2; nt++){
        int ntg = wave*2 + nt;
        const unsigned short* bp = w2p + (((ntg*8 + ks4)*64 + lane) << 3);
        short8 bh = *(const short8*)bp;
        short8 bm = *(const short8*)(bp + pstride);
        short8 bl = *(const short8*)(bp + 2*pstride);
        #pragma unroll
        for (int mt = 0; mt < 2; mt++)
          acc2[mt][nt] = mfma5(ah[mt], am[mt], bh, bm, bl, acc2[mt][nt]);
      }
    }
  }

  // ---- LN2 partials
  float bcol[2], gcol[2], becol[2];
  #pragma unroll
  for (int nt = 0; nt < 2; nt++){
    int col = (wave*2 + nt)*16 + l15;
    bcol[nt] = b2[col]; gcol[nt] = g2[col]; becol[nt] = be2[col];
  }
  #pragma unroll
  for (int mt = 0; mt < 2; mt++)
    #pragma unroll
    for (int reg = 0; reg < 4; reg++){
      float s = 0.f, q = 0.f;
      #pragma unroll
      for (int nt = 0; nt < 2; nt++){
        float z = acc2[mt][nt][reg] + bcol[nt];
        s += z; q += z*z;
      }
      #pragma unroll
      for (int o = 1; o < 16; o <<= 1){ s += __shfl_xor(s, o, 64); q += __shfl_xor(q, o, 64); }
      int row = mt*16 + lquad*4 + reg;
      if (l15 == 0){ part[wave][row][0] = s; part[wave][row][1] = q; }
    }
  __syncthreads();   // all hb reads done -> ga overlay safe after this

  // ---- LN2 finalize -> ga 2-plane bf16 (swizzled A layout)
  #pragma unroll
  for (int mt = 0; mt < 2; mt++)
    #pragma unroll
    for (int reg = 0; reg < 4; reg++){
      int row = mt*16 + lquad*4 + reg;
      float s = 0.f, q = 0.f;
      #pragma unroll
      for (int w16 = 0; w16 < 16; w16++){ s += part[w16][row][0]; q += part[w16][row][1]; }
      float mean = s * (1.0f/512.0f);
      float var  = q * (1.0f/512.0f) - mean*mean;
      float inv  = 1.0f / sqrtf(var + EPSv);
      #pragma unroll
      for (int nt = 0; nt < 2; nt++){
        int col = (wave*2 + nt)*16 + l15;
        float z = acc2[mt][nt][reg] + bcol[nt];
        float y = fmaxf((z - mean)*inv*gcol[nt] + becol[nt], 0.f);
        short hh, mm2;
        split2f(y, hh, mm2);
        int gg = col >> 3, c7 = col & 7;
        int adr = row*512 + ((gg ^ (row & 7)) << 3) + c7;
        gah[adr] = (unsigned short)hh;
        gam[adr] = (unsigned short)mm2;
      }
    }
  __syncthreads();

  // ---- waves 0-3: gate GEMM (M=32, N=64, K=512) 5-pass
  //      waves 4-15: export feats hi/mid planes to global concurrently
  if (wave < 4){
    f32x4 accg[2];
    accg[0] = (f32x4){0.f,0.f,0.f,0.f};
    accg[1] = (f32x4){0.f,0.f,0.f,0.f};
    for (int kt = 0; kt < 16; kt++){
      const unsigned short* bp = opwp + (((wave*16 + kt)*64 + lane) << 3);
      short8 bh = *(const short8*)bp;
      short8 bm = *(const short8*)(bp + 32768);
      short8 bl = *(const short8*)(bp + 65536);
      #pragma unroll
      for (int mt = 0; mt < 2; mt++){
        int r = mt*16 + l15;
        int off = r*512 + (((kt*4 + lquad) ^ (r & 7)) << 3);
        short8 ah = *(const short8*)(gah + off);
        short8 am = *(const short8*)(gam + off);
        accg[mt] = mfma5(ah, am, bh, bm, bl, accg[mt]);
      }
    }
    float opbv = opb[wave*16 + l15];
    #pragma unroll
    for (int mt = 0; mt < 2; mt++)
      #pragma unroll
      for (int reg = 0; reg < 4; reg++)
        lg[mt*16 + lquad*4 + reg][wave*16 + l15] = accg[mt][reg] + opbv;
  } else {
    int t4 = (wave - 4)*64 + lane;   // 768 threads
    for (int i = t4; i < 4096; i += 768){
      int p = i >> 11, rem = i & 2047, r = rem >> 6, gg = rem & 63;
      short8 v = *(const short8*)((p ? gam : gah) + r*512 + ((gg ^ (r & 7)) << 3));
      unsigned short* dst = (p ? fl : fh) + (size_t)(r0 + r)*512 + gg*8;
      *(short8*)dst = v;
    }
  }
  __syncthreads();

  // ---- softmax + top3 (each wave: 2 rows)
  {
    for (int rr = 0; rr < 2; rr++){
      int r = wave*2 + rr, row = r0 + r;
      float l = lg[r][lane];
      float mx = l;
      #pragma unroll
      for (int o = 32; o; o >>= 1) mx = fmaxf(mx, __shfl_xor(mx, o, 64));
      float p = expf(l - mx);
      float s = wave_sum64(p);
      p /= s;
      float pv = p;
      for (int j = 0; j < 3; j++){
        float v = pv; int idx = lane;
        #pragma unroll
        for (int o = 32; o; o >>= 1){
          float ov = __shfl_xor(v, o, 64);
          int   oi = __shfl_xor(idx, o, 64);
          if (ov > v || (ov == v && oi < idx)){ v = ov; idx = oi; }
        }
        if (lane == 0){
          dout[(size_t)row*3 + j]                = v;
          dout[(size_t)Bv*3 + (size_t)row*3 + j] = (float)idx;
        }
        if (v >= CONFv){
          if (lane == 0){
            int pos = atomicAdd(&cnt[idx], 1);
            list[idx*Bv + pos] = (row << 2) | j;
          }
        } else {
          if (lane < 16) dout[(size_t)Bv*6 + (size_t)row*48 + j*16 + lane] = 0.f;
        }
        if (lane == idx) pv = -1.0f;
      }
    }
  }
}

// ---------------- kernel 3: expert MLP, packed-B MFMA, pre-split feats ----
__global__ __launch_bounds__(256) void k_expert(const unsigned short* __restrict__ fh,
    const unsigned short* __restrict__ fl,
    const unsigned short* __restrict__ p1, const float* __restrict__ b1,
    const float* __restrict__ g,  const float* __restrict__ beta,
    const unsigned short* __restrict__ p2, const float* __restrict__ b2,
    const int* __restrict__ cnt,  const int* __restrict__ list,
    float* __restrict__ dout)
{
  extern __shared__ unsigned char smem[];
  unsigned short* xh = (unsigned short*)smem;
  unsigned short* xl = xh + 32*512;
  float*          zs = (float*)smem;
  unsigned short* zp = (unsigned short*)smem;
  __shared__ int sdesc[3];

  const int tid = threadIdx.x;
  const int wave = tid >> 6, lane = tid & 63;
  const int lquad = lane >> 4, l15 = lane & 15;

  if (wave == 0){
    int c  = cnt[lane];
    int tl = (c + 31) >> 5;
    int incl = tl;
    #pragma unroll
    for (int o = 1; o < 64; o <<= 1){
      int v = __shfl_up(incl, o, 64);
      if (lane >= o) incl += v;
    }
    int total = __shfl(incl, 63, 64);
    int G   = (total + 7) >> 3;
    int grp = blockIdx.x & 7, rr = blockIdx.x >> 3;
    int lgc = grp*G + rr;
    int ok  = (G > 0) && (rr < G) && (lgc < total);
    unsigned long long bm = __ballot(ok && (incl > lgc));
    if (lane == 0){
      if (!ok || bm == 0ull){ sdesc[0] = -1; }
      else {
        int e = __ffsll((long long)bm) - 1;
        sdesc[0] = e; sdesc[1] = lgc; sdesc[2] = 0;
      }
    }
    if (bm != 0ull && ok){
      int e = __ffsll((long long)bm) - 1;
      int excl = __shfl(incl - tl, e, 64);
      int ne   = __shfl(c, e, 64);
      if (lane == 0){ sdesc[1] = lgc - excl; sdesc[2] = ne; }
    }
  }
  __syncthreads();
  const int e = sdesc[0];
  if (e < 0) return;
  const int t = sdesc[1];
  const int n = sdesc[2];
  const int base = t * 32;
  const int m = min(32, n - base);
  const int* lrow = list + e*Bv + base;

  // ---- stage feats hi/lo planes -> swizzled LDS (pure copy)
  for (int i = tid; i < 4096; i += 256){
    int p = i >> 11, rem = i & 2047, r = rem >> 6, gg = rem & 63;
    int ev = lrow[(r < m) ? r : 0];
    int row = ev >> 2;
    const unsigned short* src = (p ? fl : fh) + (size_t)row*512 + gg*8;
    short8 v = *(const short8*)src;
    unsigned short* dst = (p ? xl : xh) + r*512 + ((gg ^ (r & 7)) << 3);
    *(short8*)dst = v;
  }
  __syncthreads();

  const unsigned short* p1e = p1 + (size_t)e * 262144;
  const int colbase = wave * 64;
  f32x4 acc[2][4];
  #pragma unroll
  for (int mt = 0; mt < 2; mt++)
    #pragma unroll
    for (int nt = 0; nt < 4; nt++) acc[mt][nt] = (f32x4){0.f,0.f,0.f,0.f};

  for (int kt = 0; kt < 16; kt++){
    short8 ah[2], al[2];
    int gk = kt*4 + lquad;
    #pragma unroll
    for (int mt = 0; mt < 2; mt++){
      int r = mt*16 + l15;
      int off = r*512 + ((gk ^ (r & 7)) << 3);
      ah[mt] = *(const short8*)(xh + off);
      al[mt] = *(const short8*)(xl + off);
    }
    #pragma unroll
    for (int nt = 0; nt < 4; nt++){
      int ntg = wave*4 + nt;
      const unsigned short* bp = p1e + (((ntg*16 + kt)*64 + lane) << 3);
      short8 bh = *(const short8*)bp;
      short8 bl = *(const short8*)(bp + 131072);
      #pragma unroll
      for (int mt = 0; mt < 2; mt++)
        acc[mt][nt] = mfma3(ah[mt], al[mt], bh, bl, acc[mt][nt]);
    }
  }
  __syncthreads();

  #pragma unroll
  for (int nt = 0; nt < 4; nt++){
    int col = colbase + nt*16 + l15;
    float bb = b1[e*256 + col];
    #pragma unroll
    for (int mt = 0; mt < 2; mt++)
      #pragma unroll
      for (int rg = 0; rg < 4; rg++){
        int rl = mt*16 + lquad*4 + rg;
        zs[rl*264 + col] = acc[mt][nt][rg] + bb;
      }
  }
  __syncthreads();

  {
    float gv[4], bv[4];
    #pragma unroll
    for (int j = 0; j < 4; j++){
      gv[j] = g[e*256 + lane + 64*j];
      bv[j] = beta[e*256 + lane + 64*j];
    }
    for (int rr2 = 0; rr2 < 8; rr2++){
      int r = wave*8 + rr2;
      float x[4];
      float s = 0.f;
      #pragma unroll
      for (int j = 0; j < 4; j++){ x[j] = zs[r*264 + lane + 64*j]; s += x[j]; }
      s = wave_sum64(s);
      float mm = s * (1.0f/256.0f);
      float v = 0.f;
      #pragma unroll
      for (int j = 0; j < 4; j++){ float d = x[j] - mm; v += d*d; }
      v = wave_sum64(v) * (1.0f/256.0f);
      float inv = 1.0f / sqrtf(v + EPSv);
      #pragma unroll
      for (int j = 0; j < 4; j++){
        int c = lane + 64*j;
        float y = fmaxf((x[j] - mm)*inv*gv[j] + bv[j], 0.f);
        unsigned u = __float_as_uint(y);
        float res = y - __uint_as_float(u & 0xffff0000u);
        zp[r*528 + c]       = (unsigned short)(u >> 16);
        zp[r*528 + 264 + c] = (unsigned short)(__float_as_uint(res) >> 16);
      }
    }
  }
  __syncthreads();

  if (wave < 2){
    const unsigned short* p2e = p2 + (size_t)e * 8192;
    f32x4 acc2 = (f32x4){0.f,0.f,0.f,0.f};
    for (int kt2 = 0; kt2 < 8; kt2++){
      const unsigned short* zb = zp + (wave*16 + l15)*528 + kt2*32 + lquad*8;
      short8 ahh = *(const short8*)zb;
      short8 all2 = *(const short8*)(zb + 264);
      const unsigned short* bp = p2e + ((kt2*64 + lane) << 3);
      short8 bh = *(const short8*)bp;
      short8 bl = *(const short8*)(bp + 4096);
      acc2 = mfma3(ahh, all2, bh, bl, acc2);
    }
    float b2v = b2[e*16 + l15];
    #pragma unroll
    for (int reg = 0; reg < 4; reg++){
      int rl = wave*16 + lquad*4 + reg;
      if (rl < m){
        int ev = lrow[rl];
        int row = ev >> 2, j = ev & 3;
        dout[(size_t)Bv*6 + (size_t)row*48 + j*16 + l15] = acc2[reg] + b2v;
      }
    }
  }
}

extern "C" void kernel_launch(void* const* d_in, const int* in_sizes, int n_in,
                              void* d_out, int out_size, void* d_ws, size_t ws_size,
                              hipStream_t stream)
{
  const float* X   = (const float*)d_in[0];
  const float* w1  = (const float*)d_in[1];
  const float* b1  = (const float*)d_in[2];
  const float* g1  = (const float*)d_in[3];
  const float* be1 = (const float*)d_in[4];
  const float* w2  = (const float*)d_in[5];
  const float* b2  = (const float*)d_in[6];
  const float* g2  = (const float*)d_in[7];
  const float* be2 = (const float*)d_in[8];
  const float* opw = (const float*)d_in[9];
  const float* opb = (const float*)d_in[10];
  const float* pw1 = (const float*)d_in[11];
  const float* pb1 = (const float*)d_in[12];
  const float* pg  = (const float*)d_in[13];
  const float* pbe = (const float*)d_in[14];
  const float* pw2 = (const float*)d_in[15];
  const float* pb2 = (const float*)d_in[16];
  float* out = (float*)d_out;
  char*  ws  = (char*)d_ws;

  // Workspace: p1E @0 (32MB), p2E @32MB (1MB), w1p_rp @33MB, w2p_rp @34MB,
  // opwp @35MB, fh @36MB (8MB), fl @44MB (8MB), list @52MB (2MB), cnt @54MB.
  unsigned short* p1E    = (unsigned short*)ws;
  unsigned short* p2E    = (unsigned short*)(ws + (size_t)32*MB);
  unsigned short* w1p_rp = (unsigned short*)(ws + (size_t)33*MB);
  unsigned short* w2p_rp = (unsigned short*)(ws + (size_t)34*MB);
  unsigned short* opwp   = (unsigned short*)(ws + (size_t)35*MB);
  unsigned short* fh     = (unsigned short*)(ws + (size_t)36*MB);
  unsigned short* fl     = (unsigned short*)(ws + (size_t)44*MB);
  int*            list   = (int*)(ws + (size_t)52*MB);
  int*            cnt    = (int*)(ws + (size_t)54*MB);

  k_pack  <<<4993, 256, 0, stream>>>(pw1, pw2, w1, w2, opw, p1E, p2E,
                                     w1p_rp, w2p_rp, opwp, cnt);
  k_fused <<<256, 1024, 65536, stream>>>(X, w1p_rp, b1, g1, be1,
                                         w2p_rp, b2, g2, be2, opwp, opb,
                                         fh, fl, out, cnt, list);
  k_expert<<<832,  256, 65536, stream>>>(fh, fl, p1E, pb1, pg, pbe, p2E, pb2,
                                         cnt, list, out);
}

// Round 10
// 173.476 us; speedup vs baseline: 1.3161x; 1.0372x over previous
//
#include <hip/hip_runtime.h>
#include <math.h>

#define Bv   8192
#define EPSv 1e-5f
#define CONFv 0.1f
#define MB (1024*1024)

typedef __attribute__((ext_vector_type(8))) short short8;
typedef __attribute__((ext_vector_type(4))) float f32x4;

__device__ __forceinline__ float wave_sum64(float v){
  #pragma unroll
  for (int o = 32; o; o >>= 1) v += __shfl_xor(v, o, 64);
  return v;
}

__device__ __forceinline__ void split3f(float x, short &h, short &m, short &l){
  unsigned u = __float_as_uint(x);
  h = (short)(u >> 16);
  float r1 = x - __uint_as_float(u & 0xffff0000u);
  unsigned u1 = __float_as_uint(r1);
  m = (short)(u1 >> 16);
  float r2 = r1 - __uint_as_float(u1 & 0xffff0000u);
  l = (short)(__float_as_uint(r2) >> 16);
}

__device__ __forceinline__ void split2f(float x, short &h, short &m){
  unsigned u = __float_as_uint(x);
  h = (short)(u >> 16);
  float r1 = x - __uint_as_float(u & 0xffff0000u);
  m = (short)(__float_as_uint(r1) >> 16);
}

// 5-pass: A 2-plane (h,m) x B 3-plane. Error ~2^-24-class, same as old 6-pass.
__device__ __forceinline__ f32x4 mfma5(short8 ah, short8 am,
                                       short8 bh, short8 bm, short8 bl, f32x4 c){
  c = __builtin_amdgcn_mfma_f32_16x16x32_bf16(am, bm, c, 0, 0, 0);
  c = __builtin_amdgcn_mfma_f32_16x16x32_bf16(ah, bl, c, 0, 0, 0);
  c = __builtin_amdgcn_mfma_f32_16x16x32_bf16(am, bh, c, 0, 0, 0);
  c = __builtin_amdgcn_mfma_f32_16x16x32_bf16(ah, bm, c, 0, 0, 0);
  c = __builtin_amdgcn_mfma_f32_16x16x32_bf16(ah, bh, c, 0, 0, 0);
  return c;
}

__device__ __forceinline__ f32x4 mfma3(short8 ah, short8 al,
                                       short8 bh, short8 bl, f32x4 c){
  c = __builtin_amdgcn_mfma_f32_16x16x32_bf16(al, bh, c, 0, 0, 0);
  c = __builtin_amdgcn_mfma_f32_16x16x32_bf16(ah, bl, c, 0, 0, 0);
  c = __builtin_amdgcn_mfma_f32_16x16x32_bf16(ah, bh, c, 0, 0, 0);
  return c;
}

// ---------------- kernel 1: all weight packing + cnt zero, one dispatch ----
__global__ __launch_bounds__(256) void k_pack(const float* __restrict__ pw1,
    const float* __restrict__ pw2, const float* __restrict__ w1,
    const float* __restrict__ w2, const float* __restrict__ opw,
    unsigned short* __restrict__ p1, unsigned short* __restrict__ p2,
    unsigned short* __restrict__ w1p, unsigned short* __restrict__ w2p,
    unsigned short* __restrict__ opwp, int* __restrict__ cnt)
{
  int bid = blockIdx.x;
  if (bid < 4096){
    int t = bid*256 + threadIdx.x;
    int e = t >> 14, rem = t & 16383, kg = rem >> 8, n = rem & 255;
    const float* src = pw1 + ((size_t)e << 17) + (size_t)(kg*8)*256 + n;
    short8 h, l;
    #pragma unroll
    for (int j = 0; j < 8; j++){
      float w = src[(size_t)j*256];
      unsigned u = __float_as_uint(w);
      float r2 = w - __uint_as_float(u & 0xffff0000u);
      h[j] = (short)(u >> 16);
      l[j] = (short)(__float_as_uint(r2) >> 16);
    }
    int idx8 = ((((n >> 4)*16 + (kg >> 2))*64) + (kg & 3)*16 + (n & 15)) << 3;
    unsigned short* ep = p1 + (size_t)e * 262144;
    *(short8*)(ep + idx8)          = h;
    *(short8*)(ep + 131072 + idx8) = l;
  } else if (bid < 4224){
    int t = (bid - 4096)*256 + threadIdx.x;
    int e = t >> 9, rem = t & 511, kg = rem >> 4, n = rem & 15;
    const float* src = pw2 + (size_t)e*4096 + (size_t)(kg*8)*16 + n;
    short8 h, l;
    #pragma unroll
    for (int j = 0; j < 8; j++){
      float w = src[(size_t)j*16];
      unsigned u = __float_as_uint(w);
      float r2 = w - __uint_as_float(u & 0xffff0000u);
      h[j] = (short)(u >> 16);
      l[j] = (short)(__float_as_uint(r2) >> 16);
    }
    int idx8 = (((kg >> 2)*64) + (kg & 3)*16 + n) << 3;
    unsigned short* ep = p2 + (size_t)e * 8192;
    *(short8*)(ep + idx8)        = h;
    *(short8*)(ep + 4096 + idx8) = l;
  } else if (bid < 4352){
    int gid = (bid - 4224)*256 + threadIdx.x;   // 32768, K=128, N=256
    int k = gid >> 8, n = gid & 255;
    short h, m, l;
    split3f(w1[gid], h, m, l);
    int idx = (((n >> 4)*4 + (k >> 5))*64 + (((k >> 3) & 3)*16 + (n & 15)))*8 + (k & 7);
    w1p[idx]             = (unsigned short)h;
    w1p[32768 + idx]     = (unsigned short)m;
    w1p[2*32768 + idx]   = (unsigned short)l;
  } else if (bid < 4864){
    int gid = (bid - 4352)*256 + threadIdx.x;   // 131072, K=256, N=512
    int k = gid >> 9, n = gid & 511;
    short h, m, l;
    split3f(w2[gid], h, m, l);
    int idx = (((n >> 4)*8 + (k >> 5))*64 + (((k >> 3) & 3)*16 + (n & 15)))*8 + (k & 7);
    w2p[idx]             = (unsigned short)h;
    w2p[131072 + idx]    = (unsigned short)m;
    w2p[2*131072 + idx]  = (unsigned short)l;
  } else if (bid < 4992){
    int gid = (bid - 4864)*256 + threadIdx.x;   // 32768, K=512, N=64
    int k = gid >> 6, n = gid & 63;
    short h, m, l;
    split3f(opw[gid], h, m, l);
    int idx = (((n >> 4)*16 + (k >> 5))*64 + (((k >> 3) & 3)*16 + (n & 15)))*8 + (k & 7);
    opwp[idx]            = (unsigned short)h;
    opwp[32768 + idx]    = (unsigned short)m;
    opwp[2*32768 + idx]  = (unsigned short)l;
  } else {
    if (threadIdx.x < 64) cnt[threadIdx.x] = 0;
  }
}

// ---------------- kernel 2: fused rp1->rp2->gate, M=32, 1024 threads ------
// 16 waves/block, grid 256. LN cross-wave reduction via transposed partials
// (ps/pq[row][wave], b128 reads by one 32-lane reducer) + mi[row] broadcast.
// Summation order w=0..15 kept identical to R9 -> bit-identical LN output.
__global__ __launch_bounds__(1024) void k_fused(const float* __restrict__ X,
    const unsigned short* __restrict__ w1p, const float* __restrict__ b1,
    const float* __restrict__ g1, const float* __restrict__ be1,
    const unsigned short* __restrict__ w2p, const float* __restrict__ b2,
    const float* __restrict__ g2, const float* __restrict__ be2,
    const unsigned short* __restrict__ opwp, const float* __restrict__ opb,
    unsigned short* __restrict__ fh, unsigned short* __restrict__ fl,
    float* __restrict__ dout, int* __restrict__ cnt, int* __restrict__ list)
{
  extern __shared__ unsigned char smem[];
  unsigned short* xh  = (unsigned short*)smem;          // [32][128]
  unsigned short* xm  = xh + 4096;
  unsigned short* hbh = xh + 8192;                      // [32][256]
  unsigned short* hbm = xh + 16384;
  unsigned short* gah = xh;                             // [32][512] overlay
  unsigned short* gam = xh + 16384;
  __shared__ float ps[32][20];                          // partial sums (pad 20)
  __shared__ float pq[32][20];                          // partial sq-sums
  __shared__ float mi[32][2];                           // {mean, inv} per row
  __shared__ float lg[32][64];

  const int tid = threadIdx.x;
  const int r0  = blockIdx.x * 32;
  const int wave = tid >> 6, lane = tid & 63, lquad = lane >> 4, l15 = lane & 15;

  // ---- stage X pre-split (1024 threads, 1 float4 each)
  {
    int r = tid >> 5, c4 = tid & 31;
    float4 v = ((const float4*)X)[(size_t)(r0+r)*32 + c4];
    unsigned u0 = __float_as_uint(v.x), u1 = __float_as_uint(v.y);
    unsigned u2 = __float_as_uint(v.z), u3 = __float_as_uint(v.w);
    float m0 = v.x - __uint_as_float(u0 & 0xffff0000u);
    float m1 = v.y - __uint_as_float(u1 & 0xffff0000u);
    float m2 = v.z - __uint_as_float(u2 & 0xffff0000u);
    float m3 = v.w - __uint_as_float(u3 & 0xffff0000u);
    unsigned hp0 = (u0 >> 16) | (u1 & 0xffff0000u);
    unsigned hp1 = (u2 >> 16) | (u3 & 0xffff0000u);
    unsigned mp0 = (__float_as_uint(m0) >> 16) | (__float_as_uint(m1) & 0xffff0000u);
    unsigned mp1 = (__float_as_uint(m2) >> 16) | (__float_as_uint(m3) & 0xffff0000u);
    int gk = c4 >> 1, half = c4 & 1;
    int off = r*128 + ((gk ^ (r & 7)) << 3) + half*4;
    ((unsigned*)(xh + off))[0] = hp0;
    ((unsigned*)(xh + off))[1] = hp1;
    ((unsigned*)(xm + off))[0] = mp0;
    ((unsigned*)(xm + off))[1] = mp1;
  }
  __syncthreads();

  // ---- GEMM1 (M=32, N=256, K=128) 5-pass; wave owns 1 ntile (16 cols)
  float bcol1, gcol1, becol1;
  {
    int col = wave*16 + l15;
    bcol1 = b1[col]; gcol1 = g1[col]; becol1 = be1[col];
  }
  {
    f32x4 acc[2];
    acc[0] = (f32x4){0.f,0.f,0.f,0.f};
    acc[1] = (f32x4){0.f,0.f,0.f,0.f};
    const int pstride = 32768;
    for (int ks4 = 0; ks4 < 4; ks4++){
      const unsigned short* bp = w1p + (((wave*4 + ks4)*64 + lane) << 3);
      short8 bh = *(const short8*)bp;
      short8 bm = *(const short8*)(bp + pstride);
      short8 bl = *(const short8*)(bp + 2*pstride);
      #pragma unroll
      for (int mt = 0; mt < 2; mt++){
        int r = mt*16 + l15;
        int off = r*128 + (((ks4*4 + lquad) ^ (r & 7)) << 3);
        short8 ah = *(const short8*)(xh + off);
        short8 am = *(const short8*)(xm + off);
        acc[mt] = mfma5(ah, am, bh, bm, bl, acc[mt]);
      }
    }
    #pragma unroll
    for (int mt = 0; mt < 2; mt++)
      #pragma unroll
      for (int reg = 0; reg < 4; reg++){
        float z = acc[mt][reg] + bcol1;
        float s = z, q = z*z;
        #pragma unroll
        for (int o = 1; o < 16; o <<= 1){ s += __shfl_xor(s, o, 64); q += __shfl_xor(q, o, 64); }
        int row = mt*16 + lquad*4 + reg;
        if (l15 == 0){ ps[row][wave] = s; pq[row][wave] = q; }
      }
    __syncthreads();
    if (tid < 32){
      int row = tid;
      float4 s0 = *(const float4*)&ps[row][0],  s1 = *(const float4*)&ps[row][4];
      float4 s2 = *(const float4*)&ps[row][8],  s3 = *(const float4*)&ps[row][12];
      float4 q0 = *(const float4*)&pq[row][0],  q1 = *(const float4*)&pq[row][4];
      float4 q2 = *(const float4*)&pq[row][8],  q3 = *(const float4*)&pq[row][12];
      float s = s0.x; s += s0.y; s += s0.z; s += s0.w;
      s += s1.x; s += s1.y; s += s1.z; s += s1.w;
      s += s2.x; s += s2.y; s += s2.z; s += s2.w;
      s += s3.x; s += s3.y; s += s3.z; s += s3.w;
      float q = q0.x; q += q0.y; q += q0.z; q += q0.w;
      q += q1.x; q += q1.y; q += q1.z; q += q1.w;
      q += q2.x; q += q2.y; q += q2.z; q += q2.w;
      q += q3.x; q += q3.y; q += q3.z; q += q3.w;
      float mean = s * (1.0f/256.0f);
      float var  = q * (1.0f/256.0f) - mean*mean;
      mi[row][0] = mean;
      mi[row][1] = 1.0f / sqrtf(var + EPSv);
    }
    __syncthreads();
    #pragma unroll
    for (int mt = 0; mt < 2; mt++)
      #pragma unroll
      for (int reg = 0; reg < 4; reg++){
        int row = mt*16 + lquad*4 + reg;
        float2 mv = *(const float2*)mi[row];
        int col = wave*16 + l15;
        float z = acc[mt][reg] + bcol1;
        float y = fmaxf((z - mv.x)*mv.y*gcol1 + becol1, 0.f);
        short hh, mm2;
        split2f(y, hh, mm2);
        int gg = col >> 3, c7 = col & 7;
        int adr = row*256 + ((gg ^ (row & 7)) << 3) + c7;
        hbh[adr] = (unsigned short)hh;
        hbm[adr] = (unsigned short)mm2;
      }
  }
  __syncthreads();

  // ---- GEMM2 (M=32, N=512, K=256) 5-pass; wave owns 2 ntiles (32 cols)
  f32x4 acc2[2][2];
  #pragma unroll
  for (int mt = 0; mt < 2; mt++)
    #pragma unroll
    for (int nt = 0; nt < 2; nt++) acc2[mt][nt] = (f32x4){0.f,0.f,0.f,0.f};
  {
    const int pstride = 131072;
    for (int ks4 = 0; ks4 < 8; ks4++){
      short8 ah[2], am[2];
      #pragma unroll
      for (int mt = 0; mt < 2; mt++){
        int r = mt*16 + l15;
        int off = r*256 + (((ks4*4 + lquad) ^ (r & 7)) << 3);
        ah[mt] = *(const short8*)(hbh + off);
        am[mt] = *(const short8*)(hbm + off);
      }
      #pragma unroll
      for (int nt = 0; nt < 2; nt++){
        int ntg = wave*2 + nt;
        const unsigned short* bp = w2p + (((ntg*8 + ks4)*64 + lane) << 3);
        short8 bh = *(const short8*)bp;
        short8 bm = *(const short8*)(bp + pstride);
        short8 bl = *(const short8*)(bp + 2*pstride);
        #pragma unroll
        for (int mt = 0; mt < 2; mt++)
          acc2[mt][nt] = mfma5(ah[mt], am[mt], bh, bm, bl, acc2[mt][nt]);
      }
    }
  }

  // ---- LN2 partials (sum over wave's 2 ntiles, then cross-wave via ps/pq)
  float bcol[2], gcol[2], becol[2];
  #pragma unroll
  for (int nt = 0; nt < 2; nt++){
    int col = (wave*2 + nt)*16 + l15;
    bcol[nt] = b2[col]; gcol[nt] = g2[col]; becol[nt] = be2[col];
  }
  #pragma unroll
  for (int mt = 0; mt < 2; mt++)
    #pragma unroll
    for (int reg = 0; reg < 4; reg++){
      float s = 0.f, q = 0.f;
      #pragma unroll
      for (int nt = 0; nt < 2; nt++){
        float z = acc2[mt][nt][reg] + bcol[nt];
        s += z; q += z*z;
      }
      #pragma unroll
      for (int o = 1; o < 16; o <<= 1){ s += __shfl_xor(s, o, 64); q += __shfl_xor(q, o, 64); }
      int row = mt*16 + lquad*4 + reg;
      if (l15 == 0){ ps[row][wave] = s; pq[row][wave] = q; }
    }
  __syncthreads();   // partials complete; also all hb reads done
  if (tid < 32){
    int row = tid;
    float4 s0 = *(const float4*)&ps[row][0],  s1 = *(const float4*)&ps[row][4];
    float4 s2 = *(const float4*)&ps[row][8],  s3 = *(const float4*)&ps[row][12];
    float4 q0 = *(const float4*)&pq[row][0],  q1 = *(const float4*)&pq[row][4];
    float4 q2 = *(const float4*)&pq[row][8],  q3 = *(const float4*)&pq[row][12];
    float s = s0.x; s += s0.y; s += s0.z; s += s0.w;
    s += s1.x; s += s1.y; s += s1.z; s += s1.w;
    s += s2.x; s += s2.y; s += s2.z; s += s2.w;
    s += s3.x; s += s3.y; s += s3.z; s += s3.w;
    float q = q0.x; q += q0.y; q += q0.z; q += q0.w;
    q += q1.x; q += q1.y; q += q1.z; q += q1.w;
    q += q2.x; q += q2.y; q += q2.z; q += q2.w;
    q += q3.x; q += q3.y; q += q3.z; q += q3.w;
    float mean = s * (1.0f/512.0f);
    float var  = q * (1.0f/512.0f) - mean*mean;
    mi[row][0] = mean;
    mi[row][1] = 1.0f / sqrtf(var + EPSv);
  }
  __syncthreads();   // mi ready; ga overlay also safe now

  // ---- LN2 finalize -> ga 2-plane bf16 (swizzled A layout)
  #pragma unroll
  for (int mt = 0; mt < 2; mt++)
    #pragma unroll
    for (int reg = 0; reg < 4; reg++){
      int row = mt*16 + lquad*4 + reg;
      float2 mv = *(const float2*)mi[row];
      #pragma unroll
      for (int nt = 0; nt < 2; nt++){
        int col = (wave*2 + nt)*16 + l15;
        float z = acc2[mt][nt][reg] + bcol[nt];
        float y = fmaxf((z - mv.x)*mv.y*gcol[nt] + becol[nt], 0.f);
        short hh, mm2;
        split2f(y, hh, mm2);
        int gg = col >> 3, c7 = col & 7;
        int adr = row*512 + ((gg ^ (row & 7)) << 3) + c7;
        gah[adr] = (unsigned short)hh;
        gam[adr] = (unsigned short)mm2;
      }
    }
  __syncthreads();

  // ---- waves 0-3: gate GEMM (M=32, N=64, K=512) 5-pass
  //      waves 4-15: export feats hi/mid planes to global concurrently
  if (wave < 4){
    f32x4 accg[2];
    accg[0] = (f32x4){0.f,0.f,0.f,0.f};
    accg[1] = (f32x4){0.f,0.f,0.f,0.f};
    for (int kt = 0; kt < 16; kt++){
      const unsigned short* bp = opwp + (((wave*16 + kt)*64 + lane) << 3);
      short8 bh = *(const short8*)bp;
      short8 bm = *(const short8*)(bp + 32768);
      short8 bl = *(const short8*)(bp + 65536);
      #pragma unroll
      for (int mt = 0; mt < 2; mt++){
        int r = mt*16 + l15;
        int off = r*512 + (((kt*4 + lquad) ^ (r & 7)) << 3);
        short8 ah = *(const short8*)(gah + off);
        short8 am = *(const short8*)(gam + off);
        accg[mt] = mfma5(ah, am, bh, bm, bl, accg[mt]);
      }
    }
    float opbv = opb[wave*16 + l15];
    #pragma unroll
    for (int mt = 0; mt < 2; mt++)
      #pragma unroll
      for (int reg = 0; reg < 4; reg++)
        lg[mt*16 + lquad*4 + reg][wave*16 + l15] = accg[mt][reg] + opbv;
  } else {
    int t4 = (wave - 4)*64 + lane;   // 768 threads
    for (int i = t4; i < 4096; i += 768){
      int p = i >> 11, rem = i & 2047, r = rem >> 6, gg = rem & 63;
      short8 v = *(const short8*)((p ? gam : gah) + r*512 + ((gg ^ (r & 7)) << 3));
      unsigned short* dst = (p ? fl : fh) + (size_t)(r0 + r)*512 + gg*8;
      *(short8*)dst = v;
    }
  }
  __syncthreads();

  // ---- softmax + top3 (each wave: 2 rows)
  {
    for (int rr = 0; rr < 2; rr++){
      int r = wave*2 + rr, row = r0 + r;
      float l = lg[r][lane];
      float mx = l;
      #pragma unroll
      for (int o = 32; o; o >>= 1) mx = fmaxf(mx, __shfl_xor(mx, o, 64));
      float p = expf(l - mx);
      float s = wave_sum64(p);
      p /= s;
      float pv = p;
      for (int j = 0; j < 3; j++){
        float v = pv; int idx = lane;
        #pragma unroll
        for (int o = 32; o; o >>= 1){
          float ov = __shfl_xor(v, o, 64);
          int   oi = __shfl_xor(idx, o, 64);
          if (ov > v || (ov == v && oi < idx)){ v = ov; idx = oi; }
        }
        if (lane == 0){
          dout[(size_t)row*3 + j]                = v;
          dout[(size_t)Bv*3 + (size_t)row*3 + j] = (float)idx;
        }
        if (v >= CONFv){
          if (lane == 0){
            int pos = atomicAdd(&cnt[idx], 1);
            list[idx*Bv + pos] = (row << 2) | j;
          }
        } else {
          if (lane < 16) dout[(size_t)Bv*6 + (size_t)row*48 + j*16 + lane] = 0.f;
        }
        if (lane == idx) pv = -1.0f;
      }
    }
  }
}

// ---------------- kernel 3: expert MLP, packed-B MFMA, pre-split feats ----
__global__ __launch_bounds__(256) void k_expert(const unsigned short* __restrict__ fh,
    const unsigned short* __restrict__ fl,
    const unsigned short* __restrict__ p1, const float* __restrict__ b1,
    const float* __restrict__ g,  const float* __restrict__ beta,
    const unsigned short* __restrict__ p2, const float* __restrict__ b2,
    const int* __restrict__ cnt,  const int* __restrict__ list,
    float* __restrict__ dout)
{
  extern __shared__ unsigned char smem[];
  unsigned short* xh = (unsigned short*)smem;
  unsigned short* xl = xh + 32*512;
  float*          zs = (float*)smem;
  unsigned short* zp = (unsigned short*)smem;
  __shared__ int sdesc[3];

  const int tid = threadIdx.x;
  const int wave = tid >> 6, lane = tid & 63;
  const int lquad = lane >> 4, l15 = lane & 15;

  if (wave == 0){
    int c  = cnt[lane];
    int tl = (c + 31) >> 5;
    int incl = tl;
    #pragma unroll
    for (int o = 1; o < 64; o <<= 1){
      int v = __shfl_up(incl, o, 64);
      if (lane >= o) incl += v;
    }
    int total = __shfl(incl, 63, 64);
    int G   = (total + 7) >> 3;
    int grp = blockIdx.x & 7, rr = blockIdx.x >> 3;
    int lgc = grp*G + rr;
    int ok  = (G > 0) && (rr < G) && (lgc < total);
    unsigned long long bm = __ballot(ok && (incl > lgc));
    if (lane == 0){
      if (!ok || bm == 0ull){ sdesc[0] = -1; }
      else {
        int e = __ffsll((long long)bm) - 1;
        sdesc[0] = e; sdesc[1] = lgc; sdesc[2] = 0;
      }
    }
    if (bm != 0ull && ok){
      int e = __ffsll((long long)bm) - 1;
      int excl = __shfl(incl - tl, e, 64);
      int ne   = __shfl(c, e, 64);
      if (lane == 0){ sdesc[1] = lgc - excl; sdesc[2] = ne; }
    }
  }
  __syncthreads();
  const int e = sdesc[0];
  if (e < 0) return;
  const int t = sdesc[1];
  const int n = sdesc[2];
  const int base = t * 32;
  const int m = min(32, n - base);
  const int* lrow = list + e*Bv + base;

  // ---- stage feats hi/lo planes -> swizzled LDS (pure copy)
  for (int i = tid; i < 4096; i += 256){
    int p = i >> 11, rem = i & 2047, r = rem >> 6, gg = rem & 63;
    int ev = lrow[(r < m) ? r : 0];
    int row = ev >> 2;
    const unsigned short* src = (p ? fl : fh) + (size_t)row*512 + gg*8;
    short8 v = *(const short8*)src;
    unsigned short* dst = (p ? xl : xh) + r*512 + ((gg ^ (r & 7)) << 3);
    *(short8*)dst = v;
  }
  __syncthreads();

  const unsigned short* p1e = p1 + (size_t)e * 262144;
  const int colbase = wave * 64;
  f32x4 acc[2][4];
  #pragma unroll
  for (int mt = 0; mt < 2; mt++)
    #pragma unroll
    for (int nt = 0; nt < 4; nt++) acc[mt][nt] = (f32x4){0.f,0.f,0.f,0.f};

  for (int kt = 0; kt < 16; kt++){
    short8 ah[2], al[2];
    int gk = kt*4 + lquad;
    #pragma unroll
    for (int mt = 0; mt < 2; mt++){
      int r = mt*16 + l15;
      int off = r*512 + ((gk ^ (r & 7)) << 3);
      ah[mt] = *(const short8*)(xh + off);
      al[mt] = *(const short8*)(xl + off);
    }
    #pragma unroll
    for (int nt = 0; nt < 4; nt++){
      int ntg = wave*4 + nt;
      const unsigned short* bp = p1e + (((ntg*16 + kt)*64 + lane) << 3);
      short8 bh = *(const short8*)bp;
      short8 bl = *(const short8*)(bp + 131072);
      #pragma unroll
      for (int mt = 0; mt < 2; mt++)
        acc[mt][nt] = mfma3(ah[mt], al[mt], bh, bl, acc[mt][nt]);
    }
  }
  __syncthreads();

  #pragma unroll
  for (int nt = 0; nt < 4; nt++){
    int col = colbase + nt*16 + l15;
    float bb = b1[e*256 + col];
    #pragma unroll
    for (int mt = 0; mt < 2; mt++)
      #pragma unroll
      for (int rg = 0; rg < 4; rg++){
        int rl = mt*16 + lquad*4 + rg;
        zs[rl*264 + col] = acc[mt][nt][rg] + bb;
      }
  }
  __syncthreads();

  {
    float gv[4], bv[4];
    #pragma unroll
    for (int j = 0; j < 4; j++){
      gv[j] = g[e*256 + lane + 64*j];
      bv[j] = beta[e*256 + lane + 64*j];
    }
    for (int rr2 = 0; rr2 < 8; rr2++){
      int r = wave*8 + rr2;
      float x[4];
      float s = 0.f;
      #pragma unroll
      for (int j = 0; j < 4; j++){ x[j] = zs[r*264 + lane + 64*j]; s += x[j]; }
      s = wave_sum64(s);
      float mm = s * (1.0f/256.0f);
      float v = 0.f;
      #pragma unroll
      for (int j = 0; j < 4; j++){ float d = x[j] - mm; v += d*d; }
      v = wave_sum64(v) * (1.0f/256.0f);
      float inv = 1.0f / sqrtf(v + EPSv);
      #pragma unroll
      for (int j = 0; j < 4; j++){
        int c = lane + 64*j;
        float y = fmaxf((x[j] - mm)*inv*gv[j] + bv[j], 0.f);
        unsigned u = __float_as_uint(y);
        float res = y - __uint_as_float(u & 0xffff0000u);
        zp[r*528 + c]       = (unsigned short)(u >> 16);
        zp[r*528 + 264 + c] = (unsigned short)(__float_as_uint(res) >> 16);
      }
    }
  }
  __syncthreads();

  if (wave < 2){
    const unsigned short* p2e = p2 + (size_t)e * 8192;
    f32x4 acc2 = (f32x4){0.f,0.f,0.f,0.f};
    for (int kt2 = 0; kt2 < 8; kt2++){
      const unsigned short* zb = zp + (wave*16 + l15)*528 + kt2*32 + lquad*8;
      short8 ahh = *(const short8*)zb;
      short8 all2 = *(const short8*)(zb + 264);
      const unsigned short* bp = p2e + ((kt2*64 + lane) << 3);
      short8 bh = *(const short8*)bp;
      short8 bl = *(const short8*)(bp + 4096);
      acc2 = mfma3(ahh, all2, bh, bl, acc2);
    }
    float b2v = b2[e*16 + l15];
    #pragma unroll
    for (int reg = 0; reg < 4; reg++){
      int rl = wave*16 + lquad*4 + reg;
      if (rl < m){
        int ev = lrow[rl];
        int row = ev >> 2, j = ev & 3;
        dout[(size_t)Bv*6 + (size_t)row*48 + j*16 + l15] = acc2[reg] + b2v;
      }
    }
  }
}

extern "C" void kernel_launch(void* const* d_in, const int* in_sizes, int n_in,
                              void* d_out, int out_size, void* d_ws, size_t ws_size,
                              hipStream_t stream)
{
  const float* X   = (const float*)d_in[0];
  const float* w1  = (const float*)d_in[1];
  const float* b1  = (const float*)d_in[2];
  const float* g1  = (const float*)d_in[3];
  const float* be1 = (const float*)d_in[4];
  const float* w2  = (const float*)d_in[5];
  const float* b2  = (const float*)d_in[6];
  const float* g2  = (const float*)d_in[7];
  const float* be2 = (const float*)d_in[8];
  const float* opw = (const float*)d_in[9];
  const float* opb = (const float*)d_in[10];
  const float* pw1 = (const float*)d_in[11];
  const float* pb1 = (const float*)d_in[12];
  const float* pg  = (const float*)d_in[13];
  const float* pbe = (const float*)d_in[14];
  const float* pw2 = (const float*)d_in[15];
  const float* pb2 = (const float*)d_in[16];
  float* out = (float*)d_out;
  char*  ws  = (char*)d_ws;

  // Workspace: p1E @0 (32MB), p2E @32MB (1MB), w1p_rp @33MB, w2p_rp @34MB,
  // opwp @35MB, fh @36MB (8MB), fl @44MB (8MB), list @52MB (2MB), cnt @54MB.
  unsigned short* p1E    = (unsigned short*)ws;
  unsigned short* p2E    = (unsigned short*)(ws + (size_t)32*MB);
  unsigned short* w1p_rp = (unsigned short*)(ws + (size_t)33*MB);
  unsigned short* w2p_rp = (unsigned short*)(ws + (size_t)34*MB);
  unsigned short* opwp   = (unsigned short*)(ws + (size_t)35*MB);
  unsigned short* fh     = (unsigned short*)(ws + (size_t)36*MB);
  unsigned short* fl     = (unsigned short*)(ws + (size_t)44*MB);
  int*            list   = (int*)(ws + (size_t)52*MB);
  int*            cnt    = (int*)(ws + (size_t)54*MB);

  k_pack  <<<4993, 256, 0, stream>>>(pw1, pw2, w1, w2, opw, p1E, p2E,
                                     w1p_rp, w2p_rp, opwp, cnt);
  k_fused <<<256, 1024, 65536, stream>>>(X, w1p_rp, b1, g1, be1,
                                         w2p_rp, b2, g2, be2, opwp, opb,
                                         fh, fl, out, cnt, list);
  k_expert<<<832,  256, 65536, stream>>>(fh, fl, p1E, pb1, pg, pbe, p2E, pb2,
                                         cnt, list, out);
}

// Round 11
// 173.060 us; speedup vs baseline: 1.3193x; 1.0024x over previous
//
#include <hip/hip_runtime.h>
#include <math.h>

#define Bv   8192
#define EPSv 1e-5f
#define CONFv 0.1f
#define MB (1024*1024)

typedef __attribute__((ext_vector_type(8))) short short8;
typedef __attribute__((ext_vector_type(4))) float f32x4;

__device__ __forceinline__ float wave_sum64(float v){
  #pragma unroll
  for (int o = 32; o; o >>= 1) v += __shfl_xor(v, o, 64);
  return v;
}

__device__ __forceinline__ void split3f(float x, short &h, short &m, short &l){
  unsigned u = __float_as_uint(x);
  h = (short)(u >> 16);
  float r1 = x - __uint_as_float(u & 0xffff0000u);
  unsigned u1 = __float_as_uint(r1);
  m = (short)(u1 >> 16);
  float r2 = r1 - __uint_as_float(u1 & 0xffff0000u);
  l = (short)(__float_as_uint(r2) >> 16);
}

__device__ __forceinline__ void split2f(float x, short &h, short &m){
  unsigned u = __float_as_uint(x);
  h = (short)(u >> 16);
  float r1 = x - __uint_as_float(u & 0xffff0000u);
  m = (short)(__float_as_uint(r1) >> 16);
}

// 5-pass: A 2-plane (h,m) x B 3-plane. Error ~2^-24-class.
__device__ __forceinline__ f32x4 mfma5(short8 ah, short8 am,
                                       short8 bh, short8 bm, short8 bl, f32x4 c){
  c = __builtin_amdgcn_mfma_f32_16x16x32_bf16(am, bm, c, 0, 0, 0);
  c = __builtin_amdgcn_mfma_f32_16x16x32_bf16(ah, bl, c, 0, 0, 0);
  c = __builtin_amdgcn_mfma_f32_16x16x32_bf16(am, bh, c, 0, 0, 0);
  c = __builtin_amdgcn_mfma_f32_16x16x32_bf16(ah, bm, c, 0, 0, 0);
  c = __builtin_amdgcn_mfma_f32_16x16x32_bf16(ah, bh, c, 0, 0, 0);
  return c;
}

__device__ __forceinline__ f32x4 mfma3(short8 ah, short8 al,
                                       short8 bh, short8 bl, f32x4 c){
  c = __builtin_amdgcn_mfma_f32_16x16x32_bf16(al, bh, c, 0, 0, 0);
  c = __builtin_amdgcn_mfma_f32_16x16x32_bf16(ah, bl, c, 0, 0, 0);
  c = __builtin_amdgcn_mfma_f32_16x16x32_bf16(ah, bh, c, 0, 0, 0);
  return c;
}

// ---------------- kernel 1: all weight packing + cnt zero, one dispatch ----
__global__ __launch_bounds__(256) void k_pack(const float* __restrict__ pw1,
    const float* __restrict__ pw2, const float* __restrict__ w1,
    const float* __restrict__ w2, const float* __restrict__ opw,
    unsigned short* __restrict__ p1, unsigned short* __restrict__ p2,
    unsigned short* __restrict__ w1p, unsigned short* __restrict__ w2p,
    unsigned short* __restrict__ opwp, int* __restrict__ cnt)
{
  int bid = blockIdx.x;
  if (bid < 4096){
    int t = bid*256 + threadIdx.x;
    int e = t >> 14, rem = t & 16383, kg = rem >> 8, n = rem & 255;
    const float* src = pw1 + ((size_t)e << 17) + (size_t)(kg*8)*256 + n;
    short8 h, l;
    #pragma unroll
    for (int j = 0; j < 8; j++){
      float w = src[(size_t)j*256];
      unsigned u = __float_as_uint(w);
      float r2 = w - __uint_as_float(u & 0xffff0000u);
      h[j] = (short)(u >> 16);
      l[j] = (short)(__float_as_uint(r2) >> 16);
    }
    int idx8 = ((((n >> 4)*16 + (kg >> 2))*64) + (kg & 3)*16 + (n & 15)) << 3;
    unsigned short* ep = p1 + (size_t)e * 262144;
    *(short8*)(ep + idx8)          = h;
    *(short8*)(ep + 131072 + idx8) = l;
  } else if (bid < 4224){
    int t = (bid - 4096)*256 + threadIdx.x;
    int e = t >> 9, rem = t & 511, kg = rem >> 4, n = rem & 15;
    const float* src = pw2 + (size_t)e*4096 + (size_t)(kg*8)*16 + n;
    short8 h, l;
    #pragma unroll
    for (int j = 0; j < 8; j++){
      float w = src[(size_t)j*16];
      unsigned u = __float_as_uint(w);
      float r2 = w - __uint_as_float(u & 0xffff0000u);
      h[j] = (short)(u >> 16);
      l[j] = (short)(__float_as_uint(r2) >> 16);
    }
    int idx8 = (((kg >> 2)*64) + (kg & 3)*16 + n) << 3;
    unsigned short* ep = p2 + (size_t)e * 8192;
    *(short8*)(ep + idx8)        = h;
    *(short8*)(ep + 4096 + idx8) = l;
  } else if (bid < 4352){
    int gid = (bid - 4224)*256 + threadIdx.x;   // 32768, K=128, N=256
    int k = gid >> 8, n = gid & 255;
    short h, m, l;
    split3f(w1[gid], h, m, l);
    int idx = (((n >> 4)*4 + (k >> 5))*64 + (((k >> 3) & 3)*16 + (n & 15)))*8 + (k & 7);
    w1p[idx]             = (unsigned short)h;
    w1p[32768 + idx]     = (unsigned short)m;
    w1p[2*32768 + idx]   = (unsigned short)l;
  } else if (bid < 4864){
    int gid = (bid - 4352)*256 + threadIdx.x;   // 131072, K=256, N=512
    int k = gid >> 9, n = gid & 511;
    short h, m, l;
    split3f(w2[gid], h, m, l);
    int idx = (((n >> 4)*8 + (k >> 5))*64 + (((k >> 3) & 3)*16 + (n & 15)))*8 + (k & 7);
    w2p[idx]             = (unsigned short)h;
    w2p[131072 + idx]    = (unsigned short)m;
    w2p[2*131072 + idx]  = (unsigned short)l;
  } else if (bid < 4992){
    int gid = (bid - 4864)*256 + threadIdx.x;   // 32768, K=512, N=64
    int k = gid >> 6, n = gid & 63;
    short h, m, l;
    split3f(opw[gid], h, m, l);
    int idx = (((n >> 4)*16 + (k >> 5))*64 + (((k >> 3) & 3)*16 + (n & 15)))*8 + (k & 7);
    opwp[idx]            = (unsigned short)h;
    opwp[32768 + idx]    = (unsigned short)m;
    opwp[2*32768 + idx]  = (unsigned short)l;
  } else {
    if (threadIdx.x < 64) cnt[threadIdx.x] = 0;
  }
}

// ---------------- kernel 2: fused rp1->rp2->gate, M=32, 1024 threads ------
// (unchanged from R10 — the passing, LN-fixed version)
__global__ __launch_bounds__(1024) void k_fused(const float* __restrict__ X,
    const unsigned short* __restrict__ w1p, const float* __restrict__ b1,
    const float* __restrict__ g1, const float* __restrict__ be1,
    const unsigned short* __restrict__ w2p, const float* __restrict__ b2,
    const float* __restrict__ g2, const float* __restrict__ be2,
    const unsigned short* __restrict__ opwp, const float* __restrict__ opb,
    unsigned short* __restrict__ fh, unsigned short* __restrict__ fl,
    float* __restrict__ dout, int* __restrict__ cnt, int* __restrict__ list)
{
  extern __shared__ unsigned char smem[];
  unsigned short* xh  = (unsigned short*)smem;          // [32][128]
  unsigned short* xm  = xh + 4096;
  unsigned short* hbh = xh + 8192;                      // [32][256]
  unsigned short* hbm = xh + 16384;
  unsigned short* gah = xh;                             // [32][512] overlay
  unsigned short* gam = xh + 16384;
  __shared__ float ps[32][20];
  __shared__ float pq[32][20];
  __shared__ float mi[32][2];
  __shared__ float lg[32][64];

  const int tid = threadIdx.x;
  const int r0  = blockIdx.x * 32;
  const int wave = tid >> 6, lane = tid & 63, lquad = lane >> 4, l15 = lane & 15;

  {
    int r = tid >> 5, c4 = tid & 31;
    float4 v = ((const float4*)X)[(size_t)(r0+r)*32 + c4];
    unsigned u0 = __float_as_uint(v.x), u1 = __float_as_uint(v.y);
    unsigned u2 = __float_as_uint(v.z), u3 = __float_as_uint(v.w);
    float m0 = v.x - __uint_as_float(u0 & 0xffff0000u);
    float m1 = v.y - __uint_as_float(u1 & 0xffff0000u);
    float m2 = v.z - __uint_as_float(u2 & 0xffff0000u);
    float m3 = v.w - __uint_as_float(u3 & 0xffff0000u);
    unsigned hp0 = (u0 >> 16) | (u1 & 0xffff0000u);
    unsigned hp1 = (u2 >> 16) | (u3 & 0xffff0000u);
    unsigned mp0 = (__float_as_uint(m0) >> 16) | (__float_as_uint(m1) & 0xffff0000u);
    unsigned mp1 = (__float_as_uint(m2) >> 16) | (__float_as_uint(m3) & 0xffff0000u);
    int gk = c4 >> 1, half = c4 & 1;
    int off = r*128 + ((gk ^ (r & 7)) << 3) + half*4;
    ((unsigned*)(xh + off))[0] = hp0;
    ((unsigned*)(xh + off))[1] = hp1;
    ((unsigned*)(xm + off))[0] = mp0;
    ((unsigned*)(xm + off))[1] = mp1;
  }
  __syncthreads();

  float bcol1, gcol1, becol1;
  {
    int col = wave*16 + l15;
    bcol1 = b1[col]; gcol1 = g1[col]; becol1 = be1[col];
  }
  {
    f32x4 acc[2];
    acc[0] = (f32x4){0.f,0.f,0.f,0.f};
    acc[1] = (f32x4){0.f,0.f,0.f,0.f};
    const int pstride = 32768;
    for (int ks4 = 0; ks4 < 4; ks4++){
      const unsigned short* bp = w1p + (((wave*4 + ks4)*64 + lane) << 3);
      short8 bh = *(const short8*)bp;
      short8 bm = *(const short8*)(bp + pstride);
      short8 bl = *(const short8*)(bp + 2*pstride);
      #pragma unroll
      for (int mt = 0; mt < 2; mt++){
        int r = mt*16 + l15;
        int off = r*128 + (((ks4*4 + lquad) ^ (r & 7)) << 3);
        short8 ah = *(const short8*)(xh + off);
        short8 am = *(const short8*)(xm + off);
        acc[mt] = mfma5(ah, am, bh, bm, bl, acc[mt]);
      }
    }
    #pragma unroll
    for (int mt = 0; mt < 2; mt++)
      #pragma unroll
      for (int reg = 0; reg < 4; reg++){
        float z = acc[mt][reg] + bcol1;
        float s = z, q = z*z;
        #pragma unroll
        for (int o = 1; o < 16; o <<= 1){ s += __shfl_xor(s, o, 64); q += __shfl_xor(q, o, 64); }
        int row = mt*16 + lquad*4 + reg;
        if (l15 == 0){ ps[row][wave] = s; pq[row][wave] = q; }
      }
    __syncthreads();
    if (tid < 32){
      int row = tid;
      float4 s0 = *(const float4*)&ps[row][0],  s1 = *(const float4*)&ps[row][4];
      float4 s2 = *(const float4*)&ps[row][8],  s3 = *(const float4*)&ps[row][12];
      float4 q0 = *(const float4*)&pq[row][0],  q1 = *(const float4*)&pq[row][4];
      float4 q2 = *(const float4*)&pq[row][8],  q3 = *(const float4*)&pq[row][12];
      float s = s0.x; s += s0.y; s += s0.z; s += s0.w;
      s += s1.x; s += s1.y; s += s1.z; s += s1.w;
      s += s2.x; s += s2.y; s += s2.z; s += s2.w;
      s += s3.x; s += s3.y; s += s3.z; s += s3.w;
      float q = q0.x; q += q0.y; q += q0.z; q += q0.w;
      q += q1.x; q += q1.y; q += q1.z; q += q1.w;
      q += q2.x; q += q2.y; q += q2.z; q += q2.w;
      q += q3.x; q += q3.y; q += q3.z; q += q3.w;
      float mean = s * (1.0f/256.0f);
      float var  = q * (1.0f/256.0f) - mean*mean;
      mi[row][0] = mean;
      mi[row][1] = 1.0f / sqrtf(var + EPSv);
    }
    __syncthreads();
    #pragma unroll
    for (int mt = 0; mt < 2; mt++)
      #pragma unroll
      for (int reg = 0; reg < 4; reg++){
        int row = mt*16 + lquad*4 + reg;
        float2 mv = *(const float2*)mi[row];
        int col = wave*16 + l15;
        float z = acc[mt][reg] + bcol1;
        float y = fmaxf((z - mv.x)*mv.y*gcol1 + becol1, 0.f);
        short hh, mm2;
        split2f(y, hh, mm2);
        int gg = col >> 3, c7 = col & 7;
        int adr = row*256 + ((gg ^ (row & 7)) << 3) + c7;
        hbh[adr] = (unsigned short)hh;
        hbm[adr] = (unsigned short)mm2;
      }
  }
  __syncthreads();

  f32x4 acc2[2][2];
  #pragma unroll
  for (int mt = 0; mt < 2; mt++)
    #pragma unroll
    for (int nt = 0; nt < 2; nt++) acc2[mt][nt] = (f32x4){0.f,0.f,0.f,0.f};
  {
    const int pstride = 131072;
    for (int ks4 = 0; ks4 < 8; ks4++){
      short8 ah[2], am[2];
      #pragma unroll
      for (int mt = 0; mt < 2; mt++){
        int r = mt*16 + l15;
        int off = r*256 + (((ks4*4 + lquad) ^ (r & 7)) << 3);
        ah[mt] = *(const short8*)(hbh + off);
        am[mt] = *(const short8*)(hbm + off);
      }
      #pragma unroll
      for (int nt = 0; nt < 2; nt++){
        int ntg = wave*2 + nt;
        const unsigned short* bp = w2p + (((ntg*8 + ks4)*64 + lane) << 3);
        short8 bh = *(const short8*)bp;
        short8 bm = *(const short8*)(bp + pstride);
        short8 bl = *(const short8*)(bp + 2*pstride);
        #pragma unroll
        for (int mt = 0; mt < 2; mt++)
          acc2[mt][nt] = mfma5(ah[mt], am[mt], bh, bm, bl, acc2[mt][nt]);
      }
    }
  }

  float bcol[2], gcol[2], becol[2];
  #pragma unroll
  for (int nt = 0; nt < 2; nt++){
    int col = (wave*2 + nt)*16 + l15;
    bcol[nt] = b2[col]; gcol[nt] = g2[col]; becol[nt] = be2[col];
  }
  #pragma unroll
  for (int mt = 0; mt < 2; mt++)
    #pragma unroll
    for (int reg = 0; reg < 4; reg++){
      float s = 0.f, q = 0.f;
      #pragma unroll
      for (int nt = 0; nt < 2; nt++){
        float z = acc2[mt][nt][reg] + bcol[nt];
        s += z; q += z*z;
      }
      #pragma unroll
      for (int o = 1; o < 16; o <<= 1){ s += __shfl_xor(s, o, 64); q += __shfl_xor(q, o, 64); }
      int row = mt*16 + lquad*4 + reg;
      if (l15 == 0){ ps[row][wave] = s; pq[row][wave] = q; }
    }
  __syncthreads();
  if (tid < 32){
    int row = tid;
    float4 s0 = *(const float4*)&ps[row][0],  s1 = *(const float4*)&ps[row][4];
    float4 s2 = *(const float4*)&ps[row][8],  s3 = *(const float4*)&ps[row][12];
    float4 q0 = *(const float4*)&pq[row][0],  q1 = *(const float4*)&pq[row][4];
    float4 q2 = *(const float4*)&pq[row][8],  q3 = *(const float4*)&pq[row][12];
    float s = s0.x; s += s0.y; s += s0.z; s += s0.w;
    s += s1.x; s += s1.y; s += s1.z; s += s1.w;
    s += s2.x; s += s2.y; s += s2.z; s += s2.w;
    s += s3.x; s += s3.y; s += s3.z; s += s3.w;
    float q = q0.x; q += q0.y; q += q0.z; q += q0.w;
    q += q1.x; q += q1.y; q += q1.z; q += q1.w;
    q += q2.x; q += q2.y; q += q2.z; q += q2.w;
    q += q3.x; q += q3.y; q += q3.z; q += q3.w;
    float mean = s * (1.0f/512.0f);
    float var  = q * (1.0f/512.0f) - mean*mean;
    mi[row][0] = mean;
    mi[row][1] = 1.0f / sqrtf(var + EPSv);
  }
  __syncthreads();

  #pragma unroll
  for (int mt = 0; mt < 2; mt++)
    #pragma unroll
    for (int reg = 0; reg < 4; reg++){
      int row = mt*16 + lquad*4 + reg;
      float2 mv = *(const float2*)mi[row];
      #pragma unroll
      for (int nt = 0; nt < 2; nt++){
        int col = (wave*2 + nt)*16 + l15;
        float z = acc2[mt][nt][reg] + bcol[nt];
        float y = fmaxf((z - mv.x)*mv.y*gcol[nt] + becol[nt], 0.f);
        short hh, mm2;
        split2f(y, hh, mm2);
        int gg = col >> 3, c7 = col & 7;
        int adr = row*512 + ((gg ^ (row & 7)) << 3) + c7;
        gah[adr] = (unsigned short)hh;
        gam[adr] = (unsigned short)mm2;
      }
    }
  __syncthreads();

  if (wave < 4){
    f32x4 accg[2];
    accg[0] = (f32x4){0.f,0.f,0.f,0.f};
    accg[1] = (f32x4){0.f,0.f,0.f,0.f};
    for (int kt = 0; kt < 16; kt++){
      const unsigned short* bp = opwp + (((wave*16 + kt)*64 + lane) << 3);
      short8 bh = *(const short8*)bp;
      short8 bm = *(const short8*)(bp + 32768);
      short8 bl = *(const short8*)(bp + 65536);
      #pragma unroll
      for (int mt = 0; mt < 2; mt++){
        int r = mt*16 + l15;
        int off = r*512 + (((kt*4 + lquad) ^ (r & 7)) << 3);
        short8 ah = *(const short8*)(gah + off);
        short8 am = *(const short8*)(gam + off);
        accg[mt] = mfma5(ah, am, bh, bm, bl, accg[mt]);
      }
    }
    float opbv = opb[wave*16 + l15];
    #pragma unroll
    for (int mt = 0; mt < 2; mt++)
      #pragma unroll
      for (int reg = 0; reg < 4; reg++)
        lg[mt*16 + lquad*4 + reg][wave*16 + l15] = accg[mt][reg] + opbv;
  } else {
    int t4 = (wave - 4)*64 + lane;
    for (int i = t4; i < 4096; i += 768){
      int p = i >> 11, rem = i & 2047, r = rem >> 6, gg = rem & 63;
      short8 v = *(const short8*)((p ? gam : gah) + r*512 + ((gg ^ (r & 7)) << 3));
      unsigned short* dst = (p ? fl : fh) + (size_t)(r0 + r)*512 + gg*8;
      *(short8*)dst = v;
    }
  }
  __syncthreads();

  {
    for (int rr = 0; rr < 2; rr++){
      int r = wave*2 + rr, row = r0 + r;
      float l = lg[r][lane];
      float mx = l;
      #pragma unroll
      for (int o = 32; o; o >>= 1) mx = fmaxf(mx, __shfl_xor(mx, o, 64));
      float p = expf(l - mx);
      float s = wave_sum64(p);
      p /= s;
      float pv = p;
      for (int j = 0; j < 3; j++){
        float v = pv; int idx = lane;
        #pragma unroll
        for (int o = 32; o; o >>= 1){
          float ov = __shfl_xor(v, o, 64);
          int   oi = __shfl_xor(idx, o, 64);
          if (ov > v || (ov == v && oi < idx)){ v = ov; idx = oi; }
        }
        if (lane == 0){
          dout[(size_t)row*3 + j]                = v;
          dout[(size_t)Bv*3 + (size_t)row*3 + j] = (float)idx;
        }
        if (v >= CONFv){
          if (lane == 0){
            int pos = atomicAdd(&cnt[idx], 1);
            list[idx*Bv + pos] = (row << 2) | j;
          }
        } else {
          if (lane < 16) dout[(size_t)Bv*6 + (size_t)row*48 + j*16 + lane] = 0.f;
        }
        if (lane == idx) pv = -1.0f;
      }
    }
  }
}

// ---------------- kernel 3: expert MLP, 512 threads, reg-resident LN ------
// 8 waves, M=32 tile; wave owns 2 ntiles (32 cols). 64KB LDS -> 2 blocks/CU
// -> 16 waves/CU (was 8). LN via transposed partials + 32-lane reducer; z
// stays in registers (no fp32 zs round-trip). zp planes overlay xh.
__global__ __launch_bounds__(512) void k_expert(const unsigned short* __restrict__ fh,
    const unsigned short* __restrict__ fl,
    const unsigned short* __restrict__ p1, const float* __restrict__ b1,
    const float* __restrict__ g,  const float* __restrict__ beta,
    const unsigned short* __restrict__ p2, const float* __restrict__ b2,
    const int* __restrict__ cnt,  const int* __restrict__ list,
    float* __restrict__ dout)
{
  extern __shared__ unsigned char smem[];
  unsigned short* xh = (unsigned short*)smem;        // [32][512]
  unsigned short* xl = xh + 32*512;
  unsigned short* zp = (unsigned short*)smem;        // overlay [32][528] hi/lo
  __shared__ float ps[32][12];
  __shared__ float pq[32][12];
  __shared__ float mi[32][2];
  __shared__ int sdesc[3];

  const int tid = threadIdx.x;
  const int wave = tid >> 6, lane = tid & 63;
  const int lquad = lane >> 4, l15 = lane & 15;

  if (wave == 0){
    int c  = cnt[lane];
    int tl = (c + 31) >> 5;
    int incl = tl;
    #pragma unroll
    for (int o = 1; o < 64; o <<= 1){
      int v = __shfl_up(incl, o, 64);
      if (lane >= o) incl += v;
    }
    int total = __shfl(incl, 63, 64);
    int G   = (total + 7) >> 3;
    int grp = blockIdx.x & 7, rr = blockIdx.x >> 3;
    int lgc = grp*G + rr;
    int ok  = (G > 0) && (rr < G) && (lgc < total);
    unsigned long long bm = __ballot(ok && (incl > lgc));
    if (lane == 0){
      if (!ok || bm == 0ull){ sdesc[0] = -1; }
      else {
        int e = __ffsll((long long)bm) - 1;
        sdesc[0] = e; sdesc[1] = lgc; sdesc[2] = 0;
      }
    }
    if (bm != 0ull && ok){
      int e = __ffsll((long long)bm) - 1;
      int excl = __shfl(incl - tl, e, 64);
      int ne   = __shfl(c, e, 64);
      if (lane == 0){ sdesc[1] = lgc - excl; sdesc[2] = ne; }
    }
  }
  __syncthreads();
  const int e = sdesc[0];
  if (e < 0) return;
  const int t = sdesc[1];
  const int n = sdesc[2];
  const int base = t * 32;
  const int m = min(32, n - base);
  const int* lrow = list + e*Bv + base;

  // ---- stage feats hi/lo planes -> swizzled LDS (pure copy)
  for (int i = tid; i < 4096; i += 512){
    int p = i >> 11, rem = i & 2047, r = rem >> 6, gg = rem & 63;
    int ev = lrow[(r < m) ? r : 0];
    int row = ev >> 2;
    const unsigned short* src = (p ? fl : fh) + (size_t)row*512 + gg*8;
    short8 v = *(const short8*)src;
    unsigned short* dst = (p ? xl : xh) + r*512 + ((gg ^ (r & 7)) << 3);
    *(short8*)dst = v;
  }
  __syncthreads();

  // ---- GEMM1: M=32, N=256, K=512; wave owns ntiles {2w, 2w+1}
  const unsigned short* p1e = p1 + (size_t)e * 262144;
  f32x4 acc[2][2];
  #pragma unroll
  for (int mt = 0; mt < 2; mt++)
    #pragma unroll
    for (int nt = 0; nt < 2; nt++) acc[mt][nt] = (f32x4){0.f,0.f,0.f,0.f};

  for (int kt = 0; kt < 16; kt++){
    short8 ah[2], al[2];
    int gk = kt*4 + lquad;
    #pragma unroll
    for (int mt = 0; mt < 2; mt++){
      int r = mt*16 + l15;
      int off = r*512 + ((gk ^ (r & 7)) << 3);
      ah[mt] = *(const short8*)(xh + off);
      al[mt] = *(const short8*)(xl + off);
    }
    #pragma unroll
    for (int nt = 0; nt < 2; nt++){
      int ntg = wave*2 + nt;
      const unsigned short* bp = p1e + (((ntg*16 + kt)*64 + lane) << 3);
      short8 bh = *(const short8*)bp;
      short8 bl = *(const short8*)(bp + 131072);
      #pragma unroll
      for (int mt = 0; mt < 2; mt++)
        acc[mt][nt] = mfma3(ah[mt], al[mt], bh, bl, acc[mt][nt]);
    }
  }

  // ---- bias + LN partials (in-register; transposed ps/pq)
  float bb[2], gv[2], bv[2];
  #pragma unroll
  for (int nt = 0; nt < 2; nt++){
    int col = (wave*2 + nt)*16 + l15;
    bb[nt] = b1[e*256 + col];
    gv[nt] = g[e*256 + col];
    bv[nt] = beta[e*256 + col];
  }
  #pragma unroll
  for (int mt = 0; mt < 2; mt++)
    #pragma unroll
    for (int reg = 0; reg < 4; reg++){
      float s = 0.f, q = 0.f;
      #pragma unroll
      for (int nt = 0; nt < 2; nt++){
        float z = acc[mt][nt][reg] + bb[nt];
        s += z; q += z*z;
      }
      #pragma unroll
      for (int o = 1; o < 16; o <<= 1){ s += __shfl_xor(s, o, 64); q += __shfl_xor(q, o, 64); }
      int row = mt*16 + lquad*4 + reg;
      if (l15 == 0){ ps[row][wave] = s; pq[row][wave] = q; }
    }
  __syncthreads();   // also: all xh/xl reads done -> zp overlay safe
  if (tid < 32){
    int row = tid;
    float4 s0 = *(const float4*)&ps[row][0], s1 = *(const float4*)&ps[row][4];
    float4 q0 = *(const float4*)&pq[row][0], q1 = *(const float4*)&pq[row][4];
    float s = s0.x; s += s0.y; s += s0.z; s += s0.w;
    s += s1.x; s += s1.y; s += s1.z; s += s1.w;
    float q = q0.x; q += q0.y; q += q0.z; q += q0.w;
    q += q1.x; q += q1.y; q += q1.z; q += q1.w;
    float mean = s * (1.0f/256.0f);
    float var  = q * (1.0f/256.0f) - mean*mean;
    mi[row][0] = mean;
    mi[row][1] = 1.0f / sqrtf(var + EPSv);
  }
  __syncthreads();

  // ---- LN finalize + ReLU -> zp hi/lo planes (row stride 528)
  #pragma unroll
  for (int mt = 0; mt < 2; mt++)
    #pragma unroll
    for (int reg = 0; reg < 4; reg++){
      int row = mt*16 + lquad*4 + reg;
      float2 mv = *(const float2*)mi[row];
      #pragma unroll
      for (int nt = 0; nt < 2; nt++){
        int col = (wave*2 + nt)*16 + l15;
        float z = acc[mt][nt][reg] + bb[nt];
        float y = fmaxf((z - mv.x)*mv.y*gv[nt] + bv[nt], 0.f);
        short hh, mm2;
        split2f(y, hh, mm2);
        zp[row*528 + col]       = (unsigned short)hh;
        zp[row*528 + 264 + col] = (unsigned short)mm2;
      }
    }
  __syncthreads();

  // ---- GEMM2: 32x16, K=256, 3-pass; waves 0,1 handle 16 rows each
  if (wave < 2){
    const unsigned short* p2e = p2 + (size_t)e * 8192;
    f32x4 acc2 = (f32x4){0.f,0.f,0.f,0.f};
    for (int kt2 = 0; kt2 < 8; kt2++){
      const unsigned short* zb = zp + (wave*16 + l15)*528 + kt2*32 + lquad*8;
      short8 ahh = *(const short8*)zb;
      short8 all2 = *(const short8*)(zb + 264);
      const unsigned short* bp = p2e + ((kt2*64 + lane) << 3);
      short8 bh = *(const short8*)bp;
      short8 bl = *(const short8*)(bp + 4096);
      acc2 = mfma3(ahh, all2, bh, bl, acc2);
    }
    float b2v = b2[e*16 + l15];
    #pragma unroll
    for (int reg = 0; reg < 4; reg++){
      int rl = wave*16 + lquad*4 + reg;
      if (rl < m){
        int ev = lrow[rl];
        int row = ev >> 2, j = ev & 3;
        dout[(size_t)Bv*6 + (size_t)row*48 + j*16 + l15] = acc2[reg] + b2v;
      }
    }
  }
}

extern "C" void kernel_launch(void* const* d_in, const int* in_sizes, int n_in,
                              void* d_out, int out_size, void* d_ws, size_t ws_size,
                              hipStream_t stream)
{
  const float* X   = (const float*)d_in[0];
  const float* w1  = (const float*)d_in[1];
  const float* b1  = (const float*)d_in[2];
  const float* g1  = (const float*)d_in[3];
  const float* be1 = (const float*)d_in[4];
  const float* w2  = (const float*)d_in[5];
  const float* b2  = (const float*)d_in[6];
  const float* g2  = (const float*)d_in[7];
  const float* be2 = (const float*)d_in[8];
  const float* opw = (const float*)d_in[9];
  const float* opb = (const float*)d_in[10];
  const float* pw1 = (const float*)d_in[11];
  const float* pb1 = (const float*)d_in[12];
  const float* pg  = (const float*)d_in[13];
  const float* pbe = (const float*)d_in[14];
  const float* pw2 = (const float*)d_in[15];
  const float* pb2 = (const float*)d_in[16];
  float* out = (float*)d_out;
  char*  ws  = (char*)d_ws;

  unsigned short* p1E    = (unsigned short*)ws;
  unsigned short* p2E    = (unsigned short*)(ws + (size_t)32*MB);
  unsigned short* w1p_rp = (unsigned short*)(ws + (size_t)33*MB);
  unsigned short* w2p_rp = (unsigned short*)(ws + (size_t)34*MB);
  unsigned short* opwp   = (unsigned short*)(ws + (size_t)35*MB);
  unsigned short* fh     = (unsigned short*)(ws + (size_t)36*MB);
  unsigned short* fl     = (unsigned short*)(ws + (size_t)44*MB);
  int*            list   = (int*)(ws + (size_t)52*MB);
  int*            cnt    = (int*)(ws + (size_t)54*MB);

  k_pack  <<<4993, 256, 0, stream>>>(pw1, pw2, w1, w2, opw, p1E, p2E,
                                     w1p_rp, w2p_rp, opwp, cnt);
  k_fused <<<256, 1024, 65536, stream>>>(X, w1p_rp, b1, g1, be1,
                                         w2p_rp, b2, g2, be2, opwp, opb,
                                         fh, fl, out, cnt, list);
  k_expert<<<832,  512, 65536, stream>>>(fh, fl, p1E, pb1, pg, pbe, p2E, pb2,
                                         cnt, list, out);
}